// Round 1
// baseline (2951.635 us; speedup 1.0000x reference)
//
#include <hip/hip_runtime.h>
#include <hip/hip_bf16.h>

#define HH 9
#define WW 9
#define HW 81
#define CC 16
#define DD 34
#define SS 6561
#define NHEAD 2
#define HD 17
#define FF 2048
#define EPSF 1e-5f

// ---------------- conv1 + conv2 + argmax ----------------
__global__ __launch_bounds__(256) void prep_kernel(
    const float* __restrict__ obs, const float* __restrict__ w1, const float* __restrict__ b1,
    const float* __restrict__ w2, const float* __restrict__ b2,
    float* __restrict__ cell, int* __restrict__ aidx) {
  __shared__ float y1[CC][HW];
  int t = threadIdx.x;
  if (t == 0) {
    int best = 0; float bv = obs[0];
    for (int i = 1; i < HW; i++) { float v = obs[i]; if (v > bv) { bv = v; best = i; } }
    *aidx = best;
  }
  for (int idx = t; idx < CC * HW; idx += 256) {
    int c = idx / HW, p = idx % HW;
    int i = p / WW, j = p % WW;
    float acc = b1[c];
    for (int ic = 0; ic < 2; ic++)
      for (int di = 0; di < 3; di++) {
        int ii = i + di - 1; if (ii < 0 || ii >= HH) continue;
        for (int dj = 0; dj < 3; dj++) {
          int jj = j + dj - 1; if (jj < 0 || jj >= WW) continue;
          acc += obs[ic * HW + ii * WW + jj] * w1[((c * 2 + ic) * 3 + di) * 3 + dj];
        }
      }
    y1[c][p] = fmaxf(acc, 0.f);
  }
  __syncthreads();
  for (int idx = t; idx < CC * HW; idx += 256) {
    int c = idx / HW, p = idx % HW;
    int i = p / WW, j = p % WW;
    float acc = b2[c];
    for (int ic = 0; ic < CC; ic++)
      for (int di = 0; di < 3; di++) {
        int ii = i + di - 1; if (ii < 0 || ii >= HH) continue;
        for (int dj = 0; dj < 3; dj++) {
          int jj = j + dj - 1; if (jj < 0 || jj >= WW) continue;
          acc += y1[ic][ii * WW + jj] * w2[((c * CC + ic) * 3 + di) * 3 + dj];
        }
      }
    cell[p * CC + c] = fmaxf(acc, 0.f);  // [81][16]
  }
}

// ---------------- token build ----------------
__global__ __launch_bounds__(256) void tokens_kernel(
    const float* __restrict__ cell, float* __restrict__ x) {
  int t = blockIdx.x * 256 + threadIdx.x;
  if (t >= SS) return;
  int i = t / HW, j = t % HW;
  float ri = (float)(i / WW), ci = (float)(i % WW);
  float rj = (float)(j / WW), cj = (float)(j % WW);
  float* row = x + (size_t)t * DD;
  for (int c = 0; c < CC; c++) row[c] = cell[i * CC + c];
  for (int c = 0; c < CC; c++) row[CC + c] = cell[j * CC + c];
  row[32] = (ri - rj) * 0.25f;
  row[33] = (ci - cj) * 0.25f;
}

// ---------------- qkv projection: [S,34] @ [102,34]^T + b -> [S,102] ----------------
__global__ __launch_bounds__(256) void qkv_kernel(
    const float* __restrict__ x, const float* __restrict__ ipw,
    const float* __restrict__ ipb, float* __restrict__ qkv) {
  __shared__ float sw[3 * DD * DD];
  __shared__ float sb[3 * DD];
  __shared__ float sx[64][DD];
  int t = threadIdx.x;
  int row0 = blockIdx.x * 64;
  int nrows = min(64, SS - row0);
  for (int i = t; i < 3 * DD * DD; i += 256) sw[i] = ipw[i];
  for (int i = t; i < 3 * DD; i += 256) sb[i] = ipb[i];
  for (int i = t; i < nrows * DD; i += 256) sx[i / DD][i % DD] = x[(size_t)row0 * DD + i];
  __syncthreads();
  for (int idx = t; idx < nrows * 102; idx += 256) {
    int r = idx / 102, o = idx % 102;
    float acc = sb[o];
    const float* wr = &sw[o * DD];
    for (int d = 0; d < DD; d++) acc += sx[r][d] * wr[d];
    qkv[(size_t)(row0 + r) * 102 + o] = acc;
  }
}

// ---------------- flash attention: 32 queries/block, one head per blockIdx.y ----------------
__global__ __launch_bounds__(256) void attn_kernel(
    const float* __restrict__ qkv, float* __restrict__ o) {
  __shared__ float qs[32][HD];
  __shared__ float ks[128][HD];
  __shared__ float vs[128][HD];
  __shared__ float sc[32][133];   // col 128 reused for alpha; 133 stride kills conflicts
  __shared__ float oa[32][HD];
  __shared__ float mrow[32], lrow[32];
  int t = threadIdx.x;
  int h = blockIdx.y;
  int q0 = blockIdx.x * 32;
  int nq = min(32, SS - q0);
  const float scale = 0.24253562503633297f;  // 1/sqrt(17)
  for (int i = t; i < nq * HD; i += 256) {
    int q = i / HD, d = i % HD;
    qs[q][d] = qkv[(size_t)(q0 + q) * 102 + h * HD + d] * scale;
  }
  for (int i = t; i < 32 * HD; i += 256) oa[i / HD][i % HD] = 0.f;
  if (t < 32) { mrow[t] = -1e30f; lrow[t] = 0.f; }
  __syncthreads();
  for (int k0 = 0; k0 < SS; k0 += 128) {
    int nk = min(128, SS - k0);
    for (int i = t; i < nk * HD; i += 256) {
      int k = i / HD, d = i % HD;
      ks[k][d] = qkv[(size_t)(k0 + k) * 102 + DD + h * HD + d];
      vs[k][d] = qkv[(size_t)(k0 + k) * 102 + 2 * DD + h * HD + d];
    }
    __syncthreads();
    for (int pi = t; pi < nq * 128; pi += 256) {
      int q = pi / 128, k = pi % 128;
      float acc;
      if (k < nk) {
        acc = 0.f;
        for (int d = 0; d < HD; d++) acc += qs[q][d] * ks[k][d];
      } else {
        acc = -1e30f;
      }
      sc[q][k] = acc;
    }
    __syncthreads();
    if (t < nq) {
      float m = mrow[t];
      float tm = m;
      for (int k = 0; k < 128; k++) tm = fmaxf(tm, sc[t][k]);
      float alpha = __expf(m - tm);
      float l = lrow[t] * alpha;
      for (int k = 0; k < 128; k++) {
        float p = __expf(sc[t][k] - tm);
        sc[t][k] = p;
        l += p;
      }
      mrow[t] = tm; lrow[t] = l;
      sc[t][128] = alpha;
    }
    __syncthreads();
    for (int pi = t; pi < nq * HD; pi += 256) {
      int q = pi / HD, d = pi % HD;
      float acc = oa[q][d] * sc[q][128];
      for (int k = 0; k < nk; k++) acc += sc[q][k] * vs[k][d];
      oa[q][d] = acc;
    }
    __syncthreads();
  }
  for (int pi = t; pi < nq * HD; pi += 256) {
    int q = pi / HD, d = pi % HD;
    o[(size_t)(q0 + q) * DD + h * HD + d] = oa[q][d] / lrow[q];
  }
}

// ---------------- out_proj + residual + LN1 (in-place on x) ----------------
__global__ __launch_bounds__(256) void proj_ln1_kernel(
    const float* __restrict__ o, const float* __restrict__ opw, const float* __restrict__ opb,
    const float* __restrict__ g, const float* __restrict__ b, float* __restrict__ x) {
  __shared__ float sw[DD * DD];
  __shared__ float so[32][DD];
  __shared__ float sy[32][35];
  int t = threadIdx.x;
  int r0 = blockIdx.x * 32;
  int nr = min(32, SS - r0);
  for (int i = t; i < DD * DD; i += 256) sw[i] = opw[i];
  for (int i = t; i < nr * DD; i += 256) so[i / DD][i % DD] = o[(size_t)r0 * DD + i];
  __syncthreads();
  for (int idx = t; idx < nr * DD; idx += 256) {
    int r = idx / DD, d = idx % DD;
    float acc = opb[d];
    for (int k = 0; k < DD; k++) acc += so[r][k] * sw[d * DD + k];
    sy[r][d] = acc + x[(size_t)(r0 + r) * DD + d];
  }
  __syncthreads();
  if (t < nr) {
    float m = 0.f;
    for (int d = 0; d < DD; d++) m += sy[t][d];
    m *= (1.f / DD);
    float v = 0.f;
    for (int d = 0; d < DD; d++) { float z = sy[t][d] - m; v += z * z; }
    v *= (1.f / DD);
    float rs = rsqrtf(v + EPSF);
    for (int d = 0; d < DD; d++)
      x[(size_t)(r0 + t) * DD + d] = (sy[t][d] - m) * rs * g[d] + b[d];
  }
}

// ---------------- fused FF (34->2048->34) + residual + LN2, in-place on x ----------------
__global__ __launch_bounds__(256) void ff_ln2_kernel(
    float* __restrict__ x, const float* __restrict__ w1, const float* __restrict__ b1,
    const float* __restrict__ w2, const float* __restrict__ b2,
    const float* __restrict__ g, const float* __restrict__ bb) {
  __shared__ float sx[32][DD];
  __shared__ float sw1[128][DD];
  __shared__ float sw2[DD][133];
  __shared__ float sh[32][129];
  __shared__ float sb1[128];
  __shared__ float fbuf[32][35];
  int t = threadIdx.x;
  int r0 = blockIdx.x * 32;
  int nr = min(32, SS - r0);
  for (int i = t; i < nr * DD; i += 256) sx[i / DD][i % DD] = x[(size_t)r0 * DD + i];
  float facc[5];
  for (int i = 0; i < 5; i++) {
    int pi = t + i * 256;
    facc[i] = (pi < nr * DD) ? b2[pi % DD] : 0.f;
  }
  __syncthreads();
  for (int k0 = 0; k0 < FF; k0 += 128) {
    for (int i = t; i < 128 * DD; i += 256) sw1[i / DD][i % DD] = w1[(size_t)k0 * DD + i];
    for (int i = t; i < DD * 128; i += 256) sw2[i / 128][i % 128] = w2[(size_t)(i / 128) * FF + k0 + (i % 128)];
    if (t < 128) sb1[t] = b1[k0 + t];
    __syncthreads();
    for (int i = t; i < nr * 128; i += 256) {
      int r = i / 128, kk = i % 128;
      float acc = sb1[kk];
      for (int d = 0; d < DD; d++) acc += sx[r][d] * sw1[kk][d];
      sh[r][kk] = fmaxf(acc, 0.f);
    }
    __syncthreads();
    for (int i = 0; i < 5; i++) {
      int pi = t + i * 256;
      if (pi < nr * DD) {
        int r = pi / DD, d = pi % DD;
        float acc = facc[i];
        for (int kk = 0; kk < 128; kk++) acc += sh[r][kk] * sw2[d][kk];
        facc[i] = acc;
      }
    }
    __syncthreads();
  }
  for (int i = 0; i < 5; i++) {
    int pi = t + i * 256;
    if (pi < nr * DD) fbuf[pi / DD][pi % DD] = facc[i];
  }
  __syncthreads();
  if (t < nr) {
    float m = 0.f;
    for (int d = 0; d < DD; d++) { fbuf[t][d] += sx[t][d]; m += fbuf[t][d]; }
    m *= (1.f / DD);
    float v = 0.f;
    for (int d = 0; d < DD; d++) { float z = fbuf[t][d] - m; v += z * z; }
    v *= (1.f / DD);
    float rs = rsqrtf(v + EPSF);
    for (int d = 0; d < DD; d++)
      x[(size_t)(r0 + t) * DD + d] = (fbuf[t][d] - m) * rs * g[d] + bb[d];
  }
}

// ---------------- final: mean of agent token block ----------------
__global__ __launch_bounds__(64) void final_kernel(
    const float* __restrict__ x, const int* __restrict__ aidx, float* __restrict__ out) {
  int d = threadIdx.x;
  if (d >= DD) return;
  int start = (*aidx) * HW;
  float acc = 0.f;
  for (int j = 0; j < HW; j++) acc += x[(size_t)(start + j) * DD + d];
  out[d] = acc * (1.f / HW);
}

extern "C" void kernel_launch(void* const* d_in, const int* in_sizes, int n_in,
                              void* d_out, int out_size, void* d_ws, size_t ws_size,
                              hipStream_t stream) {
  const float* obs = (const float*)d_in[0];
  const float* c1w = (const float*)d_in[1];
  const float* c1b = (const float*)d_in[2];
  const float* c2w = (const float*)d_in[3];
  const float* c2b = (const float*)d_in[4];
  const float* ipw = (const float*)d_in[5];
  const float* ipb = (const float*)d_in[6];
  const float* opw = (const float*)d_in[7];
  const float* opb = (const float*)d_in[8];
  const float* l1w = (const float*)d_in[9];
  const float* l1b = (const float*)d_in[10];
  const float* l2w = (const float*)d_in[11];
  const float* l2b = (const float*)d_in[12];
  const float* g1 = (const float*)d_in[13];
  const float* b1 = (const float*)d_in[14];
  const float* g2 = (const float*)d_in[15];
  const float* b2 = (const float*)d_in[16];
  float* out = (float*)d_out;

  float* ws = (float*)d_ws;
  float* x    = ws;                      // SS*DD   = 223074
  float* qkv  = x + SS * DD;             // SS*102  = 669222
  float* o    = qkv + SS * 102;          // SS*DD   = 223074
  float* cell = o + SS * DD;             // HW*CC   = 1296
  int*   aidx = (int*)(cell + HW * CC);

  prep_kernel<<<1, 256, 0, stream>>>(obs, c1w, c1b, c2w, c2b, cell, aidx);
  tokens_kernel<<<(SS + 255) / 256, 256, 0, stream>>>(cell, x);

  const int qkv_blocks  = (SS + 63) / 64;    // 103
  const int row_blocks  = (SS + 31) / 32;    // 206
  for (int l = 0; l < 2; l++) {
    qkv_kernel<<<qkv_blocks, 256, 0, stream>>>(
        x, ipw + (size_t)l * 102 * DD, ipb + (size_t)l * 102, qkv);
    dim3 ag(row_blocks, NHEAD);
    attn_kernel<<<ag, 256, 0, stream>>>(qkv, o);
    proj_ln1_kernel<<<row_blocks, 256, 0, stream>>>(
        o, opw + (size_t)l * DD * DD, opb + (size_t)l * DD,
        g1 + (size_t)l * DD, b1 + (size_t)l * DD, x);
    ff_ln2_kernel<<<row_blocks, 256, 0, stream>>>(
        x, l1w + (size_t)l * FF * DD, l1b + (size_t)l * FF,
        l2w + (size_t)l * DD * FF, l2b + (size_t)l * DD,
        g2 + (size_t)l * DD, b2 + (size_t)l * DD);
  }
  final_kernel<<<1, 64, 0, stream>>>(x, aidx, out);
}

// Round 2
// 2037.938 us; speedup vs baseline: 1.4483x; 1.4483x over previous
//
#include <hip/hip_runtime.h>
#include <hip/hip_bf16.h>

#define HH 9
#define WW 9
#define HW 81
#define CC 16
#define DD 34
#define SS 6561
#define NHEAD 2
#define HD 17
#define FF 2048
#define EPSF 1e-5f

#define NSPLIT 4
#define NTILES 52   // ceil(6561/128)
#define TPS 13      // tiles per split (52/4)

// ---------------- conv1 + conv2 + argmax ----------------
__global__ __launch_bounds__(256) void prep_kernel(
    const float* __restrict__ obs, const float* __restrict__ w1, const float* __restrict__ b1,
    const float* __restrict__ w2, const float* __restrict__ b2,
    float* __restrict__ cell, int* __restrict__ aidx) {
  __shared__ float y1[CC][HW];
  int t = threadIdx.x;
  if (t == 0) {
    int best = 0; float bv = obs[0];
    for (int i = 1; i < HW; i++) { float v = obs[i]; if (v > bv) { bv = v; best = i; } }
    *aidx = best;
  }
  for (int idx = t; idx < CC * HW; idx += 256) {
    int c = idx / HW, p = idx % HW;
    int i = p / WW, j = p % WW;
    float acc = b1[c];
    for (int ic = 0; ic < 2; ic++)
      for (int di = 0; di < 3; di++) {
        int ii = i + di - 1; if (ii < 0 || ii >= HH) continue;
        for (int dj = 0; dj < 3; dj++) {
          int jj = j + dj - 1; if (jj < 0 || jj >= WW) continue;
          acc += obs[ic * HW + ii * WW + jj] * w1[((c * 2 + ic) * 3 + di) * 3 + dj];
        }
      }
    y1[c][p] = fmaxf(acc, 0.f);
  }
  __syncthreads();
  for (int idx = t; idx < CC * HW; idx += 256) {
    int c = idx / HW, p = idx % HW;
    int i = p / WW, j = p % WW;
    float acc = b2[c];
    for (int ic = 0; ic < CC; ic++)
      for (int di = 0; di < 3; di++) {
        int ii = i + di - 1; if (ii < 0 || ii >= HH) continue;
        for (int dj = 0; dj < 3; dj++) {
          int jj = j + dj - 1; if (jj < 0 || jj >= WW) continue;
          acc += y1[ic][ii * WW + jj] * w2[((c * CC + ic) * 3 + di) * 3 + dj];
        }
      }
    cell[p * CC + c] = fmaxf(acc, 0.f);  // [81][16]
  }
}

// ---------------- token build ----------------
__global__ __launch_bounds__(256) void tokens_kernel(
    const float* __restrict__ cell, float* __restrict__ x) {
  int t = blockIdx.x * 256 + threadIdx.x;
  if (t >= SS) return;
  int i = t / HW, j = t % HW;
  float ri = (float)(i / WW), ci = (float)(i % WW);
  float rj = (float)(j / WW), cj = (float)(j % WW);
  float* row = x + (size_t)t * DD;
  for (int c = 0; c < CC; c++) row[c] = cell[i * CC + c];
  for (int c = 0; c < CC; c++) row[CC + c] = cell[j * CC + c];
  row[32] = (ri - rj) * 0.25f;
  row[33] = (ci - cj) * 0.25f;
}

// ---------------- qkv projection: [S,34] @ [102,34]^T + b -> [S,102] ----------------
__global__ __launch_bounds__(256) void qkv_kernel(
    const float* __restrict__ x, const float* __restrict__ ipw,
    const float* __restrict__ ipb, float* __restrict__ qkv) {
  __shared__ float sw[3 * DD * DD];
  __shared__ float sb[3 * DD];
  __shared__ float sx[64][DD];
  int t = threadIdx.x;
  int row0 = blockIdx.x * 64;
  int nrows = min(64, SS - row0);
  for (int i = t; i < 3 * DD * DD; i += 256) sw[i] = ipw[i];
  for (int i = t; i < 3 * DD; i += 256) sb[i] = ipb[i];
  for (int i = t; i < nrows * DD; i += 256) sx[i / DD][i % DD] = x[(size_t)row0 * DD + i];
  __syncthreads();
  for (int idx = t; idx < nrows * 102; idx += 256) {
    int r = idx / 102, o = idx % 102;
    float acc = sb[o];
    const float* wr = &sw[o * DD];
    for (int d = 0; d < DD; d++) acc += sx[r][d] * wr[d];
    qkv[(size_t)(row0 + r) * 102 + o] = acc;
  }
}

// ---------------- split-K flash attention ----------------
// grid: (206, NHEAD, NSPLIT). Each block: 32 queries, 13 K-tiles of 128.
// Emits unnormalized partial O + running (m, l) per row.
__global__ __launch_bounds__(256) void attn_split_kernel(
    const float* __restrict__ qkv, float* __restrict__ opart,
    float* __restrict__ mpart, float* __restrict__ lpart) {
  __shared__ float qs[32][HD];
  __shared__ float ks[128][HD];
  __shared__ float vs[128][HD];
  __shared__ float sc[32][133];   // stride 133: conflict-free for both access patterns
  __shared__ float oa[32][HD];
  __shared__ float mrow[32], lrow[32], salpha[32];
  int t = threadIdx.x;
  int h = blockIdx.y;
  int sp = blockIdx.z;
  int q0 = blockIdx.x * 32;
  int nq = min(32, SS - q0);
  const float scale = 0.24253562503633297f;  // 1/sqrt(17)
  for (int i = t; i < nq * HD; i += 256) {
    int q = i / HD, d = i % HD;
    qs[q][d] = qkv[(size_t)(q0 + q) * 102 + h * HD + d] * scale;
  }
  for (int i = t; i < 32 * HD; i += 256) oa[i / HD][i % HD] = 0.f;
  if (t < 32) { mrow[t] = -1e30f; lrow[t] = 0.f; salpha[t] = 1.f; }
  __syncthreads();
  int tile0 = sp * TPS, tile1 = min(tile0 + TPS, NTILES);
  for (int tile = tile0; tile < tile1; tile++) {
    int k0 = tile * 128;
    int nk = min(128, SS - k0);
    for (int i = t; i < nk * HD; i += 256) {
      int k = i / HD, d = i % HD;
      ks[k][d] = qkv[(size_t)(k0 + k) * 102 + DD + h * HD + d];
      vs[k][d] = qkv[(size_t)(k0 + k) * 102 + 2 * DD + h * HD + d];
    }
    __syncthreads();
    // scores: 32x128 over all 256 threads
    for (int pi = t; pi < nq * 128; pi += 256) {
      int q = pi >> 7, k = pi & 127;
      float acc = -1e30f;
      if (k < nk) {
        acc = 0.f;
        for (int d = 0; d < HD; d++) acc += qs[q][d] * ks[k][d];
      }
      sc[q][k] = acc;
    }
    __syncthreads();
    // parallel online softmax: 8 threads per row, 16 cols each, shfl combine
    {
      int row = t >> 3, s8 = t & 7;
      float lm = -1e30f;
      for (int i = 0; i < 16; i++) lm = fmaxf(lm, sc[row][s8 * 16 + i]);
      lm = fmaxf(lm, __shfl_xor(lm, 1));
      lm = fmaxf(lm, __shfl_xor(lm, 2));
      lm = fmaxf(lm, __shfl_xor(lm, 4));
      float mold = mrow[row];
      float nm = fmaxf(mold, lm);
      float ps = 0.f;
      for (int i = 0; i < 16; i++) {
        float p = __expf(sc[row][s8 * 16 + i] - nm);
        sc[row][s8 * 16 + i] = p;
        ps += p;
      }
      ps += __shfl_xor(ps, 1);
      ps += __shfl_xor(ps, 2);
      ps += __shfl_xor(ps, 4);
      if (s8 == 0) {
        float alpha = __expf(mold - nm);
        lrow[row] = lrow[row] * alpha + ps;
        mrow[row] = nm;
        salpha[row] = alpha;
      }
    }
    __syncthreads();
    // PV accumulate with rescale
    for (int pi = t; pi < nq * HD; pi += 256) {
      int q = pi / HD, d = pi % HD;
      float acc = oa[q][d] * salpha[q];
      for (int k = 0; k < nk; k++) acc += sc[q][k] * vs[k][d];
      oa[q][d] = acc;
    }
    __syncthreads();
  }
  for (int pi = t; pi < nq * HD; pi += 256) {
    int q = pi / HD, d = pi % HD;
    opart[(((size_t)sp * NHEAD + h) * SS + q0 + q) * HD + d] = oa[q][d];
  }
  if (t < nq) {
    mpart[((size_t)sp * NHEAD + h) * SS + q0 + t] = mrow[t];
    lpart[((size_t)sp * NHEAD + h) * SS + q0 + t] = lrow[t];
  }
}

__global__ __launch_bounds__(256) void attn_combine_kernel(
    const float* __restrict__ opart, const float* __restrict__ mpart,
    const float* __restrict__ lpart, float* __restrict__ o) {
  int idx = blockIdx.x * 256 + threadIdx.x;
  if (idx >= SS * DD) return;
  int q = idx / DD, rem = idx % DD;
  int h = rem / HD, d = rem % HD;
  float m[NSPLIT], l[NSPLIT];
  float M = -1e30f;
  for (int s = 0; s < NSPLIT; s++) {
    m[s] = mpart[((size_t)s * NHEAD + h) * SS + q];
    l[s] = lpart[((size_t)s * NHEAD + h) * SS + q];
    M = fmaxf(M, m[s]);
  }
  float L = 0.f, O = 0.f;
  for (int s = 0; s < NSPLIT; s++) {
    float c = __expf(m[s] - M);
    L += l[s] * c;
    O += opart[(((size_t)s * NHEAD + h) * SS + q) * HD + d] * c;
  }
  o[(size_t)q * DD + rem] = O / L;
}

// ---------------- out_proj + residual + LN1 (in-place on x) ----------------
__global__ __launch_bounds__(256) void proj_ln1_kernel(
    const float* __restrict__ o, const float* __restrict__ opw, const float* __restrict__ opb,
    const float* __restrict__ g, const float* __restrict__ b, float* __restrict__ x) {
  __shared__ float sw[DD * DD];
  __shared__ float so[32][DD];
  __shared__ float sy[32][35];
  int t = threadIdx.x;
  int r0 = blockIdx.x * 32;
  int nr = min(32, SS - r0);
  for (int i = t; i < DD * DD; i += 256) sw[i] = opw[i];
  for (int i = t; i < nr * DD; i += 256) so[i / DD][i % DD] = o[(size_t)r0 * DD + i];
  __syncthreads();
  for (int idx = t; idx < nr * DD; idx += 256) {
    int r = idx / DD, d = idx % DD;
    float acc = opb[d];
    for (int k = 0; k < DD; k++) acc += so[r][k] * sw[d * DD + k];
    sy[r][d] = acc + x[(size_t)(r0 + r) * DD + d];
  }
  __syncthreads();
  if (t < nr) {
    float m = 0.f;
    for (int d = 0; d < DD; d++) m += sy[t][d];
    m *= (1.f / DD);
    float v = 0.f;
    for (int d = 0; d < DD; d++) { float z = sy[t][d] - m; v += z * z; }
    v *= (1.f / DD);
    float rs = rsqrtf(v + EPSF);
    for (int d = 0; d < DD; d++)
      x[(size_t)(r0 + t) * DD + d] = (sy[t][d] - m) * rs * g[d] + b[d];
  }
}

// ---------------- fused FF (34->2048->34) + residual + LN2, in-place on x ----------------
__global__ __launch_bounds__(256) void ff_ln2_kernel(
    float* __restrict__ x, const float* __restrict__ w1, const float* __restrict__ b1,
    const float* __restrict__ w2, const float* __restrict__ b2,
    const float* __restrict__ g, const float* __restrict__ bb) {
  __shared__ float sx[32][DD];
  __shared__ float sw1[128][DD];
  __shared__ float sw2[DD][133];
  __shared__ float sh[32][129];
  __shared__ float sb1[128];
  __shared__ float fbuf[32][35];
  int t = threadIdx.x;
  int r0 = blockIdx.x * 32;
  int nr = min(32, SS - r0);
  for (int i = t; i < nr * DD; i += 256) sx[i / DD][i % DD] = x[(size_t)r0 * DD + i];
  float facc[5];
  for (int i = 0; i < 5; i++) {
    int pi = t + i * 256;
    facc[i] = (pi < nr * DD) ? b2[pi % DD] : 0.f;
  }
  __syncthreads();
  for (int k0 = 0; k0 < FF; k0 += 128) {
    for (int i = t; i < 128 * DD; i += 256) sw1[i / DD][i % DD] = w1[(size_t)k0 * DD + i];
    for (int i = t; i < DD * 128; i += 256) sw2[i / 128][i % 128] = w2[(size_t)(i / 128) * FF + k0 + (i % 128)];
    if (t < 128) sb1[t] = b1[k0 + t];
    __syncthreads();
    for (int i = t; i < nr * 128; i += 256) {
      int r = i / 128, kk = i % 128;
      float acc = sb1[kk];
      for (int d = 0; d < DD; d++) acc += sx[r][d] * sw1[kk][d];
      sh[r][kk] = fmaxf(acc, 0.f);
    }
    __syncthreads();
    for (int i = 0; i < 5; i++) {
      int pi = t + i * 256;
      if (pi < nr * DD) {
        int r = pi / DD, d = pi % DD;
        float acc = facc[i];
        for (int kk = 0; kk < 128; kk++) acc += sh[r][kk] * sw2[d][kk];
        facc[i] = acc;
      }
    }
    __syncthreads();
  }
  for (int i = 0; i < 5; i++) {
    int pi = t + i * 256;
    if (pi < nr * DD) fbuf[pi / DD][pi % DD] = facc[i];
  }
  __syncthreads();
  if (t < nr) {
    float m = 0.f;
    for (int d = 0; d < DD; d++) { fbuf[t][d] += sx[t][d]; m += fbuf[t][d]; }
    m *= (1.f / DD);
    float v = 0.f;
    for (int d = 0; d < DD; d++) { float z = fbuf[t][d] - m; v += z * z; }
    v *= (1.f / DD);
    float rs = rsqrtf(v + EPSF);
    for (int d = 0; d < DD; d++)
      x[(size_t)(r0 + t) * DD + d] = (fbuf[t][d] - m) * rs * g[d] + bb[d];
  }
}

// ---------------- final: mean of agent token block ----------------
__global__ __launch_bounds__(64) void final_kernel(
    const float* __restrict__ x, const int* __restrict__ aidx, float* __restrict__ out) {
  int d = threadIdx.x;
  if (d >= DD) return;
  int start = (*aidx) * HW;
  float acc = 0.f;
  for (int j = 0; j < HW; j++) acc += x[(size_t)(start + j) * DD + d];
  out[d] = acc * (1.f / HW);
}

extern "C" void kernel_launch(void* const* d_in, const int* in_sizes, int n_in,
                              void* d_out, int out_size, void* d_ws, size_t ws_size,
                              hipStream_t stream) {
  const float* obs = (const float*)d_in[0];
  const float* c1w = (const float*)d_in[1];
  const float* c1b = (const float*)d_in[2];
  const float* c2w = (const float*)d_in[3];
  const float* c2b = (const float*)d_in[4];
  const float* ipw = (const float*)d_in[5];
  const float* ipb = (const float*)d_in[6];
  const float* opw = (const float*)d_in[7];
  const float* opb = (const float*)d_in[8];
  const float* l1w = (const float*)d_in[9];
  const float* l1b = (const float*)d_in[10];
  const float* l2w = (const float*)d_in[11];
  const float* l2b = (const float*)d_in[12];
  const float* g1 = (const float*)d_in[13];
  const float* b1 = (const float*)d_in[14];
  const float* g2 = (const float*)d_in[15];
  const float* b2 = (const float*)d_in[16];
  float* out = (float*)d_out;

  float* ws = (float*)d_ws;
  float* x     = ws;                       // SS*DD   = 223074
  float* qkv   = x + SS * DD;              // SS*102  = 669222
  float* o     = qkv + SS * 102;           // SS*DD   = 223074
  float* cell  = o + SS * DD;              // HW*CC   = 1296
  int*   aidx  = (int*)(cell + HW * CC);   // 1
  float* opart = (float*)(aidx + 1);       // NSPLIT*NHEAD*SS*HD = 892296
  float* mpart = opart + (size_t)NSPLIT * NHEAD * SS * HD;  // 52488
  float* lpart = mpart + (size_t)NSPLIT * NHEAD * SS;       // 52488

  prep_kernel<<<1, 256, 0, stream>>>(obs, c1w, c1b, c2w, c2b, cell, aidx);
  tokens_kernel<<<(SS + 255) / 256, 256, 0, stream>>>(cell, x);

  const int qkv_blocks = (SS + 63) / 64;    // 103
  const int row_blocks = (SS + 31) / 32;    // 206
  const int comb_blocks = (SS * DD + 255) / 256;  // 872
  for (int l = 0; l < 2; l++) {
    qkv_kernel<<<qkv_blocks, 256, 0, stream>>>(
        x, ipw + (size_t)l * 102 * DD, ipb + (size_t)l * 102, qkv);
    dim3 ag(row_blocks, NHEAD, NSPLIT);
    attn_split_kernel<<<ag, 256, 0, stream>>>(qkv, opart, mpart, lpart);
    attn_combine_kernel<<<comb_blocks, 256, 0, stream>>>(opart, mpart, lpart, o);
    proj_ln1_kernel<<<row_blocks, 256, 0, stream>>>(
        o, opw + (size_t)l * DD * DD, opb + (size_t)l * DD,
        g1 + (size_t)l * DD, b1 + (size_t)l * DD, x);
    ff_ln2_kernel<<<row_blocks, 256, 0, stream>>>(
        x, l1w + (size_t)l * FF * DD, l1b + (size_t)l * FF,
        l2w + (size_t)l * DD * FF, l2b + (size_t)l * DD,
        g2 + (size_t)l * DD, b2 + (size_t)l * DD);
  }
  final_kernel<<<1, 64, 0, stream>>>(x, aidx, out);
}

// Round 3
// 1025.948 us; speedup vs baseline: 2.8770x; 1.9864x over previous
//
#include <hip/hip_runtime.h>
#include <hip/hip_bf16.h>

#define HH 9
#define WW 9
#define HW 81
#define CC 16
#define DD 34
#define SS 6561
#define NHEAD 2
#define HD 17
#define FF 2048
#define EPSF 1e-5f

#define NSPLIT 4
#define NTILES 52   // ceil(6561/128)
#define TPS 13      // tiles per split

typedef __attribute__((ext_vector_type(8))) short bf16x8;
typedef __attribute__((ext_vector_type(4))) float f32x4;

__device__ __forceinline__ unsigned short f2b(float f) {
  unsigned int u = __float_as_uint(f);
  u += 0x7fffu + ((u >> 16) & 1u);
  return (unsigned short)(u >> 16);
}

// ---------------- conv1 + conv2 + argmax ----------------
__global__ __launch_bounds__(256) void prep_kernel(
    const float* __restrict__ obs, const float* __restrict__ w1, const float* __restrict__ b1,
    const float* __restrict__ w2, const float* __restrict__ b2,
    float* __restrict__ cell, int* __restrict__ aidx) {
  __shared__ float y1[CC][HW];
  int t = threadIdx.x;
  if (t == 0) {
    int best = 0; float bv = obs[0];
    for (int i = 1; i < HW; i++) { float v = obs[i]; if (v > bv) { bv = v; best = i; } }
    *aidx = best;
  }
  for (int idx = t; idx < CC * HW; idx += 256) {
    int c = idx / HW, p = idx % HW;
    int i = p / WW, j = p % WW;
    float acc = b1[c];
    for (int ic = 0; ic < 2; ic++)
      for (int di = 0; di < 3; di++) {
        int ii = i + di - 1; if (ii < 0 || ii >= HH) continue;
        for (int dj = 0; dj < 3; dj++) {
          int jj = j + dj - 1; if (jj < 0 || jj >= WW) continue;
          acc += obs[ic * HW + ii * WW + jj] * w1[((c * 2 + ic) * 3 + di) * 3 + dj];
        }
      }
    y1[c][p] = fmaxf(acc, 0.f);
  }
  __syncthreads();
  for (int idx = t; idx < CC * HW; idx += 256) {
    int c = idx / HW, p = idx % HW;
    int i = p / WW, j = p % WW;
    float acc = b2[c];
    for (int ic = 0; ic < CC; ic++)
      for (int di = 0; di < 3; di++) {
        int ii = i + di - 1; if (ii < 0 || ii >= HH) continue;
        for (int dj = 0; dj < 3; dj++) {
          int jj = j + dj - 1; if (jj < 0 || jj >= WW) continue;
          acc += y1[ic][ii * WW + jj] * w2[((c * CC + ic) * 3 + di) * 3 + dj];
        }
      }
    cell[p * CC + c] = fmaxf(acc, 0.f);
  }
}

// ---------------- token build ----------------
__global__ __launch_bounds__(256) void tokens_kernel(
    const float* __restrict__ cell, float* __restrict__ x) {
  int t = blockIdx.x * 256 + threadIdx.x;
  if (t >= SS) return;
  int i = t / HW, j = t % HW;
  float ri = (float)(i / WW), ci = (float)(i % WW);
  float rj = (float)(j / WW), cj = (float)(j % WW);
  float* row = x + (size_t)t * DD;
  for (int c = 0; c < CC; c++) row[c] = cell[i * CC + c];
  for (int c = 0; c < CC; c++) row[CC + c] = cell[j * CC + c];
  row[32] = (ri - rj) * 0.25f;
  row[33] = (ci - cj) * 0.25f;
}

// ---------------- qkv projection ----------------
__global__ __launch_bounds__(256) void qkv_kernel(
    const float* __restrict__ x, const float* __restrict__ ipw,
    const float* __restrict__ ipb, float* __restrict__ qkv) {
  __shared__ float sw[3 * DD * DD];
  __shared__ float sb[3 * DD];
  __shared__ float sx[64][DD];
  int t = threadIdx.x;
  int row0 = blockIdx.x * 64;
  int nrows = min(64, SS - row0);
  for (int i = t; i < 3 * DD * DD; i += 256) sw[i] = ipw[i];
  for (int i = t; i < 3 * DD; i += 256) sb[i] = ipb[i];
  for (int i = t; i < nrows * DD; i += 256) sx[i / DD][i % DD] = x[(size_t)row0 * DD + i];
  __syncthreads();
  for (int idx = t; idx < nrows * 102; idx += 256) {
    int r = idx / 102, o = idx % 102;
    float acc = sb[o];
    const float* wr = &sw[o * DD];
    for (int d = 0; d < DD; d++) acc += sx[r][d] * wr[d];
    qkv[(size_t)(row0 + r) * 102 + o] = acc;
  }
}

// ---------------- split-K flash attention, bf16 MFMA ----------------
// grid (206, NHEAD, NSPLIT), 256 thr = 4 waves.
// wave w: QK^T -> m-tile (w&1), k-half (w>>1); PV -> m-tile (w&1), d-tile (w>>1).
__global__ __launch_bounds__(256) void attn_split_kernel(
    const float* __restrict__ qkv, float* __restrict__ opart,
    float* __restrict__ mpart, float* __restrict__ lpart) {
  __shared__ __align__(16) unsigned short qs[32 * 32];    // [q][d pad32]
  __shared__ __align__(16) unsigned short ks[128 * 32];   // [tok][d pad32]
  __shared__ __align__(16) unsigned short vst[32 * 128];  // [d pad32][tok]
  __shared__ __align__(16) unsigned short scb[32 * 136];  // P bf16, [q][k] stride 136
  __shared__ float mrow[32], lrow[32], salpha[32];
  __shared__ float pmax[2][32], psum[2][32];

  int t = threadIdx.x;
  int w = t >> 6;
  int lane = t & 63;
  int quad = lane >> 4;
  int col = lane & 15;
  int h = blockIdx.y, sp = blockIdx.z;
  int q0 = blockIdx.x * 32;
  int nq = min(32, SS - q0);
  int m0 = (w & 1) * 16;
  int khalf = w >> 1;
  const float scale = 0.24253562503633297f;  // 1/sqrt(17)

  // zero pads once (d=17..31 stay zero; garbage q rows harmless finite)
  for (int i = t; i < 32 * 32; i += 256) qs[i] = 0;
  for (int i = t; i < 128 * 32; i += 256) ks[i] = 0;
  for (int i = t; i < 32 * 128; i += 256) vst[i] = 0;
  __syncthreads();
  for (int i = t; i < nq * HD; i += 256) {
    int tok = i / HD, d = i % HD;
    qs[tok * 32 + d] = f2b(qkv[(size_t)(q0 + tok) * 102 + h * HD + d] * scale);
  }
  if (t < 32) { mrow[t] = -1e30f; lrow[t] = 0.f; salpha[t] = 1.f; }
  __syncthreads();

  f32x4 acc = {0.f, 0.f, 0.f, 0.f};  // PV accumulator (C layout), persists over tiles
  int tile0 = sp * TPS, tile1 = min(tile0 + TPS, NTILES);
  for (int tile = tile0; tile < tile1; tile++) {
    int k0 = tile * 128;
    int nk = min(128, SS - k0);
    // stage K [tok][d], V transposed [d][tok]
    for (int i = t; i < nk * HD; i += 256) {
      int tok = i / HD, d = i % HD;
      ks[tok * 32 + d] = f2b(qkv[(size_t)(k0 + tok) * 102 + DD + h * HD + d]);
    }
    for (int i = t; i < HD * 128; i += 256) {
      int d = i >> 7, tok = i & 127;
      if (tok < nk)
        vst[d * 128 + tok] = f2b(qkv[(size_t)(k0 + tok) * 102 + 2 * DD + h * HD + d]);
    }
    __syncthreads();

    // ---- QK^T: 4 MFMAs per wave (one a_frag, 4 b_frags) ----
    bf16x8 afrag = *(const bf16x8*)&qs[(m0 + col) * 32 + quad * 8];
    f32x4 s[4];
    for (int nt = 0; nt < 4; nt++) {
      bf16x8 bfrag = *(const bf16x8*)&ks[(khalf * 64 + nt * 16 + col) * 32 + quad * 8];
      f32x4 z = {0.f, 0.f, 0.f, 0.f};
      s[nt] = __builtin_amdgcn_mfma_f32_16x16x32_bf16(afrag, bfrag, z, 0, 0, 0);
      int kg = k0 + khalf * 64 + nt * 16 + col;
      if (kg >= SS)
        for (int r = 0; r < 4; r++) s[nt][r] = -1e30f;
    }
    // ---- row max: in-register + in-quad shuffle (rows = quad*4+r) ----
    float pm[4];
    for (int r = 0; r < 4; r++)
      pm[r] = fmaxf(fmaxf(s[0][r], s[1][r]), fmaxf(s[2][r], s[3][r]));
    for (int m = 1; m <= 8; m <<= 1)
      for (int r = 0; r < 4; r++) pm[r] = fmaxf(pm[r], __shfl_xor(pm[r], m));
    if (col == 0)
      for (int r = 0; r < 4; r++) pmax[khalf][m0 + quad * 4 + r] = pm[r];
    __syncthreads();
    // ---- exp + P write (bf16) + row sum ----
    float mnv[4], ps[4];
    for (int r = 0; r < 4; r++) {
      int row = m0 + quad * 4 + r;
      mnv[r] = fmaxf(mrow[row], fmaxf(pmax[0][row], pmax[1][row]));
      ps[r] = 0.f;
    }
    for (int nt = 0; nt < 4; nt++)
      for (int r = 0; r < 4; r++) {
        float p = __expf(s[nt][r] - mnv[r]);
        scb[(m0 + quad * 4 + r) * 136 + khalf * 64 + nt * 16 + col] = f2b(p);
        ps[r] += p;
      }
    for (int m = 1; m <= 8; m <<= 1)
      for (int r = 0; r < 4; r++) ps[r] += __shfl_xor(ps[r], m);
    if (col == 0)
      for (int r = 0; r < 4; r++) psum[khalf][m0 + quad * 4 + r] = ps[r];
    __syncthreads();
    // ---- state update (one lane per row) ----
    if (t < 32) {
      float mo = mrow[t];
      float mn = fmaxf(mo, fmaxf(pmax[0][t], pmax[1][t]));
      float al = __expf(mo - mn);
      lrow[t] = lrow[t] * al + psum[0][t] + psum[1][t];
      mrow[t] = mn;
      salpha[t] = al;
    }
    __syncthreads();
    // ---- PV: rescale acc, 4 chained MFMAs (K=128) ----
    for (int r = 0; r < 4; r++) acc[r] *= salpha[m0 + quad * 4 + r];
    for (int c = 0; c < 4; c++) {
      bf16x8 pa = *(const bf16x8*)&scb[(m0 + col) * 136 + c * 32 + quad * 8];
      bf16x8 vb = *(const bf16x8*)&vst[(khalf * 16 + col) * 128 + c * 32 + quad * 8];
      acc = __builtin_amdgcn_mfma_f32_16x16x32_bf16(pa, vb, acc, 0, 0, 0);
    }
    __syncthreads();
  }
  // epilogue: store unnormalized partial O + (m,l)
  int dl = khalf * 16 + col;
  for (int r = 0; r < 4; r++) {
    int q = q0 + m0 + quad * 4 + r;
    if (q < SS && dl < HD)
      opart[(((size_t)sp * NHEAD + h) * SS + q) * HD + dl] = acc[r];
  }
  if (t < 32 && q0 + t < SS) {
    mpart[((size_t)sp * NHEAD + h) * SS + q0 + t] = mrow[t];
    lpart[((size_t)sp * NHEAD + h) * SS + q0 + t] = lrow[t];
  }
}

__global__ __launch_bounds__(256) void attn_combine_kernel(
    const float* __restrict__ opart, const float* __restrict__ mpart,
    const float* __restrict__ lpart, float* __restrict__ o) {
  int idx = blockIdx.x * 256 + threadIdx.x;
  if (idx >= SS * DD) return;
  int q = idx / DD, rem = idx % DD;
  int h = rem / HD, d = rem % HD;
  float m[NSPLIT], l[NSPLIT];
  float M = -1e30f;
  for (int s = 0; s < NSPLIT; s++) {
    m[s] = mpart[((size_t)s * NHEAD + h) * SS + q];
    l[s] = lpart[((size_t)s * NHEAD + h) * SS + q];
    M = fmaxf(M, m[s]);
  }
  float L = 0.f, O = 0.f;
  for (int s = 0; s < NSPLIT; s++) {
    float c = __expf(m[s] - M);
    L += l[s] * c;
    O += opart[(((size_t)s * NHEAD + h) * SS + q) * HD + d] * c;
  }
  o[(size_t)q * DD + rem] = O / L;
}

// ---------------- out_proj + residual + LN1 ----------------
__global__ __launch_bounds__(256) void proj_ln1_kernel(
    const float* __restrict__ o, const float* __restrict__ opw, const float* __restrict__ opb,
    const float* __restrict__ g, const float* __restrict__ b, float* __restrict__ x) {
  __shared__ float sw[DD * DD];
  __shared__ float so[32][DD];
  __shared__ float sy[32][35];
  int t = threadIdx.x;
  int r0 = blockIdx.x * 32;
  int nr = min(32, SS - r0);
  for (int i = t; i < DD * DD; i += 256) sw[i] = opw[i];
  for (int i = t; i < nr * DD; i += 256) so[i / DD][i % DD] = o[(size_t)r0 * DD + i];
  __syncthreads();
  for (int idx = t; idx < nr * DD; idx += 256) {
    int r = idx / DD, d = idx % DD;
    float acc = opb[d];
    for (int k = 0; k < DD; k++) acc += so[r][k] * sw[d * DD + k];
    sy[r][d] = acc + x[(size_t)(r0 + r) * DD + d];
  }
  __syncthreads();
  if (t < nr) {
    float m = 0.f;
    for (int d = 0; d < DD; d++) m += sy[t][d];
    m *= (1.f / DD);
    float v = 0.f;
    for (int d = 0; d < DD; d++) { float z = sy[t][d] - m; v += z * z; }
    v *= (1.f / DD);
    float rs = rsqrtf(v + EPSF);
    for (int d = 0; d < DD; d++)
      x[(size_t)(r0 + t) * DD + d] = (sy[t][d] - m) * rs * g[d] + b[d];
  }
}

// ---------------- fused FF + residual + LN2 ----------------
__global__ __launch_bounds__(256) void ff_ln2_kernel(
    float* __restrict__ x, const float* __restrict__ w1, const float* __restrict__ b1,
    const float* __restrict__ w2, const float* __restrict__ b2,
    const float* __restrict__ g, const float* __restrict__ bb) {
  __shared__ float sx[32][DD];
  __shared__ float sw1[128][DD];
  __shared__ float sw2[DD][133];
  __shared__ float sh[32][129];
  __shared__ float sb1[128];
  __shared__ float fbuf[32][35];
  int t = threadIdx.x;
  int r0 = blockIdx.x * 32;
  int nr = min(32, SS - r0);
  for (int i = t; i < nr * DD; i += 256) sx[i / DD][i % DD] = x[(size_t)r0 * DD + i];
  float facc[5];
  for (int i = 0; i < 5; i++) {
    int pi = t + i * 256;
    facc[i] = (pi < nr * DD) ? b2[pi % DD] : 0.f;
  }
  __syncthreads();
  for (int k0 = 0; k0 < FF; k0 += 128) {
    for (int i = t; i < 128 * DD; i += 256) sw1[i / DD][i % DD] = w1[(size_t)k0 * DD + i];
    for (int i = t; i < DD * 128; i += 256) sw2[i / 128][i % 128] = w2[(size_t)(i / 128) * FF + k0 + (i % 128)];
    if (t < 128) sb1[t] = b1[k0 + t];
    __syncthreads();
    for (int i = t; i < nr * 128; i += 256) {
      int r = i / 128, kk = i % 128;
      float acc = sb1[kk];
      for (int d = 0; d < DD; d++) acc += sx[r][d] * sw1[kk][d];
      sh[r][kk] = fmaxf(acc, 0.f);
    }
    __syncthreads();
    for (int i = 0; i < 5; i++) {
      int pi = t + i * 256;
      if (pi < nr * DD) {
        int r = pi / DD, d = pi % DD;
        float acc = facc[i];
        for (int kk = 0; kk < 128; kk++) acc += sh[r][kk] * sw2[d][kk];
        facc[i] = acc;
      }
    }
    __syncthreads();
  }
  for (int i = 0; i < 5; i++) {
    int pi = t + i * 256;
    if (pi < nr * DD) fbuf[pi / DD][pi % DD] = facc[i];
  }
  __syncthreads();
  if (t < nr) {
    float m = 0.f;
    for (int d = 0; d < DD; d++) { fbuf[t][d] += sx[t][d]; m += fbuf[t][d]; }
    m *= (1.f / DD);
    float v = 0.f;
    for (int d = 0; d < DD; d++) { float z = fbuf[t][d] - m; v += z * z; }
    v *= (1.f / DD);
    float rs = rsqrtf(v + EPSF);
    for (int d = 0; d < DD; d++)
      x[(size_t)(r0 + t) * DD + d] = (fbuf[t][d] - m) * rs * g[d] + bb[d];
  }
}

// ---------------- final ----------------
__global__ __launch_bounds__(64) void final_kernel(
    const float* __restrict__ x, const int* __restrict__ aidx, float* __restrict__ out) {
  int d = threadIdx.x;
  if (d >= DD) return;
  int start = (*aidx) * HW;
  float acc = 0.f;
  for (int j = 0; j < HW; j++) acc += x[(size_t)(start + j) * DD + d];
  out[d] = acc * (1.f / HW);
}

extern "C" void kernel_launch(void* const* d_in, const int* in_sizes, int n_in,
                              void* d_out, int out_size, void* d_ws, size_t ws_size,
                              hipStream_t stream) {
  const float* obs = (const float*)d_in[0];
  const float* c1w = (const float*)d_in[1];
  const float* c1b = (const float*)d_in[2];
  const float* c2w = (const float*)d_in[3];
  const float* c2b = (const float*)d_in[4];
  const float* ipw = (const float*)d_in[5];
  const float* ipb = (const float*)d_in[6];
  const float* opw = (const float*)d_in[7];
  const float* opb = (const float*)d_in[8];
  const float* l1w = (const float*)d_in[9];
  const float* l1b = (const float*)d_in[10];
  const float* l2w = (const float*)d_in[11];
  const float* l2b = (const float*)d_in[12];
  const float* g1 = (const float*)d_in[13];
  const float* b1 = (const float*)d_in[14];
  const float* g2 = (const float*)d_in[15];
  const float* b2 = (const float*)d_in[16];
  float* out = (float*)d_out;

  float* ws = (float*)d_ws;
  float* x     = ws;
  float* qkv   = x + SS * DD;
  float* o     = qkv + SS * 102;
  float* cell  = o + SS * DD;
  int*   aidx  = (int*)(cell + HW * CC);
  float* opart = (float*)(aidx + 1);
  float* mpart = opart + (size_t)NSPLIT * NHEAD * SS * HD;
  float* lpart = mpart + (size_t)NSPLIT * NHEAD * SS;

  prep_kernel<<<1, 256, 0, stream>>>(obs, c1w, c1b, c2w, c2b, cell, aidx);
  tokens_kernel<<<(SS + 255) / 256, 256, 0, stream>>>(cell, x);

  const int qkv_blocks = (SS + 63) / 64;
  const int row_blocks = (SS + 31) / 32;
  const int comb_blocks = (SS * DD + 255) / 256;
  for (int l = 0; l < 2; l++) {
    qkv_kernel<<<qkv_blocks, 256, 0, stream>>>(
        x, ipw + (size_t)l * 102 * DD, ipb + (size_t)l * 102, qkv);
    dim3 ag(row_blocks, NHEAD, NSPLIT);
    attn_split_kernel<<<ag, 256, 0, stream>>>(qkv, opart, mpart, lpart);
    attn_combine_kernel<<<comb_blocks, 256, 0, stream>>>(opart, mpart, lpart, o);
    proj_ln1_kernel<<<row_blocks, 256, 0, stream>>>(
        o, opw + (size_t)l * DD * DD, opb + (size_t)l * DD,
        g1 + (size_t)l * DD, b1 + (size_t)l * DD, x);
    ff_ln2_kernel<<<row_blocks, 256, 0, stream>>>(
        x, l1w + (size_t)l * FF * DD, l1b + (size_t)l * FF,
        l2w + (size_t)l * DD * FF, l2b + (size_t)l * DD,
        g2 + (size_t)l * DD, b2 + (size_t)l * DD);
  }
  final_kernel<<<1, 64, 0, stream>>>(x, aidx, out);
}

// Round 4
// 631.631 us; speedup vs baseline: 4.6730x; 1.6243x over previous
//
#include <hip/hip_runtime.h>
#include <hip/hip_bf16.h>

#define HH 9
#define WW 9
#define HW 81
#define CC 16
#define DD 34
#define SS 6561
#define NHEAD 2
#define HD 17
#define FF 2048
#define EPSF 1e-5f

#define NSPLIT 4
#define NTILES 52
#define TPS 13

typedef __attribute__((ext_vector_type(8))) short bf16x8;
typedef __attribute__((ext_vector_type(4))) float f32x4;

__device__ __forceinline__ unsigned short f2b(float f) {
  unsigned int u = __float_as_uint(f);
  u += 0x7fffu + ((u >> 16) & 1u);
  return (unsigned short)(u >> 16);
}

// ---------------- conv1 + conv2 + argmax ----------------
__global__ __launch_bounds__(256) void prep_kernel(
    const float* __restrict__ obs, const float* __restrict__ w1, const float* __restrict__ b1,
    const float* __restrict__ w2, const float* __restrict__ b2,
    float* __restrict__ cell, int* __restrict__ aidx) {
  __shared__ float y1[CC][HW];
  int t = threadIdx.x;
  if (t == 0) {
    int best = 0; float bv = obs[0];
    for (int i = 1; i < HW; i++) { float v = obs[i]; if (v > bv) { bv = v; best = i; } }
    *aidx = best;
  }
  for (int idx = t; idx < CC * HW; idx += 256) {
    int c = idx / HW, p = idx % HW;
    int i = p / WW, j = p % WW;
    float acc = b1[c];
    for (int ic = 0; ic < 2; ic++)
      for (int di = 0; di < 3; di++) {
        int ii = i + di - 1; if (ii < 0 || ii >= HH) continue;
        for (int dj = 0; dj < 3; dj++) {
          int jj = j + dj - 1; if (jj < 0 || jj >= WW) continue;
          acc += obs[ic * HW + ii * WW + jj] * w1[((c * 2 + ic) * 3 + di) * 3 + dj];
        }
      }
    y1[c][p] = fmaxf(acc, 0.f);
  }
  __syncthreads();
  for (int idx = t; idx < CC * HW; idx += 256) {
    int c = idx / HW, p = idx % HW;
    int i = p / WW, j = p % WW;
    float acc = b2[c];
    for (int ic = 0; ic < CC; ic++)
      for (int di = 0; di < 3; di++) {
        int ii = i + di - 1; if (ii < 0 || ii >= HH) continue;
        for (int dj = 0; dj < 3; dj++) {
          int jj = j + dj - 1; if (jj < 0 || jj >= WW) continue;
          acc += y1[ic][ii * WW + jj] * w2[((c * CC + ic) * 3 + di) * 3 + dj];
        }
      }
    cell[p * CC + c] = fmaxf(acc, 0.f);
  }
}

// ---------------- token build ----------------
__global__ __launch_bounds__(256) void tokens_kernel(
    const float* __restrict__ cell, float* __restrict__ x) {
  int t = blockIdx.x * 256 + threadIdx.x;
  if (t >= SS) return;
  int i = t / HW, j = t % HW;
  float ri = (float)(i / WW), ci = (float)(i % WW);
  float rj = (float)(j / WW), cj = (float)(j % WW);
  float* row = x + (size_t)t * DD;
  for (int c = 0; c < CC; c++) row[c] = cell[i * CC + c];
  for (int c = 0; c < CC; c++) row[CC + c] = cell[j * CC + c];
  row[32] = (ri - rj) * 0.25f;
  row[33] = (ci - cj) * 0.25f;
}

// ---------------- qkv projection ----------------
__global__ __launch_bounds__(256) void qkv_kernel(
    const float* __restrict__ x, const float* __restrict__ ipw,
    const float* __restrict__ ipb, float* __restrict__ qkv) {
  __shared__ float sw[3 * DD * DD];
  __shared__ float sb[3 * DD];
  __shared__ float sx[64][DD];
  int t = threadIdx.x;
  int row0 = blockIdx.x * 64;
  int nrows = min(64, SS - row0);
  for (int i = t; i < 3 * DD * DD; i += 256) sw[i] = ipw[i];
  for (int i = t; i < 3 * DD; i += 256) sb[i] = ipb[i];
  for (int i = t; i < nrows * DD; i += 256) sx[i / DD][i % DD] = x[(size_t)row0 * DD + i];
  __syncthreads();
  for (int idx = t; idx < nrows * 102; idx += 256) {
    int r = idx / 102, o = idx % 102;
    float acc = sb[o];
    const float* wr = &sw[o * DD];
    for (int d = 0; d < DD; d++) acc += sx[r][d] * wr[d];
    qkv[(size_t)(row0 + r) * 102 + o] = acc;
  }
}

// ---------------- split-K flash attention, bf16 MFMA ----------------
__global__ __launch_bounds__(256) void attn_split_kernel(
    const float* __restrict__ qkv, float* __restrict__ opart,
    float* __restrict__ mpart, float* __restrict__ lpart) {
  __shared__ __align__(16) unsigned short qs[32 * 32];
  __shared__ __align__(16) unsigned short ks[128 * 32];
  __shared__ __align__(16) unsigned short vst[32 * 128];
  __shared__ __align__(16) unsigned short scb[32 * 136];
  __shared__ float mrow[32], lrow[32], salpha[32];
  __shared__ float pmax[2][32], psum[2][32];

  int t = threadIdx.x;
  int w = t >> 6;
  int lane = t & 63;
  int quad = lane >> 4;
  int col = lane & 15;
  int h = blockIdx.y, sp = blockIdx.z;
  int q0 = blockIdx.x * 32;
  int nq = min(32, SS - q0);
  int m0 = (w & 1) * 16;
  int khalf = w >> 1;
  const float scale = 0.24253562503633297f;

  for (int i = t; i < 32 * 32; i += 256) qs[i] = 0;
  for (int i = t; i < 128 * 32; i += 256) ks[i] = 0;
  for (int i = t; i < 32 * 128; i += 256) vst[i] = 0;
  __syncthreads();
  for (int i = t; i < nq * HD; i += 256) {
    int tok = i / HD, d = i % HD;
    qs[tok * 32 + d] = f2b(qkv[(size_t)(q0 + tok) * 102 + h * HD + d] * scale);
  }
  if (t < 32) { mrow[t] = -1e30f; lrow[t] = 0.f; salpha[t] = 1.f; }
  __syncthreads();

  f32x4 acc = {0.f, 0.f, 0.f, 0.f};
  int tile0 = sp * TPS, tile1 = min(tile0 + TPS, NTILES);
  for (int tile = tile0; tile < tile1; tile++) {
    int k0 = tile * 128;
    int nk = min(128, SS - k0);
    for (int i = t; i < nk * HD; i += 256) {
      int tok = i / HD, d = i % HD;
      ks[tok * 32 + d] = f2b(qkv[(size_t)(k0 + tok) * 102 + DD + h * HD + d]);
    }
    for (int i = t; i < HD * 128; i += 256) {
      int d = i >> 7, tok = i & 127;
      if (tok < nk)
        vst[d * 128 + tok] = f2b(qkv[(size_t)(k0 + tok) * 102 + 2 * DD + h * HD + d]);
    }
    __syncthreads();

    bf16x8 afrag = *(const bf16x8*)&qs[(m0 + col) * 32 + quad * 8];
    f32x4 s[4];
    for (int nt = 0; nt < 4; nt++) {
      bf16x8 bfrag = *(const bf16x8*)&ks[(khalf * 64 + nt * 16 + col) * 32 + quad * 8];
      f32x4 z = {0.f, 0.f, 0.f, 0.f};
      s[nt] = __builtin_amdgcn_mfma_f32_16x16x32_bf16(afrag, bfrag, z, 0, 0, 0);
      int kg = k0 + khalf * 64 + nt * 16 + col;
      if (kg >= SS)
        for (int r = 0; r < 4; r++) s[nt][r] = -1e30f;
    }
    float pm[4];
    for (int r = 0; r < 4; r++)
      pm[r] = fmaxf(fmaxf(s[0][r], s[1][r]), fmaxf(s[2][r], s[3][r]));
    for (int m = 1; m <= 8; m <<= 1)
      for (int r = 0; r < 4; r++) pm[r] = fmaxf(pm[r], __shfl_xor(pm[r], m));
    if (col == 0)
      for (int r = 0; r < 4; r++) pmax[khalf][m0 + quad * 4 + r] = pm[r];
    __syncthreads();
    float mnv[4], ps[4];
    for (int r = 0; r < 4; r++) {
      int row = m0 + quad * 4 + r;
      mnv[r] = fmaxf(mrow[row], fmaxf(pmax[0][row], pmax[1][row]));
      ps[r] = 0.f;
    }
    for (int nt = 0; nt < 4; nt++)
      for (int r = 0; r < 4; r++) {
        float p = __expf(s[nt][r] - mnv[r]);
        scb[(m0 + quad * 4 + r) * 136 + khalf * 64 + nt * 16 + col] = f2b(p);
        ps[r] += p;
      }
    for (int m = 1; m <= 8; m <<= 1)
      for (int r = 0; r < 4; r++) ps[r] += __shfl_xor(ps[r], m);
    if (col == 0)
      for (int r = 0; r < 4; r++) psum[khalf][m0 + quad * 4 + r] = ps[r];
    __syncthreads();
    if (t < 32) {
      float mo = mrow[t];
      float mn = fmaxf(mo, fmaxf(pmax[0][t], pmax[1][t]));
      float al = __expf(mo - mn);
      lrow[t] = lrow[t] * al + psum[0][t] + psum[1][t];
      mrow[t] = mn;
      salpha[t] = al;
    }
    __syncthreads();
    for (int r = 0; r < 4; r++) acc[r] *= salpha[m0 + quad * 4 + r];
    for (int c = 0; c < 4; c++) {
      bf16x8 pa = *(const bf16x8*)&scb[(m0 + col) * 136 + c * 32 + quad * 8];
      bf16x8 vb = *(const bf16x8*)&vst[(khalf * 16 + col) * 128 + c * 32 + quad * 8];
      acc = __builtin_amdgcn_mfma_f32_16x16x32_bf16(pa, vb, acc, 0, 0, 0);
    }
    __syncthreads();
  }
  int dl = khalf * 16 + col;
  for (int r = 0; r < 4; r++) {
    int q = q0 + m0 + quad * 4 + r;
    if (q < SS && dl < HD)
      opart[(((size_t)sp * NHEAD + h) * SS + q) * HD + dl] = acc[r];
  }
  if (t < 32 && q0 + t < SS) {
    mpart[((size_t)sp * NHEAD + h) * SS + q0 + t] = mrow[t];
    lpart[((size_t)sp * NHEAD + h) * SS + q0 + t] = lrow[t];
  }
}

__global__ __launch_bounds__(256) void attn_combine_kernel(
    const float* __restrict__ opart, const float* __restrict__ mpart,
    const float* __restrict__ lpart, float* __restrict__ o) {
  int idx = blockIdx.x * 256 + threadIdx.x;
  if (idx >= SS * DD) return;
  int q = idx / DD, rem = idx % DD;
  int h = rem / HD, d = rem % HD;
  float m[NSPLIT], l[NSPLIT];
  float M = -1e30f;
  for (int s = 0; s < NSPLIT; s++) {
    m[s] = mpart[((size_t)s * NHEAD + h) * SS + q];
    l[s] = lpart[((size_t)s * NHEAD + h) * SS + q];
    M = fmaxf(M, m[s]);
  }
  float L = 0.f, O = 0.f;
  for (int s = 0; s < NSPLIT; s++) {
    float c = __expf(m[s] - M);
    L += l[s] * c;
    O += opart[(((size_t)s * NHEAD + h) * SS + q) * HD + d] * c;
  }
  o[(size_t)q * DD + rem] = O / L;
}

// ---------------- out_proj + residual + LN1 ----------------
__global__ __launch_bounds__(256) void proj_ln1_kernel(
    const float* __restrict__ o, const float* __restrict__ opw, const float* __restrict__ opb,
    const float* __restrict__ g, const float* __restrict__ b, float* __restrict__ x) {
  __shared__ float sw[DD * DD];
  __shared__ float so[32][DD];
  __shared__ float sy[32][35];
  int t = threadIdx.x;
  int r0 = blockIdx.x * 32;
  int nr = min(32, SS - r0);
  for (int i = t; i < DD * DD; i += 256) sw[i] = opw[i];
  for (int i = t; i < nr * DD; i += 256) so[i / DD][i % DD] = o[(size_t)r0 * DD + i];
  __syncthreads();
  for (int idx = t; idx < nr * DD; idx += 256) {
    int r = idx / DD, d = idx % DD;
    float acc = opb[d];
    for (int k = 0; k < DD; k++) acc += so[r][k] * sw[d * DD + k];
    sy[r][d] = acc + x[(size_t)(r0 + r) * DD + d];
  }
  __syncthreads();
  if (t < nr) {
    float m = 0.f;
    for (int d = 0; d < DD; d++) m += sy[t][d];
    m *= (1.f / DD);
    float v = 0.f;
    for (int d = 0; d < DD; d++) { float z = sy[t][d] - m; v += z * z; }
    v *= (1.f / DD);
    float rs = rsqrtf(v + EPSF);
    for (int d = 0; d < DD; d++)
      x[(size_t)(r0 + t) * DD + d] = (sy[t][d] - m) * rs * g[d] + b[d];
  }
}

// ---------------- weight prep: bf16, zero-padded, MFMA-ready ----------------
// w1p[2048][64] (K 34->64), w2p[48][2048] (d 34->48)
__global__ __launch_bounds__(256) void wprep_kernel(
    const float* __restrict__ w1, const float* __restrict__ w2,
    unsigned short* __restrict__ w1p, unsigned short* __restrict__ w2p) {
  int i = blockIdx.x * 256 + threadIdx.x;
  if (i < FF * 64) {
    int f = i >> 6, k = i & 63;
    w1p[i] = (k < DD) ? f2b(w1[f * DD + k]) : (unsigned short)0;
  } else {
    int j = i - FF * 64;
    if (j < 48 * FF) {
      int d = j >> 11, kk = j & 2047;
      w2p[j] = (d < DD) ? f2b(w2[d * FF + kk]) : (unsigned short)0;
    }
  }
}

// ---------------- MFMA FF + residual + LN2 ----------------
// 32 rows/block, 4 waves: m0=(w&1)*16, half=w>>1 (ff n-half for h, K-half for y)
__global__ __launch_bounds__(256) void ff_mfma_kernel(
    float* __restrict__ x, const unsigned short* __restrict__ w1p,
    const unsigned short* __restrict__ w2p, const float* __restrict__ b1g,
    const float* __restrict__ b2g, const float* __restrict__ g,
    const float* __restrict__ bb) {
  __shared__ __align__(16) unsigned short sxA[32 * 72];   // x bf16, K pad 34->64, stride 72
  __shared__ float sxF[32][35];                            // residual fp32
  __shared__ __align__(16) unsigned short hs[32 * 136];   // h bf16, stride 136
  __shared__ float yred[32 * 49];                          // cross-wave K-half partials
  int t = threadIdx.x;
  int w = t >> 6, lane = t & 63, quad = lane >> 4, col = lane & 15;
  int m0 = (w & 1) * 16, half = w >> 1;
  int r0 = blockIdx.x * 32;
  int nr = min(32, SS - r0);

  for (int i = t; i < 32 * 72; i += 256) sxA[i] = 0;
  for (int i = t; i < 32 * 35; i += 256) ((float*)sxF)[i] = 0.f;
  __syncthreads();
  for (int i = t; i < nr * DD; i += 256) {
    int r = i / DD, d = i % DD;
    float v = x[(size_t)(r0 + r) * DD + d];
    sxF[r][d] = v;
    sxA[r * 72 + d] = f2b(v);
  }
  __syncthreads();

  bf16x8 a0 = *(const bf16x8*)&sxA[(m0 + col) * 72 + quad * 8];
  bf16x8 a1 = *(const bf16x8*)&sxA[(m0 + col) * 72 + 32 + quad * 8];
  f32x4 acc3[3];
  for (int nt = 0; nt < 3; nt++) acc3[nt] = (f32x4){0.f, 0.f, 0.f, 0.f};

  for (int kt = 0; kt < 16; kt++) {
    int fbase = kt * 128 + half * 64;
    // h = relu(x @ W1^T + b1), write bf16 to LDS (C->A layout transform)
    for (int nt = 0; nt < 4; nt++) {
      int f = fbase + nt * 16 + col;
      bf16x8 bq0 = *(const bf16x8*)&w1p[f * 64 + quad * 8];
      bf16x8 bq1 = *(const bf16x8*)&w1p[f * 64 + 32 + quad * 8];
      f32x4 hacc = {0.f, 0.f, 0.f, 0.f};
      hacc = __builtin_amdgcn_mfma_f32_16x16x32_bf16(a0, bq0, hacc, 0, 0, 0);
      hacc = __builtin_amdgcn_mfma_f32_16x16x32_bf16(a1, bq1, hacc, 0, 0, 0);
      float bias = b1g[f];
      for (int r = 0; r < 4; r++) {
        float hv = fmaxf(hacc[r] + bias, 0.f);
        hs[(m0 + quad * 4 + r) * 136 + half * 64 + nt * 16 + col] = f2b(hv);
      }
    }
    __syncthreads();
    // y += h @ W2^T (this wave's K-half of the 128)
    bf16x8 ha0 = *(const bf16x8*)&hs[(m0 + col) * 136 + half * 64 + quad * 8];
    bf16x8 ha1 = *(const bf16x8*)&hs[(m0 + col) * 136 + half * 64 + 32 + quad * 8];
    for (int nt = 0; nt < 3; nt++) {
      const unsigned short* wp = &w2p[(size_t)(nt * 16 + col) * FF + kt * 128 + half * 64];
      bf16x8 wb0 = *(const bf16x8*)&wp[quad * 8];
      bf16x8 wb1 = *(const bf16x8*)&wp[32 + quad * 8];
      acc3[nt] = __builtin_amdgcn_mfma_f32_16x16x32_bf16(ha0, wb0, acc3[nt], 0, 0, 0);
      acc3[nt] = __builtin_amdgcn_mfma_f32_16x16x32_bf16(ha1, wb1, acc3[nt], 0, 0, 0);
    }
    __syncthreads();
  }

  // epilogue: combine K-halves, bias + residual + LN2
  if (half == 1) {
    for (int nt = 0; nt < 3; nt++)
      for (int r = 0; r < 4; r++)
        yred[(m0 + quad * 4 + r) * 49 + nt * 16 + col] = acc3[nt][r];
  }
  __syncthreads();
  if (half == 0) {
    float yv[3][4];
    float s1[4] = {0.f, 0.f, 0.f, 0.f}, s2[4] = {0.f, 0.f, 0.f, 0.f};
    for (int nt = 0; nt < 3; nt++) {
      int d = nt * 16 + col;
      bool valid = d < DD;
      float b2v = valid ? b2g[d] : 0.f;
      for (int r = 0; r < 4; r++) {
        int row = m0 + quad * 4 + r;
        float v = acc3[nt][r] + yred[row * 49 + nt * 16 + col];
        v = valid ? (v + b2v + sxF[row][d]) : 0.f;
        yv[nt][r] = v;
        s1[r] += v;
        s2[r] += v * v;
      }
    }
    for (int msk = 1; msk <= 8; msk <<= 1)
      for (int r = 0; r < 4; r++) {
        s1[r] += __shfl_xor(s1[r], msk);
        s2[r] += __shfl_xor(s2[r], msk);
      }
    for (int r = 0; r < 4; r++) {
      int row = m0 + quad * 4 + r;
      if (row >= nr) continue;
      float mean = s1[r] * (1.f / DD);
      float var = s2[r] * (1.f / DD) - mean * mean;
      float rs = rsqrtf(var + EPSF);
      for (int nt = 0; nt < 3; nt++) {
        int d = nt * 16 + col;
        if (d < DD)
          x[(size_t)(r0 + row) * DD + d] = (yv[nt][r] - mean) * rs * g[d] + bb[d];
      }
    }
  }
}

// ---------------- final ----------------
__global__ __launch_bounds__(64) void final_kernel(
    const float* __restrict__ x, const int* __restrict__ aidx, float* __restrict__ out) {
  int d = threadIdx.x;
  if (d >= DD) return;
  int start = (*aidx) * HW;
  float acc = 0.f;
  for (int j = 0; j < HW; j++) acc += x[(size_t)(start + j) * DD + d];
  out[d] = acc * (1.f / HW);
}

extern "C" void kernel_launch(void* const* d_in, const int* in_sizes, int n_in,
                              void* d_out, int out_size, void* d_ws, size_t ws_size,
                              hipStream_t stream) {
  const float* obs = (const float*)d_in[0];
  const float* c1w = (const float*)d_in[1];
  const float* c1b = (const float*)d_in[2];
  const float* c2w = (const float*)d_in[3];
  const float* c2b = (const float*)d_in[4];
  const float* ipw = (const float*)d_in[5];
  const float* ipb = (const float*)d_in[6];
  const float* opw = (const float*)d_in[7];
  const float* opb = (const float*)d_in[8];
  const float* l1w = (const float*)d_in[9];
  const float* l1b = (const float*)d_in[10];
  const float* l2w = (const float*)d_in[11];
  const float* l2b = (const float*)d_in[12];
  const float* g1 = (const float*)d_in[13];
  const float* b1 = (const float*)d_in[14];
  const float* g2 = (const float*)d_in[15];
  const float* b2 = (const float*)d_in[16];
  float* out = (float*)d_out;

  float* ws = (float*)d_ws;
  float* x     = ws;                                        // 223074
  float* qkv   = x + SS * DD;                               // 669222
  float* o     = qkv + SS * 102;                            // 223074
  float* cell  = o + SS * DD;                               // 1296
  int*   aidx  = (int*)(cell + HW * CC);                    // 1
  float* opart = (float*)(aidx + 1);                        // 892296
  float* mpart = opart + (size_t)NSPLIT * NHEAD * SS * HD;  // 52488
  float* lpart = mpart + (size_t)NSPLIT * NHEAD * SS;       // 52488
  // bf16 weight buffers OVERLAY opart (free during FF; reconverted per layer).
  // 16B-align the short pointer.
  size_t opart_off = (size_t)(opart - ws);
  size_t woff = (opart_off + 3) & ~(size_t)3;
  unsigned short* w1p = (unsigned short*)(ws + woff);            // 2048*64 shorts
  unsigned short* w2p = (unsigned short*)(ws + woff + FF * 32);  // 48*2048 shorts

  prep_kernel<<<1, 256, 0, stream>>>(obs, c1w, c1b, c2w, c2b, cell, aidx);
  tokens_kernel<<<(SS + 255) / 256, 256, 0, stream>>>(cell, x);

  const int qkv_blocks = (SS + 63) / 64;
  const int row_blocks = (SS + 31) / 32;
  const int comb_blocks = (SS * DD + 255) / 256;
  const int wprep_blocks = (FF * 64 + 48 * FF + 255) / 256;
  for (int l = 0; l < 2; l++) {
    qkv_kernel<<<qkv_blocks, 256, 0, stream>>>(
        x, ipw + (size_t)l * 102 * DD, ipb + (size_t)l * 102, qkv);
    dim3 ag(row_blocks, NHEAD, NSPLIT);
    attn_split_kernel<<<ag, 256, 0, stream>>>(qkv, opart, mpart, lpart);
    attn_combine_kernel<<<comb_blocks, 256, 0, stream>>>(opart, mpart, lpart, o);
    proj_ln1_kernel<<<row_blocks, 256, 0, stream>>>(
        o, opw + (size_t)l * DD * DD, opb + (size_t)l * DD,
        g1 + (size_t)l * DD, b1 + (size_t)l * DD, x);
    wprep_kernel<<<wprep_blocks, 256, 0, stream>>>(
        l1w + (size_t)l * FF * DD, l2w + (size_t)l * DD * FF, w1p, w2p);
    ff_mfma_kernel<<<row_blocks, 256, 0, stream>>>(
        x, w1p, w2p, l1b + (size_t)l * FF,
        l2b + (size_t)l * DD, g2 + (size_t)l * DD, b2 + (size_t)l * DD);
  }
  final_kernel<<<1, 64, 0, stream>>>(x, aidx, out);
}

// Round 5
// 439.659 us; speedup vs baseline: 6.7135x; 1.4366x over previous
//
#include <hip/hip_runtime.h>
#include <hip/hip_bf16.h>

#define HH 9
#define WW 9
#define HW 81
#define CC 16
#define DD 34
#define SS 6561
#define NHEAD 2
#define HD 17
#define FF 2048
#define EPSF 1e-5f

#define NSPLIT 4
#define NTILES 52
#define TPS 13
#define QB 64

typedef __attribute__((ext_vector_type(8))) short bf16x8;
typedef __attribute__((ext_vector_type(4))) float f32x4;

__device__ __forceinline__ unsigned short f2b(float f) {
  unsigned int u = __float_as_uint(f);
  u += 0x7fffu + ((u >> 16) & 1u);
  return (unsigned short)(u >> 16);
}

// ---------------- conv1 + conv2 + argmax ----------------
__global__ __launch_bounds__(256) void prep_kernel(
    const float* __restrict__ obs, const float* __restrict__ w1, const float* __restrict__ b1,
    const float* __restrict__ w2, const float* __restrict__ b2,
    float* __restrict__ cell, int* __restrict__ aidx) {
  __shared__ float y1[CC][HW];
  int t = threadIdx.x;
  if (t == 0) {
    int best = 0; float bv = obs[0];
    for (int i = 1; i < HW; i++) { float v = obs[i]; if (v > bv) { bv = v; best = i; } }
    *aidx = best;
  }
  for (int idx = t; idx < CC * HW; idx += 256) {
    int c = idx / HW, p = idx % HW;
    int i = p / WW, j = p % WW;
    float acc = b1[c];
    for (int ic = 0; ic < 2; ic++)
      for (int di = 0; di < 3; di++) {
        int ii = i + di - 1; if (ii < 0 || ii >= HH) continue;
        for (int dj = 0; dj < 3; dj++) {
          int jj = j + dj - 1; if (jj < 0 || jj >= WW) continue;
          acc += obs[ic * HW + ii * WW + jj] * w1[((c * 2 + ic) * 3 + di) * 3 + dj];
        }
      }
    y1[c][p] = fmaxf(acc, 0.f);
  }
  __syncthreads();
  for (int idx = t; idx < CC * HW; idx += 256) {
    int c = idx / HW, p = idx % HW;
    int i = p / WW, j = p % WW;
    float acc = b2[c];
    for (int ic = 0; ic < CC; ic++)
      for (int di = 0; di < 3; di++) {
        int ii = i + di - 1; if (ii < 0 || ii >= HH) continue;
        for (int dj = 0; dj < 3; dj++) {
          int jj = j + dj - 1; if (jj < 0 || jj >= WW) continue;
          acc += y1[ic][ii * WW + jj] * w2[((c * CC + ic) * 3 + di) * 3 + dj];
        }
      }
    cell[p * CC + c] = fmaxf(acc, 0.f);
  }
}

// ---------------- token build ----------------
__global__ __launch_bounds__(256) void tokens_kernel(
    const float* __restrict__ cell, float* __restrict__ x) {
  int t = blockIdx.x * 256 + threadIdx.x;
  if (t >= SS) return;
  int i = t / HW, j = t % HW;
  float ri = (float)(i / WW), ci = (float)(i % WW);
  float rj = (float)(j / WW), cj = (float)(j % WW);
  float* row = x + (size_t)t * DD;
  for (int c = 0; c < CC; c++) row[c] = cell[i * CC + c];
  for (int c = 0; c < CC; c++) row[CC + c] = cell[j * CC + c];
  row[32] = (ri - rj) * 0.25f;
  row[33] = (ci - cj) * 0.25f;
}

// ---------------- qkv projection ----------------
__global__ __launch_bounds__(256) void qkv_kernel(
    const float* __restrict__ x, const float* __restrict__ ipw,
    const float* __restrict__ ipb, float* __restrict__ qkv) {
  __shared__ float sw[3 * DD * DD];
  __shared__ float sb[3 * DD];
  __shared__ float sx[64][DD];
  int t = threadIdx.x;
  int row0 = blockIdx.x * 64;
  int nrows = min(64, SS - row0);
  for (int i = t; i < 3 * DD * DD; i += 256) sw[i] = ipw[i];
  for (int i = t; i < 3 * DD; i += 256) sb[i] = ipb[i];
  for (int i = t; i < nrows * DD; i += 256) sx[i / DD][i % DD] = x[(size_t)row0 * DD + i];
  __syncthreads();
  for (int idx = t; idx < nrows * 102; idx += 256) {
    int r = idx / 102, o = idx % 102;
    float acc = sb[o];
    const float* wr = &sw[o * DD];
    for (int d = 0; d < DD; d++) acc += sx[r][d] * wr[d];
    qkv[(size_t)(row0 + r) * 102 + o] = acc;
  }
}

// ---------------- K/V fragment pre-pack (per layer) ----------------
// kfp: ((h*52+T)*8 + nt)*512 + lane*8 + j  = K[tok = T*128 + col*8 + nt][d = quad*8+j]
// vfp: ((h*52+T)*4 + c )*512 + lane*8 + j  = V[tok = T*128 + c*32 + quad*8 + j][d = col]
// v16: [h][T*128 + tl] = V[tok][16]  (fp32)
__global__ __launch_bounds__(256) void kvprep_kernel(
    const float* __restrict__ qkv, unsigned short* __restrict__ kfp,
    unsigned short* __restrict__ vfp, float* __restrict__ v16) {
  const int NK = NHEAD * NTILES * 8 * 512;   // 425984
  const int NV = NHEAD * NTILES * 4 * 512;   // 212992
  const int NV16 = NHEAD * NTILES * 128;     // 13312
  int i = blockIdx.x * 256 + threadIdx.x;
  if (i < NK) {
    int j = i & 7, l = (i >> 3) & 63, nt = (i >> 9) & 7, rest = i >> 12;
    int T = rest % NTILES, h = rest / NTILES;
    int colf = l & 15, quadf = l >> 4;
    int tok = T * 128 + colf * 8 + nt;
    int d = quadf * 8 + j;
    unsigned short v = 0;
    if (tok < SS && d < HD) v = f2b(qkv[(size_t)tok * 102 + DD + h * HD + d]);
    kfp[i] = v;
  } else if (i < NK + NV) {
    int ii = i - NK;
    int j = ii & 7, l = (ii >> 3) & 63, c = (ii >> 9) & 3, rest = ii >> 11;
    int T = rest % NTILES, h = rest / NTILES;
    int colf = l & 15, quadf = l >> 4;
    int tok = T * 128 + c * 32 + quadf * 8 + j;
    unsigned short v = 0;
    if (tok < SS) v = f2b(qkv[(size_t)tok * 102 + 2 * DD + h * HD + colf]);
    vfp[ii] = v;
  } else {
    int ii = i - NK - NV;
    if (ii < NV16) {
      int tl = ii % (NTILES * 128), h = ii / (NTILES * 128);
      v16[ii] = (tl < SS) ? qkv[(size_t)tl * 102 + 2 * DD + h * HD + 16] : 0.f;
    }
  }
}

// ---------------- split-K flash attention: barrier-free, frag-direct ----------------
// grid (103, NHEAD, NSPLIT), 256 thr = 4 waves; wave w owns q-rows [q0+w*16, +16).
__global__ __launch_bounds__(256) void attn_split_kernel(
    const float* __restrict__ qkv, const unsigned short* __restrict__ kfp,
    const unsigned short* __restrict__ vfp, const float* __restrict__ v16,
    float* __restrict__ opart, float* __restrict__ mpart, float* __restrict__ lpart) {
  __shared__ __align__(16) unsigned short scb[4][16 * 136];  // wave-private P, stride 136
  int t = threadIdx.x, w = t >> 6, lane = t & 63, quad = lane >> 4, col = lane & 15;
  int h = blockIdx.y, sp = blockIdx.z;
  int q0 = blockIdx.x * QB;
  const float scale = 0.24253562503633297f;  // 1/sqrt(17)
  const unsigned short* kf = kfp + (size_t)h * (NTILES * 8 * 512);
  const unsigned short* vf = vfp + (size_t)h * (NTILES * 4 * 512);
  const float* v16h = v16 + (size_t)h * (NTILES * 128);
  unsigned short* myscb = &scb[w][0];

  // Q a-frag (A[m=col][k=quad*8+j]); clamp OOB rows (results discarded at store)
  int mq = q0 + w * 16 + col;
  int qc = mq < SS ? mq : SS - 1;
  bf16x8 aq;
#pragma unroll
  for (int j = 0; j < 8; j++) {
    int d = quad * 8 + j;
    aq[j] = (short)((d < HD) ? f2b(qkv[(size_t)qc * 102 + h * HD + d] * scale) : 0);
  }

  f32x4 oacc = {0.f, 0.f, 0.f, 0.f};
  float o16a[4] = {0.f, 0.f, 0.f, 0.f};
  float mreg[4] = {-1e30f, -1e30f, -1e30f, -1e30f};
  float lreg[4] = {0.f, 0.f, 0.f, 0.f};

  int tile0 = sp * TPS, tile1 = min(tile0 + TPS, NTILES);
  for (int tile = tile0; tile < tile1; tile++) {
    int k0 = tile * 128;
    const unsigned short* kt = kf + (size_t)tile * (8 * 512);
    f32x4 s[8];
#pragma unroll
    for (int nt = 0; nt < 8; nt++) {
      bf16x8 kb = *(const bf16x8*)(kt + nt * 512 + lane * 8);
      f32x4 z = {0.f, 0.f, 0.f, 0.f};
      s[nt] = __builtin_amdgcn_mfma_f32_16x16x32_bf16(aq, kb, z, 0, 0, 0);
    }
    if (k0 + 128 > SS) {  // mask invalid tokens (last tile only)
#pragma unroll
      for (int nt = 0; nt < 8; nt++)
        if (k0 + col * 8 + nt >= SS) {
          s[nt][0] = -1e30f; s[nt][1] = -1e30f; s[nt][2] = -1e30f; s[nt][3] = -1e30f;
        }
    }
    // row max (rows = quad*4+r, spread across 16 cols)
    float pm[4];
#pragma unroll
    for (int r = 0; r < 4; r++) {
      pm[r] = fmaxf(fmaxf(fmaxf(s[0][r], s[1][r]), fmaxf(s[2][r], s[3][r])),
                    fmaxf(fmaxf(s[4][r], s[5][r]), fmaxf(s[6][r], s[7][r])));
    }
#pragma unroll
    for (int msk = 1; msk <= 8; msk <<= 1)
#pragma unroll
      for (int r = 0; r < 4; r++) pm[r] = fmaxf(pm[r], __shfl_xor(pm[r], msk));
    float al[4], ps[4];
#pragma unroll
    for (int r = 0; r < 4; r++) {
      float mn = fmaxf(mreg[r], pm[r]);
      al[r] = __expf(mreg[r] - mn);
      mreg[r] = mn;
      ps[r] = 0.f;
    }
    // exp, pack row-contiguous (tok_local = col*8 + nt), one b128 store per r
#pragma unroll
    for (int r = 0; r < 4; r++) {
      bf16x8 pv;
#pragma unroll
      for (int nt = 0; nt < 8; nt++) {
        float p = __expf(s[nt][r] - mreg[r]);
        s[nt][r] = p;
        ps[r] += p;
        pv[nt] = (short)f2b(p);
      }
      *(bf16x8*)(myscb + (quad * 4 + r) * 136 + col * 8) = pv;
    }
#pragma unroll
    for (int msk = 1; msk <= 8; msk <<= 1)
#pragma unroll
      for (int r = 0; r < 4; r++) ps[r] += __shfl_xor(ps[r], msk);
#pragma unroll
    for (int r = 0; r < 4; r++) lreg[r] = lreg[r] * al[r] + ps[r];
    // d=16 column via VALU dot (v16 packed in tok_local order)
    f32x4 va = *(const f32x4*)(v16h + k0 + col * 8);
    f32x4 vb4 = *(const f32x4*)(v16h + k0 + col * 8 + 4);
#pragma unroll
    for (int r = 0; r < 4; r++) {
      o16a[r] = o16a[r] * al[r]
              + s[0][r] * va[0] + s[1][r] * va[1] + s[2][r] * va[2] + s[3][r] * va[3]
              + s[4][r] * vb4[0] + s[5][r] * vb4[1] + s[6][r] * vb4[2] + s[7][r] * vb4[3];
      oacc[r] *= al[r];
    }
    // PV: A-frag from wave-private LDS, B-frag direct from vfp
    const unsigned short* vt = vf + (size_t)tile * (4 * 512);
#pragma unroll
    for (int c = 0; c < 4; c++) {
      bf16x8 pa = *(const bf16x8*)(myscb + col * 136 + c * 32 + quad * 8);
      bf16x8 vbf = *(const bf16x8*)(vt + c * 512 + lane * 8);
      oacc = __builtin_amdgcn_mfma_f32_16x16x32_bf16(pa, vbf, oacc, 0, 0, 0);
    }
  }
  // epilogue: reduce o16 across cols, store partials
#pragma unroll
  for (int msk = 1; msk <= 8; msk <<= 1)
#pragma unroll
    for (int r = 0; r < 4; r++) o16a[r] += __shfl_xor(o16a[r], msk);
  size_t obase = ((size_t)sp * NHEAD + h) * SS;
#pragma unroll
  for (int r = 0; r < 4; r++) {
    int q = q0 + w * 16 + quad * 4 + r;
    if (q < SS) {
      opart[(obase + q) * HD + col] = oacc[r];
      if (col == 0) {
        opart[(obase + q) * HD + 16] = o16a[r];
        mpart[obase + q] = mreg[r];
        lpart[obase + q] = lreg[r];
      }
    }
  }
}

__global__ __launch_bounds__(256) void attn_combine_kernel(
    const float* __restrict__ opart, const float* __restrict__ mpart,
    const float* __restrict__ lpart, float* __restrict__ o) {
  int idx = blockIdx.x * 256 + threadIdx.x;
  if (idx >= SS * DD) return;
  int q = idx / DD, rem = idx % DD;
  int h = rem / HD, d = rem % HD;
  float m[NSPLIT], l[NSPLIT];
  float M = -1e30f;
  for (int s = 0; s < NSPLIT; s++) {
    m[s] = mpart[((size_t)s * NHEAD + h) * SS + q];
    l[s] = lpart[((size_t)s * NHEAD + h) * SS + q];
    M = fmaxf(M, m[s]);
  }
  float L = 0.f, O = 0.f;
  for (int s = 0; s < NSPLIT; s++) {
    float c = __expf(m[s] - M);
    L += l[s] * c;
    O += opart[(((size_t)s * NHEAD + h) * SS + q) * HD + d] * c;
  }
  o[(size_t)q * DD + rem] = O / L;
}

// ---------------- out_proj + residual + LN1 ----------------
__global__ __launch_bounds__(256) void proj_ln1_kernel(
    const float* __restrict__ o, const float* __restrict__ opw, const float* __restrict__ opb,
    const float* __restrict__ g, const float* __restrict__ b, float* __restrict__ x) {
  __shared__ float sw[DD * DD];
  __shared__ float so[32][DD];
  __shared__ float sy[32][35];
  int t = threadIdx.x;
  int r0 = blockIdx.x * 32;
  int nr = min(32, SS - r0);
  for (int i = t; i < DD * DD; i += 256) sw[i] = opw[i];
  for (int i = t; i < nr * DD; i += 256) so[i / DD][i % DD] = o[(size_t)r0 * DD + i];
  __syncthreads();
  for (int idx = t; idx < nr * DD; idx += 256) {
    int r = idx / DD, d = idx % DD;
    float acc = opb[d];
    for (int k = 0; k < DD; k++) acc += so[r][k] * sw[d * DD + k];
    sy[r][d] = acc + x[(size_t)(r0 + r) * DD + d];
  }
  __syncthreads();
  if (t < nr) {
    float m = 0.f;
    for (int d = 0; d < DD; d++) m += sy[t][d];
    m *= (1.f / DD);
    float v = 0.f;
    for (int d = 0; d < DD; d++) { float z = sy[t][d] - m; v += z * z; }
    v *= (1.f / DD);
    float rs = rsqrtf(v + EPSF);
    for (int d = 0; d < DD; d++)
      x[(size_t)(r0 + t) * DD + d] = (sy[t][d] - m) * rs * g[d] + b[d];
  }
}

// ---------------- weight prep for FF ----------------
__global__ __launch_bounds__(256) void wprep_kernel(
    const float* __restrict__ w1, const float* __restrict__ w2,
    unsigned short* __restrict__ w1p, unsigned short* __restrict__ w2p) {
  int i = blockIdx.x * 256 + threadIdx.x;
  if (i < FF * 64) {
    int f = i >> 6, k = i & 63;
    w1p[i] = (k < DD) ? f2b(w1[f * DD + k]) : (unsigned short)0;
  } else {
    int j = i - FF * 64;
    if (j < 48 * FF) {
      int d = j >> 11, kk = j & 2047;
      w2p[j] = (d < DD) ? f2b(w2[d * FF + kk]) : (unsigned short)0;
    }
  }
}

// ---------------- MFMA FF + residual + LN2 ----------------
__global__ __launch_bounds__(256) void ff_mfma_kernel(
    float* __restrict__ x, const unsigned short* __restrict__ w1p,
    const unsigned short* __restrict__ w2p, const float* __restrict__ b1g,
    const float* __restrict__ b2g, const float* __restrict__ g,
    const float* __restrict__ bb) {
  __shared__ __align__(16) unsigned short sxA[32 * 72];
  __shared__ float sxF[32][35];
  __shared__ __align__(16) unsigned short hs[32 * 136];
  __shared__ float yred[32 * 49];
  int t = threadIdx.x;
  int w = t >> 6, lane = t & 63, quad = lane >> 4, col = lane & 15;
  int m0 = (w & 1) * 16, half = w >> 1;
  int r0 = blockIdx.x * 32;
  int nr = min(32, SS - r0);

  for (int i = t; i < 32 * 72; i += 256) sxA[i] = 0;
  for (int i = t; i < 32 * 35; i += 256) ((float*)sxF)[i] = 0.f;
  __syncthreads();
  for (int i = t; i < nr * DD; i += 256) {
    int r = i / DD, d = i % DD;
    float v = x[(size_t)(r0 + r) * DD + d];
    sxF[r][d] = v;
    sxA[r * 72 + d] = f2b(v);
  }
  __syncthreads();

  bf16x8 a0 = *(const bf16x8*)&sxA[(m0 + col) * 72 + quad * 8];
  bf16x8 a1 = *(const bf16x8*)&sxA[(m0 + col) * 72 + 32 + quad * 8];
  f32x4 acc3[3];
  for (int nt = 0; nt < 3; nt++) acc3[nt] = (f32x4){0.f, 0.f, 0.f, 0.f};

  for (int kt = 0; kt < 16; kt++) {
    int fbase = kt * 128 + half * 64;
    for (int nt = 0; nt < 4; nt++) {
      int f = fbase + nt * 16 + col;
      bf16x8 bq0 = *(const bf16x8*)&w1p[f * 64 + quad * 8];
      bf16x8 bq1 = *(const bf16x8*)&w1p[f * 64 + 32 + quad * 8];
      f32x4 hacc = {0.f, 0.f, 0.f, 0.f};
      hacc = __builtin_amdgcn_mfma_f32_16x16x32_bf16(a0, bq0, hacc, 0, 0, 0);
      hacc = __builtin_amdgcn_mfma_f32_16x16x32_bf16(a1, bq1, hacc, 0, 0, 0);
      float bias = b1g[f];
      for (int r = 0; r < 4; r++) {
        float hv = fmaxf(hacc[r] + bias, 0.f);
        hs[(m0 + quad * 4 + r) * 136 + half * 64 + nt * 16 + col] = f2b(hv);
      }
    }
    __syncthreads();
    bf16x8 ha0 = *(const bf16x8*)&hs[(m0 + col) * 136 + half * 64 + quad * 8];
    bf16x8 ha1 = *(const bf16x8*)&hs[(m0 + col) * 136 + half * 64 + 32 + quad * 8];
    for (int nt = 0; nt < 3; nt++) {
      const unsigned short* wp = &w2p[(size_t)(nt * 16 + col) * FF + kt * 128 + half * 64];
      bf16x8 wb0 = *(const bf16x8*)&wp[quad * 8];
      bf16x8 wb1 = *(const bf16x8*)&wp[32 + quad * 8];
      acc3[nt] = __builtin_amdgcn_mfma_f32_16x16x32_bf16(ha0, wb0, acc3[nt], 0, 0, 0);
      acc3[nt] = __builtin_amdgcn_mfma_f32_16x16x32_bf16(ha1, wb1, acc3[nt], 0, 0, 0);
    }
    __syncthreads();
  }

  if (half == 1) {
    for (int nt = 0; nt < 3; nt++)
      for (int r = 0; r < 4; r++)
        yred[(m0 + quad * 4 + r) * 49 + nt * 16 + col] = acc3[nt][r];
  }
  __syncthreads();
  if (half == 0) {
    float yv[3][4];
    float s1[4] = {0.f, 0.f, 0.f, 0.f}, s2[4] = {0.f, 0.f, 0.f, 0.f};
    for (int nt = 0; nt < 3; nt++) {
      int d = nt * 16 + col;
      bool valid = d < DD;
      float b2v = valid ? b2g[d] : 0.f;
      for (int r = 0; r < 4; r++) {
        int row = m0 + quad * 4 + r;
        float v = acc3[nt][r] + yred[row * 49 + nt * 16 + col];
        v = valid ? (v + b2v + sxF[row][d]) : 0.f;
        yv[nt][r] = v;
        s1[r] += v;
        s2[r] += v * v;
      }
    }
    for (int msk = 1; msk <= 8; msk <<= 1)
      for (int r = 0; r < 4; r++) {
        s1[r] += __shfl_xor(s1[r], msk);
        s2[r] += __shfl_xor(s2[r], msk);
      }
    for (int r = 0; r < 4; r++) {
      int row = m0 + quad * 4 + r;
      if (row >= nr) continue;
      float mean = s1[r] * (1.f / DD);
      float var = s2[r] * (1.f / DD) - mean * mean;
      float rs = rsqrtf(var + EPSF);
      for (int nt = 0; nt < 3; nt++) {
        int d = nt * 16 + col;
        if (d < DD)
          x[(size_t)(r0 + row) * DD + d] = (yv[nt][r] - mean) * rs * g[d] + bb[d];
      }
    }
  }
}

// ---------------- final ----------------
__global__ __launch_bounds__(64) void final_kernel(
    const float* __restrict__ x, const int* __restrict__ aidx, float* __restrict__ out) {
  int d = threadIdx.x;
  if (d >= DD) return;
  int start = (*aidx) * HW;
  float acc = 0.f;
  for (int j = 0; j < HW; j++) acc += x[(size_t)(start + j) * DD + d];
  out[d] = acc * (1.f / HW);
}

extern "C" void kernel_launch(void* const* d_in, const int* in_sizes, int n_in,
                              void* d_out, int out_size, void* d_ws, size_t ws_size,
                              hipStream_t stream) {
  const float* obs = (const float*)d_in[0];
  const float* c1w = (const float*)d_in[1];
  const float* c1b = (const float*)d_in[2];
  const float* c2w = (const float*)d_in[3];
  const float* c2b = (const float*)d_in[4];
  const float* ipw = (const float*)d_in[5];
  const float* ipb = (const float*)d_in[6];
  const float* opw = (const float*)d_in[7];
  const float* opb = (const float*)d_in[8];
  const float* l1w = (const float*)d_in[9];
  const float* l1b = (const float*)d_in[10];
  const float* l2w = (const float*)d_in[11];
  const float* l2b = (const float*)d_in[12];
  const float* g1 = (const float*)d_in[13];
  const float* b1 = (const float*)d_in[14];
  const float* g2 = (const float*)d_in[15];
  const float* b2 = (const float*)d_in[16];
  float* out = (float*)d_out;

  float* ws = (float*)d_ws;
  size_t off = 0;
  float* x     = ws + off; off += SS * DD;
  float* qkv   = ws + off; off += SS * 102;
  float* o     = ws + off; off += SS * DD;
  float* cell  = ws + off; off += HW * CC;
  int*   aidx  = (int*)(ws + off); off += 1;
  size_t opart_off = off;
  float* opart = ws + off; off += (size_t)NSPLIT * NHEAD * SS * HD;
  float* mpart = ws + off; off += (size_t)NSPLIT * NHEAD * SS;
  float* lpart = ws + off; off += (size_t)NSPLIT * NHEAD * SS;
  off = (off + 3) & ~(size_t)3;  // 16B align
  unsigned short* kfp = (unsigned short*)(ws + off); off += (NHEAD * NTILES * 8 * 512) / 2;
  unsigned short* vfp = (unsigned short*)(ws + off); off += (NHEAD * NTILES * 4 * 512) / 2;
  float* v16 = ws + off; off += NHEAD * NTILES * 128;
  // FF weight buffers overlay opart (dead during FF phase)
  size_t woff = (opart_off + 3) & ~(size_t)3;
  unsigned short* w1p = (unsigned short*)(ws + woff);
  unsigned short* w2p = (unsigned short*)(ws + woff + FF * 32);

  prep_kernel<<<1, 256, 0, stream>>>(obs, c1w, c1b, c2w, c2b, cell, aidx);
  tokens_kernel<<<(SS + 255) / 256, 256, 0, stream>>>(cell, x);

  const int qkv_blocks = (SS + 63) / 64;
  const int row_blocks = (SS + 31) / 32;
  const int q64_blocks = (SS + QB - 1) / QB;  // 103
  const int comb_blocks = (SS * DD + 255) / 256;
  const int kvprep_elems = NHEAD * NTILES * (8 * 512 + 4 * 512 + 128);
  const int kvprep_blocks = (kvprep_elems + 255) / 256;
  const int wprep_blocks = (FF * 64 + 48 * FF + 255) / 256;
  for (int l = 0; l < 2; l++) {
    qkv_kernel<<<qkv_blocks, 256, 0, stream>>>(
        x, ipw + (size_t)l * 102 * DD, ipb + (size_t)l * 102, qkv);
    kvprep_kernel<<<kvprep_blocks, 256, 0, stream>>>(qkv, kfp, vfp, v16);
    dim3 ag(q64_blocks, NHEAD, NSPLIT);
    attn_split_kernel<<<ag, 256, 0, stream>>>(qkv, kfp, vfp, v16, opart, mpart, lpart);
    attn_combine_kernel<<<comb_blocks, 256, 0, stream>>>(opart, mpart, lpart, o);
    proj_ln1_kernel<<<row_blocks, 256, 0, stream>>>(
        o, opw + (size_t)l * DD * DD, opb + (size_t)l * DD,
        g1 + (size_t)l * DD, b1 + (size_t)l * DD, x);
    wprep_kernel<<<wprep_blocks, 256, 0, stream>>>(
        l1w + (size_t)l * FF * DD, l2w + (size_t)l * DD * FF, w1p, w2p);
    ff_mfma_kernel<<<row_blocks, 256, 0, stream>>>(
        x, w1p, w2p, l1b + (size_t)l * FF,
        l2b + (size_t)l * DD, g2 + (size_t)l * DD, b2 + (size_t)l * DD);
  }
  final_kernel<<<1, 64, 0, stream>>>(x, aidx, out);
}

// Round 6
// 398.009 us; speedup vs baseline: 7.4160x; 1.1046x over previous
//
#include <hip/hip_runtime.h>
#include <hip/hip_bf16.h>

#define HH 9
#define WW 9
#define HW 81
#define CC 16
#define DD 34
#define SS 6561
#define NHEAD 2
#define HD 17
#define FF 2048
#define EPSF 1e-5f

#define NSPLIT 4
#define NTILES 52
#define TPS 13
#define QB 64

typedef __attribute__((ext_vector_type(8))) short bf16x8;
typedef __attribute__((ext_vector_type(4))) float f32x4;

__device__ __forceinline__ unsigned short f2b(float f) {
  unsigned int u = __float_as_uint(f);
  u += 0x7fffu + ((u >> 16) & 1u);
  return (unsigned short)(u >> 16);
}

// ---------------- conv1 + conv2 + argmax (all operands LDS-staged) ----------------
__global__ __launch_bounds__(256) void prep_kernel(
    const float* __restrict__ obs, const float* __restrict__ w1, const float* __restrict__ b1,
    const float* __restrict__ w2, const float* __restrict__ b2,
    float* __restrict__ cell, int* __restrict__ aidx) {
  __shared__ float s_obs[2 * HW];      // 162
  __shared__ float s_w1[16 * 2 * 9];   // 288
  __shared__ float s_w2[16 * 16 * 9];  // 2304
  __shared__ float s_b1[16], s_b2[16];
  __shared__ float y1[CC][HW];
  int t = threadIdx.x;
  for (int i = t; i < 2 * HW; i += 256) s_obs[i] = obs[i];
  for (int i = t; i < 288; i += 256) s_w1[i] = w1[i];
  for (int i = t; i < 2304; i += 256) s_w2[i] = w2[i];
  if (t < 16) { s_b1[t] = b1[t]; s_b2[t] = b2[t]; }
  __syncthreads();
  if (t == 0) {
    int best = 0; float bv = s_obs[0];
    for (int i = 1; i < HW; i++) { float v = s_obs[i]; if (v > bv) { bv = v; best = i; } }
    *aidx = best;
  }
  for (int idx = t; idx < CC * HW; idx += 256) {
    int c = idx / HW, p = idx % HW;
    int i = p / WW, j = p % WW;
    float acc = s_b1[c];
    for (int ic = 0; ic < 2; ic++)
      for (int di = 0; di < 3; di++) {
        int ii = i + di - 1; if (ii < 0 || ii >= HH) continue;
        for (int dj = 0; dj < 3; dj++) {
          int jj = j + dj - 1; if (jj < 0 || jj >= WW) continue;
          acc += s_obs[ic * HW + ii * WW + jj] * s_w1[((c * 2 + ic) * 3 + di) * 3 + dj];
        }
      }
    y1[c][p] = fmaxf(acc, 0.f);
  }
  __syncthreads();
  for (int idx = t; idx < CC * HW; idx += 256) {
    int c = idx / HW, p = idx % HW;
    int i = p / WW, j = p % WW;
    float acc = s_b2[c];
    for (int ic = 0; ic < CC; ic++)
      for (int di = 0; di < 3; di++) {
        int ii = i + di - 1; if (ii < 0 || ii >= HH) continue;
        for (int dj = 0; dj < 3; dj++) {
          int jj = j + dj - 1; if (jj < 0 || jj >= WW) continue;
          acc += y1[ic][ii * WW + jj] * s_w2[((c * CC + ic) * 3 + di) * 3 + dj];
        }
      }
    cell[p * CC + c] = fmaxf(acc, 0.f);
  }
}

// ---------------- token build: one element per thread, coalesced ----------------
__global__ __launch_bounds__(256) void tokens_kernel(
    const float* __restrict__ cell, float* __restrict__ x) {
  int idx = blockIdx.x * 256 + threadIdx.x;
  if (idx >= SS * DD) return;
  int row = idx / DD, d = idx - row * DD;
  int i = row / HW, j = row - i * HW;
  float v;
  if (d < CC) v = cell[i * CC + d];
  else if (d < 2 * CC) v = cell[j * CC + (d - CC)];
  else if (d == 32) v = (float)((i / WW) - (j / WW)) * 0.25f;
  else v = (float)((i % WW) - (j % WW)) * 0.25f;
  x[idx] = v;
}

// ---------------- qkv projection ----------------
__global__ __launch_bounds__(256) void qkv_kernel(
    const float* __restrict__ x, const float* __restrict__ ipw,
    const float* __restrict__ ipb, float* __restrict__ qkv) {
  __shared__ float sw[3 * DD * DD];
  __shared__ float sb[3 * DD];
  __shared__ float sx[64][DD];
  int t = threadIdx.x;
  int row0 = blockIdx.x * 64;
  int nrows = min(64, SS - row0);
  for (int i = t; i < 3 * DD * DD; i += 256) sw[i] = ipw[i];
  for (int i = t; i < 3 * DD; i += 256) sb[i] = ipb[i];
  for (int i = t; i < nrows * DD; i += 256) sx[i / DD][i % DD] = x[(size_t)row0 * DD + i];
  __syncthreads();
  for (int idx = t; idx < nrows * 102; idx += 256) {
    int r = idx / 102, o = idx % 102;
    float acc = sb[o];
    const float* wr = &sw[o * DD];
    for (int d = 0; d < DD; d++) acc += sx[r][d] * wr[d];
    qkv[(size_t)(row0 + r) * 102 + o] = acc;
  }
}

// ---------------- K/V fragment pre-pack (per layer) ----------------
__global__ __launch_bounds__(256) void kvprep_kernel(
    const float* __restrict__ qkv, unsigned short* __restrict__ kfp,
    unsigned short* __restrict__ vfp, float* __restrict__ v16) {
  const int NK = NHEAD * NTILES * 8 * 512;
  const int NV = NHEAD * NTILES * 4 * 512;
  const int NV16 = NHEAD * NTILES * 128;
  int i = blockIdx.x * 256 + threadIdx.x;
  if (i < NK) {
    int j = i & 7, l = (i >> 3) & 63, nt = (i >> 9) & 7, rest = i >> 12;
    int T = rest % NTILES, h = rest / NTILES;
    int colf = l & 15, quadf = l >> 4;
    int tok = T * 128 + colf * 8 + nt;
    int d = quadf * 8 + j;
    unsigned short v = 0;
    if (tok < SS && d < HD) v = f2b(qkv[(size_t)tok * 102 + DD + h * HD + d]);
    kfp[i] = v;
  } else if (i < NK + NV) {
    int ii = i - NK;
    int j = ii & 7, l = (ii >> 3) & 63, c = (ii >> 9) & 3, rest = ii >> 11;
    int T = rest % NTILES, h = rest / NTILES;
    int colf = l & 15, quadf = l >> 4;
    int tok = T * 128 + c * 32 + quadf * 8 + j;
    unsigned short v = 0;
    if (tok < SS) v = f2b(qkv[(size_t)tok * 102 + 2 * DD + h * HD + colf]);
    vfp[ii] = v;
  } else {
    int ii = i - NK - NV;
    if (ii < NV16) {
      int tl = ii % (NTILES * 128), h = ii / (NTILES * 128);
      v16[ii] = (tl < SS) ? qkv[(size_t)tl * 102 + 2 * DD + h * HD + 16] : 0.f;
    }
  }
}

// ---------------- split-K flash attention: barrier-free, frag-direct ----------------
__global__ __launch_bounds__(256) void attn_split_kernel(
    const float* __restrict__ qkv, const unsigned short* __restrict__ kfp,
    const unsigned short* __restrict__ vfp, const float* __restrict__ v16,
    float* __restrict__ opart, float* __restrict__ mpart, float* __restrict__ lpart) {
  __shared__ __align__(16) unsigned short scb[4][16 * 136];
  int t = threadIdx.x, w = t >> 6, lane = t & 63, quad = lane >> 4, col = lane & 15;
  int h = blockIdx.y, sp = blockIdx.z;
  int q0 = blockIdx.x * QB;
  const float scale = 0.24253562503633297f;
  const unsigned short* kf = kfp + (size_t)h * (NTILES * 8 * 512);
  const unsigned short* vf = vfp + (size_t)h * (NTILES * 4 * 512);
  const float* v16h = v16 + (size_t)h * (NTILES * 128);
  unsigned short* myscb = &scb[w][0];

  int mq = q0 + w * 16 + col;
  int qc = mq < SS ? mq : SS - 1;
  bf16x8 aq;
#pragma unroll
  for (int j = 0; j < 8; j++) {
    int d = quad * 8 + j;
    aq[j] = (short)((d < HD) ? f2b(qkv[(size_t)qc * 102 + h * HD + d] * scale) : 0);
  }

  f32x4 oacc = {0.f, 0.f, 0.f, 0.f};
  float o16a[4] = {0.f, 0.f, 0.f, 0.f};
  float mreg[4] = {-1e30f, -1e30f, -1e30f, -1e30f};
  float lreg[4] = {0.f, 0.f, 0.f, 0.f};

  int tile0 = sp * TPS, tile1 = min(tile0 + TPS, NTILES);
  for (int tile = tile0; tile < tile1; tile++) {
    int k0 = tile * 128;
    const unsigned short* kt = kf + (size_t)tile * (8 * 512);
    f32x4 s[8];
#pragma unroll
    for (int nt = 0; nt < 8; nt++) {
      bf16x8 kb = *(const bf16x8*)(kt + nt * 512 + lane * 8);
      f32x4 z = {0.f, 0.f, 0.f, 0.f};
      s[nt] = __builtin_amdgcn_mfma_f32_16x16x32_bf16(aq, kb, z, 0, 0, 0);
    }
    if (k0 + 128 > SS) {
#pragma unroll
      for (int nt = 0; nt < 8; nt++)
        if (k0 + col * 8 + nt >= SS) {
          s[nt][0] = -1e30f; s[nt][1] = -1e30f; s[nt][2] = -1e30f; s[nt][3] = -1e30f;
        }
    }
    float pm[4];
#pragma unroll
    for (int r = 0; r < 4; r++) {
      pm[r] = fmaxf(fmaxf(fmaxf(s[0][r], s[1][r]), fmaxf(s[2][r], s[3][r])),
                    fmaxf(fmaxf(s[4][r], s[5][r]), fmaxf(s[6][r], s[7][r])));
    }
#pragma unroll
    for (int msk = 1; msk <= 8; msk <<= 1)
#pragma unroll
      for (int r = 0; r < 4; r++) pm[r] = fmaxf(pm[r], __shfl_xor(pm[r], msk));
    float al[4], ps[4];
#pragma unroll
    for (int r = 0; r < 4; r++) {
      float mn = fmaxf(mreg[r], pm[r]);
      al[r] = __expf(mreg[r] - mn);
      mreg[r] = mn;
      ps[r] = 0.f;
    }
#pragma unroll
    for (int r = 0; r < 4; r++) {
      bf16x8 pv;
#pragma unroll
      for (int nt = 0; nt < 8; nt++) {
        float p = __expf(s[nt][r] - mreg[r]);
        s[nt][r] = p;
        ps[r] += p;
        pv[nt] = (short)f2b(p);
      }
      *(bf16x8*)(myscb + (quad * 4 + r) * 136 + col * 8) = pv;
    }
#pragma unroll
    for (int msk = 1; msk <= 8; msk <<= 1)
#pragma unroll
      for (int r = 0; r < 4; r++) ps[r] += __shfl_xor(ps[r], msk);
#pragma unroll
    for (int r = 0; r < 4; r++) lreg[r] = lreg[r] * al[r] + ps[r];
    f32x4 va = *(const f32x4*)(v16h + k0 + col * 8);
    f32x4 vb4 = *(const f32x4*)(v16h + k0 + col * 8 + 4);
#pragma unroll
    for (int r = 0; r < 4; r++) {
      o16a[r] = o16a[r] * al[r]
              + s[0][r] * va[0] + s[1][r] * va[1] + s[2][r] * va[2] + s[3][r] * va[3]
              + s[4][r] * vb4[0] + s[5][r] * vb4[1] + s[6][r] * vb4[2] + s[7][r] * vb4[3];
      oacc[r] *= al[r];
    }
    const unsigned short* vt = vf + (size_t)tile * (4 * 512);
#pragma unroll
    for (int c = 0; c < 4; c++) {
      bf16x8 pa = *(const bf16x8*)(myscb + col * 136 + c * 32 + quad * 8);
      bf16x8 vbf = *(const bf16x8*)(vt + c * 512 + lane * 8);
      oacc = __builtin_amdgcn_mfma_f32_16x16x32_bf16(pa, vbf, oacc, 0, 0, 0);
    }
  }
#pragma unroll
  for (int msk = 1; msk <= 8; msk <<= 1)
#pragma unroll
    for (int r = 0; r < 4; r++) o16a[r] += __shfl_xor(o16a[r], msk);
  size_t obase = ((size_t)sp * NHEAD + h) * SS;
#pragma unroll
  for (int r = 0; r < 4; r++) {
    int q = q0 + w * 16 + quad * 4 + r;
    if (q < SS) {
      opart[(obase + q) * HD + col] = oacc[r];
      if (col == 0) {
        opart[(obase + q) * HD + 16] = o16a[r];
        mpart[obase + q] = mreg[r];
        lpart[obase + q] = lreg[r];
      }
    }
  }
}

// ---------------- combine + out_proj + residual + LN1 (fused) ----------------
__global__ __launch_bounds__(256) void proj_ln1_kernel(
    const float* __restrict__ opart, const float* __restrict__ mpart,
    const float* __restrict__ lpart, const float* __restrict__ opw,
    const float* __restrict__ opb, const float* __restrict__ g,
    const float* __restrict__ b, float* __restrict__ x) {
  __shared__ float sw[DD * DD];
  __shared__ float so[32][DD];
  __shared__ float sy[32][35];
  int t = threadIdx.x;
  int r0 = blockIdx.x * 32;
  int nr = min(32, SS - r0);
  for (int i = t; i < DD * DD; i += 256) sw[i] = opw[i];
  for (int i = t; i < nr * DD; i += 256) {
    int r = i / DD, rem = i - r * DD;
    int q = r0 + r;
    int h = rem / HD, d = rem - h * HD;
    float mm[NSPLIT], ll[NSPLIT];
    float M = -1e30f;
#pragma unroll
    for (int s = 0; s < NSPLIT; s++) {
      mm[s] = mpart[((size_t)s * NHEAD + h) * SS + q];
      ll[s] = lpart[((size_t)s * NHEAD + h) * SS + q];
      M = fmaxf(M, mm[s]);
    }
    float L = 0.f, O = 0.f;
#pragma unroll
    for (int s = 0; s < NSPLIT; s++) {
      float c = __expf(mm[s] - M);
      L += ll[s] * c;
      O += opart[(((size_t)s * NHEAD + h) * SS + q) * HD + d] * c;
    }
    so[r][rem] = O / L;
  }
  __syncthreads();
  for (int idx = t; idx < nr * DD; idx += 256) {
    int r = idx / DD, d = idx % DD;
    float acc = opb[d];
    for (int k = 0; k < DD; k++) acc += so[r][k] * sw[d * DD + k];
    sy[r][d] = acc + x[(size_t)(r0 + r) * DD + d];
  }
  __syncthreads();
  int row = t >> 3, s8 = t & 7;
  if (row < nr) {
    float s1 = 0.f, s2 = 0.f;
    for (int d = s8; d < DD; d += 8) { float v = sy[row][d]; s1 += v; s2 += v * v; }
    s1 += __shfl_xor(s1, 1); s2 += __shfl_xor(s2, 1);
    s1 += __shfl_xor(s1, 2); s2 += __shfl_xor(s2, 2);
    s1 += __shfl_xor(s1, 4); s2 += __shfl_xor(s2, 4);
    float mean = s1 * (1.f / DD);
    float var = s2 * (1.f / DD) - mean * mean;
    float rs = rsqrtf(var + EPSF);
    for (int d = s8; d < DD; d += 8)
      x[(size_t)(r0 + row) * DD + d] = (sy[row][d] - mean) * rs * g[d] + b[d];
  }
}

// ---------------- weight prep for FF ----------------
__global__ __launch_bounds__(256) void wprep_kernel(
    const float* __restrict__ w1, const float* __restrict__ w2,
    unsigned short* __restrict__ w1p, unsigned short* __restrict__ w2p) {
  int i = blockIdx.x * 256 + threadIdx.x;
  if (i < FF * 64) {
    int f = i >> 6, k = i & 63;
    w1p[i] = (k < DD) ? f2b(w1[f * DD + k]) : (unsigned short)0;
  } else {
    int j = i - FF * 64;
    if (j < 48 * FF) {
      int d = j >> 11, kk = j & 2047;
      w2p[j] = (d < DD) ? f2b(w2[d * FF + kk]) : (unsigned short)0;
    }
  }
}

// ---------------- MFMA FF + residual + LN2 ----------------
__global__ __launch_bounds__(256) void ff_mfma_kernel(
    float* __restrict__ x, const unsigned short* __restrict__ w1p,
    const unsigned short* __restrict__ w2p, const float* __restrict__ b1g,
    const float* __restrict__ b2g, const float* __restrict__ g,
    const float* __restrict__ bb) {
  __shared__ __align__(16) unsigned short sxA[32 * 72];
  __shared__ float sxF[32][35];
  __shared__ __align__(16) unsigned short hs[32 * 136];
  __shared__ float yred[32 * 49];
  int t = threadIdx.x;
  int w = t >> 6, lane = t & 63, quad = lane >> 4, col = lane & 15;
  int m0 = (w & 1) * 16, half = w >> 1;
  int r0 = blockIdx.x * 32;
  int nr = min(32, SS - r0);

  for (int i = t; i < 32 * 72; i += 256) sxA[i] = 0;
  for (int i = t; i < 32 * 35; i += 256) ((float*)sxF)[i] = 0.f;
  __syncthreads();
  for (int i = t; i < nr * DD; i += 256) {
    int r = i / DD, d = i % DD;
    float v = x[(size_t)(r0 + r) * DD + d];
    sxF[r][d] = v;
    sxA[r * 72 + d] = f2b(v);
  }
  __syncthreads();

  bf16x8 a0 = *(const bf16x8*)&sxA[(m0 + col) * 72 + quad * 8];
  bf16x8 a1 = *(const bf16x8*)&sxA[(m0 + col) * 72 + 32 + quad * 8];
  f32x4 acc3[3];
  for (int nt = 0; nt < 3; nt++) acc3[nt] = (f32x4){0.f, 0.f, 0.f, 0.f};

  for (int kt = 0; kt < 16; kt++) {
    int fbase = kt * 128 + half * 64;
    for (int nt = 0; nt < 4; nt++) {
      int f = fbase + nt * 16 + col;
      bf16x8 bq0 = *(const bf16x8*)&w1p[f * 64 + quad * 8];
      bf16x8 bq1 = *(const bf16x8*)&w1p[f * 64 + 32 + quad * 8];
      f32x4 hacc = {0.f, 0.f, 0.f, 0.f};
      hacc = __builtin_amdgcn_mfma_f32_16x16x32_bf16(a0, bq0, hacc, 0, 0, 0);
      hacc = __builtin_amdgcn_mfma_f32_16x16x32_bf16(a1, bq1, hacc, 0, 0, 0);
      float bias = b1g[f];
      for (int r = 0; r < 4; r++) {
        float hv = fmaxf(hacc[r] + bias, 0.f);
        hs[(m0 + quad * 4 + r) * 136 + half * 64 + nt * 16 + col] = f2b(hv);
      }
    }
    __syncthreads();
    bf16x8 ha0 = *(const bf16x8*)&hs[(m0 + col) * 136 + half * 64 + quad * 8];
    bf16x8 ha1 = *(const bf16x8*)&hs[(m0 + col) * 136 + half * 64 + 32 + quad * 8];
    for (int nt = 0; nt < 3; nt++) {
      const unsigned short* wp = &w2p[(size_t)(nt * 16 + col) * FF + kt * 128 + half * 64];
      bf16x8 wb0 = *(const bf16x8*)&wp[quad * 8];
      bf16x8 wb1 = *(const bf16x8*)&wp[32 + quad * 8];
      acc3[nt] = __builtin_amdgcn_mfma_f32_16x16x32_bf16(ha0, wb0, acc3[nt], 0, 0, 0);
      acc3[nt] = __builtin_amdgcn_mfma_f32_16x16x32_bf16(ha1, wb1, acc3[nt], 0, 0, 0);
    }
    __syncthreads();
  }

  if (half == 1) {
    for (int nt = 0; nt < 3; nt++)
      for (int r = 0; r < 4; r++)
        yred[(m0 + quad * 4 + r) * 49 + nt * 16 + col] = acc3[nt][r];
  }
  __syncthreads();
  if (half == 0) {
    float yv[3][4];
    float s1[4] = {0.f, 0.f, 0.f, 0.f}, s2[4] = {0.f, 0.f, 0.f, 0.f};
    for (int nt = 0; nt < 3; nt++) {
      int d = nt * 16 + col;
      bool valid = d < DD;
      float b2v = valid ? b2g[d] : 0.f;
      for (int r = 0; r < 4; r++) {
        int row = m0 + quad * 4 + r;
        float v = acc3[nt][r] + yred[row * 49 + nt * 16 + col];
        v = valid ? (v + b2v + sxF[row][d]) : 0.f;
        yv[nt][r] = v;
        s1[r] += v;
        s2[r] += v * v;
      }
    }
    for (int msk = 1; msk <= 8; msk <<= 1)
      for (int r = 0; r < 4; r++) {
        s1[r] += __shfl_xor(s1[r], msk);
        s2[r] += __shfl_xor(s2[r], msk);
      }
    for (int r = 0; r < 4; r++) {
      int row = m0 + quad * 4 + r;
      if (row >= nr) continue;
      float mean = s1[r] * (1.f / DD);
      float var = s2[r] * (1.f / DD) - mean * mean;
      float rs = rsqrtf(var + EPSF);
      for (int nt = 0; nt < 3; nt++) {
        int d = nt * 16 + col;
        if (d < DD)
          x[(size_t)(r0 + row) * DD + d] = (yv[nt][r] - mean) * rs * g[d] + bb[d];
      }
    }
  }
}

// ---------------- final ----------------
__global__ __launch_bounds__(64) void final_kernel(
    const float* __restrict__ x, const int* __restrict__ aidx, float* __restrict__ out) {
  int d = threadIdx.x;
  if (d >= DD) return;
  int start = (*aidx) * HW;
  float acc = 0.f;
  for (int j = 0; j < HW; j++) acc += x[(size_t)(start + j) * DD + d];
  out[d] = acc * (1.f / HW);
}

extern "C" void kernel_launch(void* const* d_in, const int* in_sizes, int n_in,
                              void* d_out, int out_size, void* d_ws, size_t ws_size,
                              hipStream_t stream) {
  const float* obs = (const float*)d_in[0];
  const float* c1w = (const float*)d_in[1];
  const float* c1b = (const float*)d_in[2];
  const float* c2w = (const float*)d_in[3];
  const float* c2b = (const float*)d_in[4];
  const float* ipw = (const float*)d_in[5];
  const float* ipb = (const float*)d_in[6];
  const float* opw = (const float*)d_in[7];
  const float* opb = (const float*)d_in[8];
  const float* l1w = (const float*)d_in[9];
  const float* l1b = (const float*)d_in[10];
  const float* l2w = (const float*)d_in[11];
  const float* l2b = (const float*)d_in[12];
  const float* g1 = (const float*)d_in[13];
  const float* b1 = (const float*)d_in[14];
  const float* g2 = (const float*)d_in[15];
  const float* b2 = (const float*)d_in[16];
  float* out = (float*)d_out;

  float* ws = (float*)d_ws;
  size_t off = 0;
  float* x     = ws + off; off += SS * DD;
  float* qkv   = ws + off; off += SS * 102;
  float* o     = ws + off; off += SS * DD;  // dead (kept for layout stability)
  (void)o;
  float* cell  = ws + off; off += HW * CC;
  int*   aidx  = (int*)(ws + off); off += 1;
  size_t opart_off = off;
  float* opart = ws + off; off += (size_t)NSPLIT * NHEAD * SS * HD;
  float* mpart = ws + off; off += (size_t)NSPLIT * NHEAD * SS;
  float* lpart = ws + off; off += (size_t)NSPLIT * NHEAD * SS;
  off = (off + 3) & ~(size_t)3;
  unsigned short* kfp = (unsigned short*)(ws + off); off += (NHEAD * NTILES * 8 * 512) / 2;
  unsigned short* vfp = (unsigned short*)(ws + off); off += (NHEAD * NTILES * 4 * 512) / 2;
  float* v16 = ws + off; off += NHEAD * NTILES * 128;
  size_t woff = (opart_off + 3) & ~(size_t)3;
  unsigned short* w1p = (unsigned short*)(ws + woff);
  unsigned short* w2p = (unsigned short*)(ws + woff + FF * 32);

  prep_kernel<<<1, 256, 0, stream>>>(obs, c1w, c1b, c2w, c2b, cell, aidx);
  tokens_kernel<<<(SS * DD + 255) / 256, 256, 0, stream>>>(cell, x);

  const int qkv_blocks = (SS + 63) / 64;
  const int row_blocks = (SS + 31) / 32;
  const int q64_blocks = (SS + QB - 1) / QB;
  const int kvprep_elems = NHEAD * NTILES * (8 * 512 + 4 * 512 + 128);
  const int kvprep_blocks = (kvprep_elems + 255) / 256;
  const int wprep_blocks = (FF * 64 + 48 * FF + 255) / 256;
  for (int l = 0; l < 2; l++) {
    qkv_kernel<<<qkv_blocks, 256, 0, stream>>>(
        x, ipw + (size_t)l * 102 * DD, ipb + (size_t)l * 102, qkv);
    kvprep_kernel<<<kvprep_blocks, 256, 0, stream>>>(qkv, kfp, vfp, v16);
    dim3 ag(q64_blocks, NHEAD, NSPLIT);
    attn_split_kernel<<<ag, 256, 0, stream>>>(qkv, kfp, vfp, v16, opart, mpart, lpart);
    proj_ln1_kernel<<<row_blocks, 256, 0, stream>>>(
        opart, mpart, lpart, opw + (size_t)l * DD * DD, opb + (size_t)l * DD,
        g1 + (size_t)l * DD, b1 + (size_t)l * DD, x);
    wprep_kernel<<<wprep_blocks, 256, 0, stream>>>(
        l1w + (size_t)l * FF * DD, l2w + (size_t)l * DD * FF, w1p, w2p);
    ff_mfma_kernel<<<row_blocks, 256, 0, stream>>>(
        x, w1p, w2p, l1b + (size_t)l * FF,
        l2b + (size_t)l * DD, g2 + (size_t)l * DD, b2 + (size_t)l * DD);
  }
  final_kernel<<<1, 64, 0, stream>>>(x, aidx, out);
}

// Round 7
// 362.441 us; speedup vs baseline: 8.1438x; 1.0981x over previous
//
#include <hip/hip_runtime.h>
#include <hip/hip_bf16.h>

#define HH 9
#define WW 9
#define HW 81
#define CC 16
#define DD 34
#define SS 6561
#define NHEAD 2
#define HD 17
#define FF 2048
#define EPSF 1e-5f

#define NSPLIT 8
#define NTILES 52
#define QB 64

typedef __attribute__((ext_vector_type(8))) short bf16x8;
typedef __attribute__((ext_vector_type(4))) float f32x4;

__device__ __forceinline__ unsigned short f2b(float f) {
  unsigned int u = __float_as_uint(f);
  u += 0x7fffu + ((u >> 16) & 1u);
  return (unsigned short)(u >> 16);
}

// ---------------- conv1 + conv2 + argmax (LDS-staged) ----------------
__global__ __launch_bounds__(256) void prep_kernel(
    const float* __restrict__ obs, const float* __restrict__ w1, const float* __restrict__ b1,
    const float* __restrict__ w2, const float* __restrict__ b2,
    float* __restrict__ cell, int* __restrict__ aidx) {
  __shared__ float s_obs[2 * HW];
  __shared__ float s_w1[288];
  __shared__ float s_w2[2304];
  __shared__ float s_b1[16], s_b2[16];
  __shared__ float y1[CC][HW];
  int t = threadIdx.x;
  for (int i = t; i < 2 * HW; i += 256) s_obs[i] = obs[i];
  for (int i = t; i < 288; i += 256) s_w1[i] = w1[i];
  for (int i = t; i < 2304; i += 256) s_w2[i] = w2[i];
  if (t < 16) { s_b1[t] = b1[t]; s_b2[t] = b2[t]; }
  __syncthreads();
  if (t == 0) {
    int best = 0; float bv = s_obs[0];
    for (int i = 1; i < HW; i++) { float v = s_obs[i]; if (v > bv) { bv = v; best = i; } }
    *aidx = best;
  }
  for (int idx = t; idx < CC * HW; idx += 256) {
    int c = idx / HW, p = idx % HW;
    int i = p / WW, j = p % WW;
    float acc = s_b1[c];
    for (int ic = 0; ic < 2; ic++)
      for (int di = 0; di < 3; di++) {
        int ii = i + di - 1; if (ii < 0 || ii >= HH) continue;
        for (int dj = 0; dj < 3; dj++) {
          int jj = j + dj - 1; if (jj < 0 || jj >= WW) continue;
          acc += s_obs[ic * HW + ii * WW + jj] * s_w1[((c * 2 + ic) * 3 + di) * 3 + dj];
        }
      }
    y1[c][p] = fmaxf(acc, 0.f);
  }
  __syncthreads();
  for (int idx = t; idx < CC * HW; idx += 256) {
    int c = idx / HW, p = idx % HW;
    int i = p / WW, j = p % WW;
    float acc = s_b2[c];
    for (int ic = 0; ic < CC; ic++)
      for (int di = 0; di < 3; di++) {
        int ii = i + di - 1; if (ii < 0 || ii >= HH) continue;
        for (int dj = 0; dj < 3; dj++) {
          int jj = j + dj - 1; if (jj < 0 || jj >= WW) continue;
          acc += y1[ic][ii * WW + jj] * s_w2[((c * CC + ic) * 3 + di) * 3 + dj];
        }
      }
    cell[p * CC + c] = fmaxf(acc, 0.f);
  }
}

// ---------------- token build ----------------
__global__ __launch_bounds__(256) void tokens_kernel(
    const float* __restrict__ cell, float* __restrict__ x) {
  int idx = blockIdx.x * 256 + threadIdx.x;
  if (idx >= SS * DD) return;
  int row = idx / DD, d = idx - row * DD;
  int i = row / HW, j = row - i * HW;
  float v;
  if (d < CC) v = cell[i * CC + d];
  else if (d < 2 * CC) v = cell[j * CC + (d - CC)];
  else if (d == 32) v = (float)((i / WW) - (j / WW)) * 0.25f;
  else v = (float)((i % WW) - (j % WW)) * 0.25f;
  x[idx] = v;
}

// ---------------- per-layer weight pack: ipw, opw, l1w, l2w -> bf16 MFMA-ready ----------------
// ipwp[112][64], opwp[48][64], w1p[2048][64], w2p[48][2048]
__global__ __launch_bounds__(256) void lprep_kernel(
    const float* __restrict__ ipw, const float* __restrict__ opw,
    const float* __restrict__ w1, const float* __restrict__ w2,
    unsigned short* __restrict__ ipwp, unsigned short* __restrict__ opwp,
    unsigned short* __restrict__ w1p, unsigned short* __restrict__ w2p) {
  int i = blockIdx.x * 256 + threadIdx.x;
  if (i < 7168) {
    int n = i >> 6, k = i & 63;
    ipwp[i] = (n < 102 && k < DD) ? f2b(ipw[n * DD + k]) : (unsigned short)0;
  } else if (i < 10240) {
    int ii = i - 7168;
    int n = ii >> 6, k = ii & 63;
    opwp[ii] = (n < DD && k < DD) ? f2b(opw[n * DD + k]) : (unsigned short)0;
  } else if (i < 141312) {
    int ii = i - 10240;
    int f = ii >> 6, k = ii & 63;
    w1p[ii] = (k < DD) ? f2b(w1[f * DD + k]) : (unsigned short)0;
  } else {
    int ii = i - 141312;
    if (ii < 48 * FF) {
      int d = ii >> 11, kk = ii & 2047;
      w2p[ii] = (d < DD) ? f2b(w2[d * FF + kk]) : (unsigned short)0;
    }
  }
}

// ---------------- qkv projection via MFMA: [S,34] @ [102,34]^T + b ----------------
// 32 rows/block, 4 waves: m-tile = w&1, n-half = w>>1 (tiles 0-3 / 4-6 of 7)
__global__ __launch_bounds__(256) void qkv_mfma_kernel(
    const float* __restrict__ x, const unsigned short* __restrict__ ipwp,
    const float* __restrict__ ipb, float* __restrict__ qkv) {
  __shared__ __align__(16) unsigned short sxA[32 * 72];
  int t = threadIdx.x;
  int w = t >> 6, lane = t & 63, quad = lane >> 4, col = lane & 15;
  int m0 = (w & 1) * 16, half = w >> 1;
  int row0 = blockIdx.x * 32;
  int nr = min(32, SS - row0);
  for (int i = t; i < 32 * 72; i += 256) sxA[i] = 0;
  __syncthreads();
  for (int i = t; i < nr * DD; i += 256) {
    int r = i / DD, d = i - r * DD;
    sxA[r * 72 + d] = f2b(x[(size_t)row0 * DD + i]);
  }
  __syncthreads();
  bf16x8 a0 = *(const bf16x8*)&sxA[(m0 + col) * 72 + quad * 8];
  bf16x8 a1 = *(const bf16x8*)&sxA[(m0 + col) * 72 + 32 + quad * 8];
  int ntc = half ? 3 : 4;
  for (int nt2 = 0; nt2 < ntc; nt2++) {
    int nt = half * 4 + nt2;
    int n = nt * 16 + col;
    bf16x8 b0 = *(const bf16x8*)&ipwp[n * 64 + quad * 8];
    bf16x8 b1 = *(const bf16x8*)&ipwp[n * 64 + 32 + quad * 8];
    f32x4 acc = {0.f, 0.f, 0.f, 0.f};
    acc = __builtin_amdgcn_mfma_f32_16x16x32_bf16(a0, b0, acc, 0, 0, 0);
    acc = __builtin_amdgcn_mfma_f32_16x16x32_bf16(a1, b1, acc, 0, 0, 0);
    if (n < 102) {
      float bias = ipb[n];
#pragma unroll
      for (int r = 0; r < 4; r++) {
        int m = m0 + quad * 4 + r;
        if (m < nr) qkv[(size_t)(row0 + m) * 102 + n] = acc[r] + bias;
      }
    }
  }
}

// ---------------- K/V fragment pre-pack ----------------
__global__ __launch_bounds__(256) void kvprep_kernel(
    const float* __restrict__ qkv, unsigned short* __restrict__ kfp,
    unsigned short* __restrict__ vfp, float* __restrict__ v16) {
  const int NK = NHEAD * NTILES * 8 * 512;
  const int NV = NHEAD * NTILES * 4 * 512;
  const int NV16 = NHEAD * NTILES * 128;
  int i = blockIdx.x * 256 + threadIdx.x;
  if (i < NK) {
    int j = i & 7, l = (i >> 3) & 63, nt = (i >> 9) & 7, rest = i >> 12;
    int T = rest % NTILES, h = rest / NTILES;
    int colf = l & 15, quadf = l >> 4;
    int tok = T * 128 + colf * 8 + nt;
    int d = quadf * 8 + j;
    unsigned short v = 0;
    if (tok < SS && d < HD) v = f2b(qkv[(size_t)tok * 102 + DD + h * HD + d]);
    kfp[i] = v;
  } else if (i < NK + NV) {
    int ii = i - NK;
    int j = ii & 7, l = (ii >> 3) & 63, c = (ii >> 9) & 3, rest = ii >> 11;
    int T = rest % NTILES, h = rest / NTILES;
    int colf = l & 15, quadf = l >> 4;
    int tok = T * 128 + c * 32 + quadf * 8 + j;
    unsigned short v = 0;
    if (tok < SS) v = f2b(qkv[(size_t)tok * 102 + 2 * DD + h * HD + colf]);
    vfp[ii] = v;
  } else {
    int ii = i - NK - NV;
    if (ii < NV16) {
      int tl = ii % (NTILES * 128), h = ii / (NTILES * 128);
      v16[ii] = (tl < SS) ? qkv[(size_t)tl * 102 + 2 * DD + h * HD + 16] : 0.f;
    }
  }
}

// ---------------- split-K flash attention (NSPLIT=8, strided tiles) ----------------
__global__ __launch_bounds__(256) void attn_split_kernel(
    const float* __restrict__ qkv, const unsigned short* __restrict__ kfp,
    const unsigned short* __restrict__ vfp, const float* __restrict__ v16,
    float* __restrict__ opart, float* __restrict__ mpart, float* __restrict__ lpart) {
  __shared__ __align__(16) unsigned short scb[4][16 * 136];
  int t = threadIdx.x, w = t >> 6, lane = t & 63, quad = lane >> 4, col = lane & 15;
  int h = blockIdx.y, sp = blockIdx.z;
  int q0 = blockIdx.x * QB;
  const float scale = 0.24253562503633297f;
  const unsigned short* kf = kfp + (size_t)h * (NTILES * 8 * 512);
  const unsigned short* vf = vfp + (size_t)h * (NTILES * 4 * 512);
  const float* v16h = v16 + (size_t)h * (NTILES * 128);
  unsigned short* myscb = &scb[w][0];

  int mq = q0 + w * 16 + col;
  int qc = mq < SS ? mq : SS - 1;
  bf16x8 aq;
#pragma unroll
  for (int j = 0; j < 8; j++) {
    int d = quad * 8 + j;
    aq[j] = (short)((d < HD) ? f2b(qkv[(size_t)qc * 102 + h * HD + d] * scale) : 0);
  }

  f32x4 oacc = {0.f, 0.f, 0.f, 0.f};
  float o16a[4] = {0.f, 0.f, 0.f, 0.f};
  float mreg[4] = {-1e30f, -1e30f, -1e30f, -1e30f};
  float lreg[4] = {0.f, 0.f, 0.f, 0.f};

  for (int tile = sp; tile < NTILES; tile += NSPLIT) {
    int k0 = tile * 128;
    const unsigned short* kt = kf + (size_t)tile * (8 * 512);
    f32x4 s[8];
#pragma unroll
    for (int nt = 0; nt < 8; nt++) {
      bf16x8 kb = *(const bf16x8*)(kt + nt * 512 + lane * 8);
      f32x4 z = {0.f, 0.f, 0.f, 0.f};
      s[nt] = __builtin_amdgcn_mfma_f32_16x16x32_bf16(aq, kb, z, 0, 0, 0);
    }
    if (k0 + 128 > SS) {
#pragma unroll
      for (int nt = 0; nt < 8; nt++)
        if (k0 + col * 8 + nt >= SS) {
          s[nt][0] = -1e30f; s[nt][1] = -1e30f; s[nt][2] = -1e30f; s[nt][3] = -1e30f;
        }
    }
    float pm[4];
#pragma unroll
    for (int r = 0; r < 4; r++) {
      pm[r] = fmaxf(fmaxf(fmaxf(s[0][r], s[1][r]), fmaxf(s[2][r], s[3][r])),
                    fmaxf(fmaxf(s[4][r], s[5][r]), fmaxf(s[6][r], s[7][r])));
    }
#pragma unroll
    for (int msk = 1; msk <= 8; msk <<= 1)
#pragma unroll
      for (int r = 0; r < 4; r++) pm[r] = fmaxf(pm[r], __shfl_xor(pm[r], msk));
    float al[4], ps[4];
#pragma unroll
    for (int r = 0; r < 4; r++) {
      float mn = fmaxf(mreg[r], pm[r]);
      al[r] = __expf(mreg[r] - mn);
      mreg[r] = mn;
      ps[r] = 0.f;
    }
#pragma unroll
    for (int r = 0; r < 4; r++) {
      bf16x8 pv;
#pragma unroll
      for (int nt = 0; nt < 8; nt++) {
        float p = __expf(s[nt][r] - mreg[r]);
        s[nt][r] = p;
        ps[r] += p;
        pv[nt] = (short)f2b(p);
      }
      *(bf16x8*)(myscb + (quad * 4 + r) * 136 + col * 8) = pv;
    }
#pragma unroll
    for (int msk = 1; msk <= 8; msk <<= 1)
#pragma unroll
      for (int r = 0; r < 4; r++) ps[r] += __shfl_xor(ps[r], msk);
#pragma unroll
    for (int r = 0; r < 4; r++) lreg[r] = lreg[r] * al[r] + ps[r];
    f32x4 va = *(const f32x4*)(v16h + k0 + col * 8);
    f32x4 vb4 = *(const f32x4*)(v16h + k0 + col * 8 + 4);
#pragma unroll
    for (int r = 0; r < 4; r++) {
      o16a[r] = o16a[r] * al[r]
              + s[0][r] * va[0] + s[1][r] * va[1] + s[2][r] * va[2] + s[3][r] * va[3]
              + s[4][r] * vb4[0] + s[5][r] * vb4[1] + s[6][r] * vb4[2] + s[7][r] * vb4[3];
      oacc[r] *= al[r];
    }
    const unsigned short* vt = vf + (size_t)tile * (4 * 512);
#pragma unroll
    for (int c = 0; c < 4; c++) {
      bf16x8 pa = *(const bf16x8*)(myscb + col * 136 + c * 32 + quad * 8);
      bf16x8 vbf = *(const bf16x8*)(vt + c * 512 + lane * 8);
      oacc = __builtin_amdgcn_mfma_f32_16x16x32_bf16(pa, vbf, oacc, 0, 0, 0);
    }
  }
#pragma unroll
  for (int msk = 1; msk <= 8; msk <<= 1)
#pragma unroll
    for (int r = 0; r < 4; r++) o16a[r] += __shfl_xor(o16a[r], msk);
  size_t obase = ((size_t)sp * NHEAD + h) * SS;
#pragma unroll
  for (int r = 0; r < 4; r++) {
    int q = q0 + w * 16 + quad * 4 + r;
    if (q < SS) {
      opart[(obase + q) * HD + col] = oacc[r];
      if (col == 0) {
        opart[(obase + q) * HD + 16] = o16a[r];
        mpart[obase + q] = mreg[r];
        lpart[obase + q] = lreg[r];
      }
    }
  }
}

// ---------------- combine + out_proj (MFMA) + residual + LN1 ----------------
// 32 rows/block; all 256 threads stage combine; waves 0,1 do MFMA + LN.
__global__ __launch_bounds__(256) void proj_ln1_kernel(
    const float* __restrict__ opart, const float* __restrict__ mpart,
    const float* __restrict__ lpart, const unsigned short* __restrict__ opwp,
    const float* __restrict__ opb, const float* __restrict__ g,
    const float* __restrict__ b, float* __restrict__ x) {
  __shared__ __align__(16) unsigned short soA[32 * 72];
  int t = threadIdx.x;
  int w = t >> 6, lane = t & 63, quad = lane >> 4, col = lane & 15;
  int r0 = blockIdx.x * 32;
  int nr = min(32, SS - r0);
  for (int i = t; i < 32 * 72; i += 256) soA[i] = 0;
  __syncthreads();
  for (int i = t; i < nr * DD; i += 256) {
    int r = i / DD, rem = i - r * DD;
    int q = r0 + r;
    int h = rem / HD, d = rem - h * HD;
    float mm[NSPLIT], ll[NSPLIT];
    float M = -1e30f;
#pragma unroll
    for (int s = 0; s < NSPLIT; s++) {
      mm[s] = mpart[((size_t)s * NHEAD + h) * SS + q];
      ll[s] = lpart[((size_t)s * NHEAD + h) * SS + q];
      M = fmaxf(M, mm[s]);
    }
    float L = 0.f, O = 0.f;
#pragma unroll
    for (int s = 0; s < NSPLIT; s++) {
      float c = __expf(mm[s] - M);
      L += ll[s] * c;
      O += opart[(((size_t)s * NHEAD + h) * SS + q) * HD + d] * c;
    }
    soA[r * 72 + rem] = f2b(O / L);
  }
  __syncthreads();
  if (w < 2) {
    int m0 = w * 16;
    bf16x8 a0 = *(const bf16x8*)&soA[(m0 + col) * 72 + quad * 8];
    bf16x8 a1 = *(const bf16x8*)&soA[(m0 + col) * 72 + 32 + quad * 8];
    f32x4 y[3];
#pragma unroll
    for (int nt = 0; nt < 3; nt++) {
      int n = nt * 16 + col;
      bf16x8 b0 = *(const bf16x8*)&opwp[n * 64 + quad * 8];
      bf16x8 b1 = *(const bf16x8*)&opwp[n * 64 + 32 + quad * 8];
      f32x4 acc = {0.f, 0.f, 0.f, 0.f};
      acc = __builtin_amdgcn_mfma_f32_16x16x32_bf16(a0, b0, acc, 0, 0, 0);
      y[nt] = __builtin_amdgcn_mfma_f32_16x16x32_bf16(a1, b1, acc, 0, 0, 0);
    }
    float yv[3][4];
    float s1[4] = {0.f, 0.f, 0.f, 0.f}, s2[4] = {0.f, 0.f, 0.f, 0.f};
#pragma unroll
    for (int nt = 0; nt < 3; nt++) {
      int d = nt * 16 + col;
      bool vd = d < DD;
      float ob = vd ? opb[d] : 0.f;
#pragma unroll
      for (int r = 0; r < 4; r++) {
        int row = r0 + m0 + quad * 4 + r;
        float v = 0.f;
        if (vd && row < SS) v = y[nt][r] + ob + x[(size_t)row * DD + d];
        yv[nt][r] = v;
        s1[r] += v;
        s2[r] += v * v;
      }
    }
#pragma unroll
    for (int msk = 1; msk <= 8; msk <<= 1)
#pragma unroll
      for (int r = 0; r < 4; r++) {
        s1[r] += __shfl_xor(s1[r], msk);
        s2[r] += __shfl_xor(s2[r], msk);
      }
#pragma unroll
    for (int r = 0; r < 4; r++) {
      int row = r0 + m0 + quad * 4 + r;
      if (row >= SS) continue;
      float mean = s1[r] * (1.f / DD);
      float var = s2[r] * (1.f / DD) - mean * mean;
      float rs = rsqrtf(var + EPSF);
#pragma unroll
      for (int nt = 0; nt < 3; nt++) {
        int d = nt * 16 + col;
        if (d < DD)
          x[(size_t)row * DD + d] = (yv[nt][r] - mean) * rs * g[d] + b[d];
      }
    }
  }
}

// ---------------- MFMA FF + residual + LN2 ----------------
__global__ __launch_bounds__(256) void ff_mfma_kernel(
    float* __restrict__ x, const unsigned short* __restrict__ w1p,
    const unsigned short* __restrict__ w2p, const float* __restrict__ b1g,
    const float* __restrict__ b2g, const float* __restrict__ g,
    const float* __restrict__ bb) {
  __shared__ __align__(16) unsigned short sxA[32 * 72];
  __shared__ float sxF[32][35];
  __shared__ __align__(16) unsigned short hs[32 * 136];
  __shared__ float yred[32 * 49];
  int t = threadIdx.x;
  int w = t >> 6, lane = t & 63, quad = lane >> 4, col = lane & 15;
  int m0 = (w & 1) * 16, half = w >> 1;
  int r0 = blockIdx.x * 32;
  int nr = min(32, SS - r0);

  for (int i = t; i < 32 * 72; i += 256) sxA[i] = 0;
  for (int i = t; i < 32 * 35; i += 256) ((float*)sxF)[i] = 0.f;
  __syncthreads();
  for (int i = t; i < nr * DD; i += 256) {
    int r = i / DD, d = i % DD;
    float v = x[(size_t)(r0 + r) * DD + d];
    sxF[r][d] = v;
    sxA[r * 72 + d] = f2b(v);
  }
  __syncthreads();

  bf16x8 a0 = *(const bf16x8*)&sxA[(m0 + col) * 72 + quad * 8];
  bf16x8 a1 = *(const bf16x8*)&sxA[(m0 + col) * 72 + 32 + quad * 8];
  f32x4 acc3[3];
  for (int nt = 0; nt < 3; nt++) acc3[nt] = (f32x4){0.f, 0.f, 0.f, 0.f};

  for (int kt = 0; kt < 16; kt++) {
    int fbase = kt * 128 + half * 64;
    for (int nt = 0; nt < 4; nt++) {
      int f = fbase + nt * 16 + col;
      bf16x8 bq0 = *(const bf16x8*)&w1p[f * 64 + quad * 8];
      bf16x8 bq1 = *(const bf16x8*)&w1p[f * 64 + 32 + quad * 8];
      f32x4 hacc = {0.f, 0.f, 0.f, 0.f};
      hacc = __builtin_amdgcn_mfma_f32_16x16x32_bf16(a0, bq0, hacc, 0, 0, 0);
      hacc = __builtin_amdgcn_mfma_f32_16x16x32_bf16(a1, bq1, hacc, 0, 0, 0);
      float bias = b1g[f];
      for (int r = 0; r < 4; r++) {
        float hv = fmaxf(hacc[r] + bias, 0.f);
        hs[(m0 + quad * 4 + r) * 136 + half * 64 + nt * 16 + col] = f2b(hv);
      }
    }
    __syncthreads();
    bf16x8 ha0 = *(const bf16x8*)&hs[(m0 + col) * 136 + half * 64 + quad * 8];
    bf16x8 ha1 = *(const bf16x8*)&hs[(m0 + col) * 136 + half * 64 + 32 + quad * 8];
    for (int nt = 0; nt < 3; nt++) {
      const unsigned short* wp = &w2p[(size_t)(nt * 16 + col) * FF + kt * 128 + half * 64];
      bf16x8 wb0 = *(const bf16x8*)&wp[quad * 8];
      bf16x8 wb1 = *(const bf16x8*)&wp[32 + quad * 8];
      acc3[nt] = __builtin_amdgcn_mfma_f32_16x16x32_bf16(ha0, wb0, acc3[nt], 0, 0, 0);
      acc3[nt] = __builtin_amdgcn_mfma_f32_16x16x32_bf16(ha1, wb1, acc3[nt], 0, 0, 0);
    }
    __syncthreads();
  }

  if (half == 1) {
    for (int nt = 0; nt < 3; nt++)
      for (int r = 0; r < 4; r++)
        yred[(m0 + quad * 4 + r) * 49 + nt * 16 + col] = acc3[nt][r];
  }
  __syncthreads();
  if (half == 0) {
    float yv[3][4];
    float s1[4] = {0.f, 0.f, 0.f, 0.f}, s2[4] = {0.f, 0.f, 0.f, 0.f};
    for (int nt = 0; nt < 3; nt++) {
      int d = nt * 16 + col;
      bool valid = d < DD;
      float b2v = valid ? b2g[d] : 0.f;
      for (int r = 0; r < 4; r++) {
        int row = m0 + quad * 4 + r;
        float v = acc3[nt][r] + yred[row * 49 + nt * 16 + col];
        v = valid ? (v + b2v + sxF[row][d]) : 0.f;
        yv[nt][r] = v;
        s1[r] += v;
        s2[r] += v * v;
      }
    }
    for (int msk = 1; msk <= 8; msk <<= 1)
      for (int r = 0; r < 4; r++) {
        s1[r] += __shfl_xor(s1[r], msk);
        s2[r] += __shfl_xor(s2[r], msk);
      }
    for (int r = 0; r < 4; r++) {
      int row = m0 + quad * 4 + r;
      if (row >= nr) continue;
      float mean = s1[r] * (1.f / DD);
      float var = s2[r] * (1.f / DD) - mean * mean;
      float rs = rsqrtf(var + EPSF);
      for (int nt = 0; nt < 3; nt++) {
        int d = nt * 16 + col;
        if (d < DD)
          x[(size_t)(r0 + row) * DD + d] = (yv[nt][r] - mean) * rs * g[d] + bb[d];
      }
    }
  }
}

// ---------------- final ----------------
__global__ __launch_bounds__(64) void final_kernel(
    const float* __restrict__ x, const int* __restrict__ aidx, float* __restrict__ out) {
  int d = threadIdx.x;
  if (d >= DD) return;
  int start = (*aidx) * HW;
  float acc = 0.f;
  for (int j = 0; j < HW; j++) acc += x[(size_t)(start + j) * DD + d];
  out[d] = acc * (1.f / HW);
}

extern "C" void kernel_launch(void* const* d_in, const int* in_sizes, int n_in,
                              void* d_out, int out_size, void* d_ws, size_t ws_size,
                              hipStream_t stream) {
  const float* obs = (const float*)d_in[0];
  const float* c1w = (const float*)d_in[1];
  const float* c1b = (const float*)d_in[2];
  const float* c2w = (const float*)d_in[3];
  const float* c2b = (const float*)d_in[4];
  const float* ipw = (const float*)d_in[5];
  const float* ipb = (const float*)d_in[6];
  const float* opw = (const float*)d_in[7];
  const float* opb = (const float*)d_in[8];
  const float* l1w = (const float*)d_in[9];
  const float* l1b = (const float*)d_in[10];
  const float* l2w = (const float*)d_in[11];
  const float* l2b = (const float*)d_in[12];
  const float* g1 = (const float*)d_in[13];
  const float* b1 = (const float*)d_in[14];
  const float* g2 = (const float*)d_in[15];
  const float* b2 = (const float*)d_in[16];
  float* out = (float*)d_out;

  float* ws = (float*)d_ws;
  size_t off = 0;
  float* x     = ws + off; off += SS * DD;           // 223074
  float* qkv   = ws + off; off += SS * 102;          // 669222
  float* cell  = ws + off; off += HW * CC;           // 1296
  int*   aidx  = (int*)(ws + off); off += 1;
  off = (off + 3) & ~(size_t)3;
  float* opart = ws + off; off += (size_t)NSPLIT * NHEAD * SS * HD;  // 1784592
  float* mpart = ws + off; off += (size_t)NSPLIT * NHEAD * SS;       // 104976
  float* lpart = ws + off; off += (size_t)NSPLIT * NHEAD * SS;       // 104976
  off = (off + 3) & ~(size_t)3;
  unsigned short* kfp  = (unsigned short*)(ws + off); off += (NHEAD * NTILES * 8 * 512) / 2;
  unsigned short* vfp  = (unsigned short*)(ws + off); off += (NHEAD * NTILES * 4 * 512) / 2;
  float* v16 = ws + off; off += NHEAD * NTILES * 128;
  unsigned short* ipwp = (unsigned short*)(ws + off); off += 7168 / 2;
  unsigned short* opwp = (unsigned short*)(ws + off); off += 3072 / 2;
  unsigned short* w1p  = (unsigned short*)(ws + off); off += (FF * 64) / 2;
  unsigned short* w2p  = (unsigned short*)(ws + off); off += (48 * FF) / 2;

  prep_kernel<<<1, 256, 0, stream>>>(obs, c1w, c1b, c2w, c2b, cell, aidx);
  tokens_kernel<<<(SS * DD + 255) / 256, 256, 0, stream>>>(cell, x);

  const int row32_blocks = (SS + 31) / 32;   // 206
  const int q64_blocks = (SS + QB - 1) / QB; // 103
  const int lprep_blocks = (7168 + 3072 + FF * 64 + 48 * FF + 255) / 256;  // 936
  const int kvprep_elems = NHEAD * NTILES * (8 * 512 + 4 * 512 + 128);
  const int kvprep_blocks = (kvprep_elems + 255) / 256;
  for (int l = 0; l < 2; l++) {
    lprep_kernel<<<lprep_blocks, 256, 0, stream>>>(
        ipw + (size_t)l * 102 * DD, opw + (size_t)l * DD * DD,
        l1w + (size_t)l * FF * DD, l2w + (size_t)l * DD * FF,
        ipwp, opwp, w1p, w2p);
    qkv_mfma_kernel<<<row32_blocks, 256, 0, stream>>>(
        x, ipwp, ipb + (size_t)l * 102, qkv);
    kvprep_kernel<<<kvprep_blocks, 256, 0, stream>>>(qkv, kfp, vfp, v16);
    dim3 ag(q64_blocks, NHEAD, NSPLIT);
    attn_split_kernel<<<ag, 256, 0, stream>>>(qkv, kfp, vfp, v16, opart, mpart, lpart);
    proj_ln1_kernel<<<row32_blocks, 256, 0, stream>>>(
        opart, mpart, lpart, opwp, opb + (size_t)l * DD,
        g1 + (size_t)l * DD, b1 + (size_t)l * DD, x);
    ff_mfma_kernel<<<row32_blocks, 256, 0, stream>>>(
        x, w1p, w2p, l1b + (size_t)l * FF,
        l2b + (size_t)l * DD, g2 + (size_t)l * DD, b2 + (size_t)l * DD);
  }
  final_kernel<<<1, 64, 0, stream>>>(x, aidx, out);
}

// Round 8
// 332.943 us; speedup vs baseline: 8.8653x; 1.0886x over previous
//
#include <hip/hip_runtime.h>
#include <hip/hip_bf16.h>

#define HH 9
#define WW 9
#define HW 81
#define CC 16
#define DD 34
#define SS 6561
#define NHEAD 2
#define HD 17
#define FF 2048
#define EPSF 1e-5f

#define NSPLIT 8
#define NTILES 52
#define QB 64

typedef __attribute__((ext_vector_type(8))) short bf16x8;
typedef __attribute__((ext_vector_type(4))) float f32x4;

__device__ __forceinline__ unsigned short f2b(float f) {
  unsigned int u = __float_as_uint(f);
  u += 0x7fffu + ((u >> 16) & 1u);
  return (unsigned short)(u >> 16);
}

// ---------------- conv1 + conv2 + argmax (LDS-staged) ----------------
__global__ __launch_bounds__(256) void prep_kernel(
    const float* __restrict__ obs, const float* __restrict__ w1, const float* __restrict__ b1,
    const float* __restrict__ w2, const float* __restrict__ b2,
    float* __restrict__ cell, int* __restrict__ aidx) {
  __shared__ float s_obs[2 * HW];
  __shared__ float s_w1[288];
  __shared__ float s_w2[2304];
  __shared__ float s_b1[16], s_b2[16];
  __shared__ float y1[CC][HW];
  int t = threadIdx.x;
  for (int i = t; i < 2 * HW; i += 256) s_obs[i] = obs[i];
  for (int i = t; i < 288; i += 256) s_w1[i] = w1[i];
  for (int i = t; i < 2304; i += 256) s_w2[i] = w2[i];
  if (t < 16) { s_b1[t] = b1[t]; s_b2[t] = b2[t]; }
  __syncthreads();
  if (t == 0) {
    int best = 0; float bv = s_obs[0];
    for (int i = 1; i < HW; i++) { float v = s_obs[i]; if (v > bv) { bv = v; best = i; } }
    *aidx = best;
  }
  for (int idx = t; idx < CC * HW; idx += 256) {
    int c = idx / HW, p = idx % HW;
    int i = p / WW, j = p % WW;
    float acc = s_b1[c];
    for (int ic = 0; ic < 2; ic++)
      for (int di = 0; di < 3; di++) {
        int ii = i + di - 1; if (ii < 0 || ii >= HH) continue;
        for (int dj = 0; dj < 3; dj++) {
          int jj = j + dj - 1; if (jj < 0 || jj >= WW) continue;
          acc += s_obs[ic * HW + ii * WW + jj] * s_w1[((c * 2 + ic) * 3 + di) * 3 + dj];
        }
      }
    y1[c][p] = fmaxf(acc, 0.f);
  }
  __syncthreads();
  for (int idx = t; idx < CC * HW; idx += 256) {
    int c = idx / HW, p = idx % HW;
    int i = p / WW, j = p % WW;
    float acc = s_b2[c];
    for (int ic = 0; ic < CC; ic++)
      for (int di = 0; di < 3; di++) {
        int ii = i + di - 1; if (ii < 0 || ii >= HH) continue;
        for (int dj = 0; dj < 3; dj++) {
          int jj = j + dj - 1; if (jj < 0 || jj >= WW) continue;
          acc += y1[ic][ii * WW + jj] * s_w2[((c * CC + ic) * 3 + di) * 3 + dj];
        }
      }
    cell[p * CC + c] = fmaxf(acc, 0.f);
  }
}

// ---------------- token build ----------------
__global__ __launch_bounds__(256) void tokens_kernel(
    const float* __restrict__ cell, float* __restrict__ x) {
  int idx = blockIdx.x * 256 + threadIdx.x;
  if (idx >= SS * DD) return;
  int row = idx / DD, d = idx - row * DD;
  int i = row / HW, j = row - i * HW;
  float v;
  if (d < CC) v = cell[i * CC + d];
  else if (d < 2 * CC) v = cell[j * CC + (d - CC)];
  else if (d == 32) v = (float)((i / WW) - (j / WW)) * 0.25f;
  else v = (float)((i % WW) - (j % WW)) * 0.25f;
  x[idx] = v;
}

// ---------------- per-layer weight pack ----------------
__global__ __launch_bounds__(256) void lprep_kernel(
    const float* __restrict__ ipw, const float* __restrict__ opw,
    const float* __restrict__ w1, const float* __restrict__ w2,
    unsigned short* __restrict__ ipwp, unsigned short* __restrict__ opwp,
    unsigned short* __restrict__ w1p, unsigned short* __restrict__ w2p) {
  int i = blockIdx.x * 256 + threadIdx.x;
  if (i < 7168) {
    int n = i >> 6, k = i & 63;
    ipwp[i] = (n < 102 && k < DD) ? f2b(ipw[n * DD + k]) : (unsigned short)0;
  } else if (i < 10240) {
    int ii = i - 7168;
    int n = ii >> 6, k = ii & 63;
    opwp[ii] = (n < DD && k < DD) ? f2b(opw[n * DD + k]) : (unsigned short)0;
  } else if (i < 141312) {
    int ii = i - 10240;
    int f = ii >> 6, k = ii & 63;
    w1p[ii] = (k < DD) ? f2b(w1[f * DD + k]) : (unsigned short)0;
  } else {
    int ii = i - 141312;
    if (ii < 48 * FF) {
      int d = ii >> 11, kk = ii & 2047;
      w2p[ii] = (d < DD) ? f2b(w2[d * FF + kk]) : (unsigned short)0;
    }
  }
}

// ---------------- qkv projection via MFMA ----------------
__global__ __launch_bounds__(256) void qkv_mfma_kernel(
    const float* __restrict__ x, const unsigned short* __restrict__ ipwp,
    const float* __restrict__ ipb, float* __restrict__ qkv) {
  __shared__ __align__(16) unsigned short sxA[32 * 72];
  int t = threadIdx.x;
  int w = t >> 6, lane = t & 63, quad = lane >> 4, col = lane & 15;
  int m0 = (w & 1) * 16, half = w >> 1;
  int row0 = blockIdx.x * 32;
  int nr = min(32, SS - row0);
  for (int i = t; i < 32 * 72; i += 256) sxA[i] = 0;
  __syncthreads();
  for (int i = t; i < nr * DD; i += 256) {
    int r = i / DD, d = i - r * DD;
    sxA[r * 72 + d] = f2b(x[(size_t)row0 * DD + i]);
  }
  __syncthreads();
  bf16x8 a0 = *(const bf16x8*)&sxA[(m0 + col) * 72 + quad * 8];
  bf16x8 a1 = *(const bf16x8*)&sxA[(m0 + col) * 72 + 32 + quad * 8];
  int ntc = half ? 3 : 4;
  for (int nt2 = 0; nt2 < ntc; nt2++) {
    int nt = half * 4 + nt2;
    int n = nt * 16 + col;
    bf16x8 b0 = *(const bf16x8*)&ipwp[n * 64 + quad * 8];
    bf16x8 b1 = *(const bf16x8*)&ipwp[n * 64 + 32 + quad * 8];
    f32x4 acc = {0.f, 0.f, 0.f, 0.f};
    acc = __builtin_amdgcn_mfma_f32_16x16x32_bf16(a0, b0, acc, 0, 0, 0);
    acc = __builtin_amdgcn_mfma_f32_16x16x32_bf16(a1, b1, acc, 0, 0, 0);
    if (n < 102) {
      float bias = ipb[n];
#pragma unroll
      for (int r = 0; r < 4; r++) {
        int m = m0 + quad * 4 + r;
        if (m < nr) qkv[(size_t)(row0 + m) * 102 + n] = acc[r] + bias;
      }
    }
  }
}

// ---------------- K/V fragment pre-pack ----------------
__global__ __launch_bounds__(256) void kvprep_kernel(
    const float* __restrict__ qkv, unsigned short* __restrict__ kfp,
    unsigned short* __restrict__ vfp, float* __restrict__ v16) {
  const int NK = NHEAD * NTILES * 8 * 512;
  const int NV = NHEAD * NTILES * 4 * 512;
  const int NV16 = NHEAD * NTILES * 128;
  int i = blockIdx.x * 256 + threadIdx.x;
  if (i < NK) {
    int j = i & 7, l = (i >> 3) & 63, nt = (i >> 9) & 7, rest = i >> 12;
    int T = rest % NTILES, h = rest / NTILES;
    int colf = l & 15, quadf = l >> 4;
    int tok = T * 128 + colf * 8 + nt;
    int d = quadf * 8 + j;
    unsigned short v = 0;
    if (tok < SS && d < HD) v = f2b(qkv[(size_t)tok * 102 + DD + h * HD + d]);
    kfp[i] = v;
  } else if (i < NK + NV) {
    int ii = i - NK;
    int j = ii & 7, l = (ii >> 3) & 63, c = (ii >> 9) & 3, rest = ii >> 11;
    int T = rest % NTILES, h = rest / NTILES;
    int colf = l & 15, quadf = l >> 4;
    int tok = T * 128 + c * 32 + quadf * 8 + j;
    unsigned short v = 0;
    if (tok < SS) v = f2b(qkv[(size_t)tok * 102 + 2 * DD + h * HD + colf]);
    vfp[ii] = v;
  } else {
    int ii = i - NK - NV;
    if (ii < NV16) {
      int tl = ii % (NTILES * 128), h = ii / (NTILES * 128);
      v16[ii] = (tl < SS) ? qkv[(size_t)tl * 102 + 2 * DD + h * HD + 16] : 0.f;
    }
  }
}

// ---------------- split-K flash attention: fixed-max softmax ----------------
// softmax is shift-invariant; scores clamped at 70 so exp never overflows fp32
// (6561*e^70 ~ 1.6e34). No running max, no alpha rescale; l/o16 are plain sums
// reduced once at the end. Masked tokens: s=-1e30 -> exp -> 0.
__global__ __launch_bounds__(256) void attn_split_kernel(
    const float* __restrict__ qkv, const unsigned short* __restrict__ kfp,
    const unsigned short* __restrict__ vfp, const float* __restrict__ v16,
    float* __restrict__ opart, float* __restrict__ lpart) {
  __shared__ __align__(16) unsigned short scb[4][16 * 136];
  int t = threadIdx.x, w = t >> 6, lane = t & 63, quad = lane >> 4, col = lane & 15;
  int h = blockIdx.y, sp = blockIdx.z;
  int q0 = blockIdx.x * QB;
  const float scale = 0.24253562503633297f;
  const unsigned short* kf = kfp + (size_t)h * (NTILES * 8 * 512);
  const unsigned short* vf = vfp + (size_t)h * (NTILES * 4 * 512);
  const float* v16h = v16 + (size_t)h * (NTILES * 128);
  unsigned short* myscb = &scb[w][0];

  int mq = q0 + w * 16 + col;
  int qc = mq < SS ? mq : SS - 1;
  bf16x8 aq;
#pragma unroll
  for (int j = 0; j < 8; j++) {
    int d = quad * 8 + j;
    aq[j] = (short)((d < HD) ? f2b(qkv[(size_t)qc * 102 + h * HD + d] * scale) : 0);
  }

  f32x4 oacc = {0.f, 0.f, 0.f, 0.f};
  float o16a[4] = {0.f, 0.f, 0.f, 0.f};
  float lreg[4] = {0.f, 0.f, 0.f, 0.f};

  for (int tile = sp; tile < NTILES; tile += NSPLIT) {
    int k0 = tile * 128;
    const unsigned short* kt = kf + (size_t)tile * (8 * 512);
    f32x4 s[8];
#pragma unroll
    for (int nt = 0; nt < 8; nt++) {
      bf16x8 kb = *(const bf16x8*)(kt + nt * 512 + lane * 8);
      f32x4 z = {0.f, 0.f, 0.f, 0.f};
      s[nt] = __builtin_amdgcn_mfma_f32_16x16x32_bf16(aq, kb, z, 0, 0, 0);
    }
    if (k0 + 128 > SS) {
#pragma unroll
      for (int nt = 0; nt < 8; nt++)
        if (k0 + col * 8 + nt >= SS) {
          s[nt][0] = -1e30f; s[nt][1] = -1e30f; s[nt][2] = -1e30f; s[nt][3] = -1e30f;
        }
    }
    // p = exp(clamp(s,70)), pack row-contiguous, lane-local l accumulation
#pragma unroll
    for (int r = 0; r < 4; r++) {
      bf16x8 pv;
      float psl = 0.f;
#pragma unroll
      for (int nt = 0; nt < 8; nt++) {
        float p = __expf(fminf(s[nt][r], 70.f));
        s[nt][r] = p;
        psl += p;
        pv[nt] = (short)f2b(p);
      }
      lreg[r] += psl;
      *(bf16x8*)(myscb + (quad * 4 + r) * 136 + col * 8) = pv;
    }
    // d=16 column via VALU dot
    f32x4 va = *(const f32x4*)(v16h + k0 + col * 8);
    f32x4 vb4 = *(const f32x4*)(v16h + k0 + col * 8 + 4);
#pragma unroll
    for (int r = 0; r < 4; r++) {
      o16a[r] += s[0][r] * va[0] + s[1][r] * va[1] + s[2][r] * va[2] + s[3][r] * va[3]
               + s[4][r] * vb4[0] + s[5][r] * vb4[1] + s[6][r] * vb4[2] + s[7][r] * vb4[3];
    }
    const unsigned short* vt = vf + (size_t)tile * (4 * 512);
#pragma unroll
    for (int c = 0; c < 4; c++) {
      bf16x8 pa = *(const bf16x8*)(myscb + col * 136 + c * 32 + quad * 8);
      bf16x8 vbf = *(const bf16x8*)(vt + c * 512 + lane * 8);
      oacc = __builtin_amdgcn_mfma_f32_16x16x32_bf16(pa, vbf, oacc, 0, 0, 0);
    }
  }
  // single end-of-kernel cross-col reduction for o16 and l
#pragma unroll
  for (int msk = 1; msk <= 8; msk <<= 1)
#pragma unroll
    for (int r = 0; r < 4; r++) {
      o16a[r] += __shfl_xor(o16a[r], msk);
      lreg[r] += __shfl_xor(lreg[r], msk);
    }
  size_t obase = ((size_t)sp * NHEAD + h) * SS;
#pragma unroll
  for (int r = 0; r < 4; r++) {
    int q = q0 + w * 16 + quad * 4 + r;
    if (q < SS) {
      opart[(obase + q) * HD + col] = oacc[r];
      if (col == 0) {
        opart[(obase + q) * HD + 16] = o16a[r];
        lpart[obase + q] = lreg[r];
      }
    }
  }
}

// ---------------- combine + out_proj (MFMA) + residual + LN1 ----------------
__global__ __launch_bounds__(256) void proj_ln1_kernel(
    const float* __restrict__ opart, const float* __restrict__ lpart,
    const unsigned short* __restrict__ opwp, const float* __restrict__ opb,
    const float* __restrict__ g, const float* __restrict__ b, float* __restrict__ x) {
  __shared__ __align__(16) unsigned short soA[32 * 72];
  int t = threadIdx.x;
  int w = t >> 6, lane = t & 63, quad = lane >> 4, col = lane & 15;
  int r0 = blockIdx.x * 32;
  int nr = min(32, SS - r0);
  for (int i = t; i < 32 * 72; i += 256) soA[i] = 0;
  __syncthreads();
  for (int i = t; i < nr * DD; i += 256) {
    int r = i / DD, rem = i - r * DD;
    int q = r0 + r;
    int h = rem / HD, d = rem - h * HD;
    float L = 0.f, O = 0.f;
#pragma unroll
    for (int s = 0; s < NSPLIT; s++) {
      L += lpart[((size_t)s * NHEAD + h) * SS + q];
      O += opart[(((size_t)s * NHEAD + h) * SS + q) * HD + d];
    }
    soA[r * 72 + rem] = f2b(O / L);
  }
  __syncthreads();
  if (w < 2) {
    int m0 = w * 16;
    bf16x8 a0 = *(const bf16x8*)&soA[(m0 + col) * 72 + quad * 8];
    bf16x8 a1 = *(const bf16x8*)&soA[(m0 + col) * 72 + 32 + quad * 8];
    f32x4 y[3];
#pragma unroll
    for (int nt = 0; nt < 3; nt++) {
      int n = nt * 16 + col;
      bf16x8 b0 = *(const bf16x8*)&opwp[n * 64 + quad * 8];
      bf16x8 b1 = *(const bf16x8*)&opwp[n * 64 + 32 + quad * 8];
      f32x4 acc = {0.f, 0.f, 0.f, 0.f};
      acc = __builtin_amdgcn_mfma_f32_16x16x32_bf16(a0, b0, acc, 0, 0, 0);
      y[nt] = __builtin_amdgcn_mfma_f32_16x16x32_bf16(a1, b1, acc, 0, 0, 0);
    }
    float yv[3][4];
    float s1[4] = {0.f, 0.f, 0.f, 0.f}, s2[4] = {0.f, 0.f, 0.f, 0.f};
#pragma unroll
    for (int nt = 0; nt < 3; nt++) {
      int d = nt * 16 + col;
      bool vd = d < DD;
      float ob = vd ? opb[d] : 0.f;
#pragma unroll
      for (int r = 0; r < 4; r++) {
        int row = r0 + m0 + quad * 4 + r;
        float v = 0.f;
        if (vd && row < SS) v = y[nt][r] + ob + x[(size_t)row * DD + d];
        yv[nt][r] = v;
        s1[r] += v;
        s2[r] += v * v;
      }
    }
#pragma unroll
    for (int msk = 1; msk <= 8; msk <<= 1)
#pragma unroll
      for (int r = 0; r < 4; r++) {
        s1[r] += __shfl_xor(s1[r], msk);
        s2[r] += __shfl_xor(s2[r], msk);
      }
#pragma unroll
    for (int r = 0; r < 4; r++) {
      int row = r0 + m0 + quad * 4 + r;
      if (row >= SS) continue;
      float mean = s1[r] * (1.f / DD);
      float var = s2[r] * (1.f / DD) - mean * mean;
      float rs = rsqrtf(var + EPSF);
#pragma unroll
      for (int nt = 0; nt < 3; nt++) {
        int d = nt * 16 + col;
        if (d < DD)
          x[(size_t)row * DD + d] = (yv[nt][r] - mean) * rs * g[d] + b[d];
      }
    }
  }
}

// ---------------- MFMA FF + residual + LN2: barrier-free K-loop ----------------
// 16 rows/block (411 blocks). Wave w owns f-columns kt*128 + w*32: the y K-range
// a wave consumes equals the h n-range it produces -> no cross-wave deps in the
// K-loop; only one final barrier for the 4-way y reduction.
__global__ __launch_bounds__(256) void ff_mfma_kernel(
    float* __restrict__ x, const unsigned short* __restrict__ w1p,
    const unsigned short* __restrict__ w2p, const float* __restrict__ b1g,
    const float* __restrict__ b2g, const float* __restrict__ g,
    const float* __restrict__ bb) {
  __shared__ __align__(16) unsigned short sxA[16 * 72];
  __shared__ float sxF[16][35];
  __shared__ __align__(16) unsigned short hw_[4][16 * 40];  // wave-private h
  __shared__ float yred[4][16][49];
  int t = threadIdx.x;
  int w = t >> 6, lane = t & 63, quad = lane >> 4, col = lane & 15;
  int r0 = blockIdx.x * 16;
  int nr = min(16, SS - r0);

  for (int i = t; i < 16 * 72; i += 256) sxA[i] = 0;
  for (int i = t; i < 16 * 35; i += 256) ((float*)sxF)[i] = 0.f;
  __syncthreads();
  for (int i = t; i < nr * DD; i += 256) {
    int r = i / DD, d = i - r * DD;
    float v = x[(size_t)(r0 + r) * DD + d];
    sxF[r][d] = v;
    sxA[r * 72 + d] = f2b(v);
  }
  __syncthreads();

  bf16x8 a0 = *(const bf16x8*)&sxA[col * 72 + quad * 8];
  bf16x8 a1 = *(const bf16x8*)&sxA[col * 72 + 32 + quad * 8];
  unsigned short* myh = &hw_[w][0];
  f32x4 acc3[3];
#pragma unroll
  for (int nt = 0; nt < 3; nt++) acc3[nt] = (f32x4){0.f, 0.f, 0.f, 0.f};

  for (int kt = 0; kt < 16; kt++) {
    int fbase = kt * 128 + w * 32;
    // h = relu(x @ W1^T + b1) for this wave's 32 f-columns
#pragma unroll
    for (int nt = 0; nt < 2; nt++) {
      int f = fbase + nt * 16 + col;
      bf16x8 b0 = *(const bf16x8*)&w1p[f * 64 + quad * 8];
      bf16x8 b1 = *(const bf16x8*)&w1p[f * 64 + 32 + quad * 8];
      f32x4 hacc = {0.f, 0.f, 0.f, 0.f};
      hacc = __builtin_amdgcn_mfma_f32_16x16x32_bf16(a0, b0, hacc, 0, 0, 0);
      hacc = __builtin_amdgcn_mfma_f32_16x16x32_bf16(a1, b1, hacc, 0, 0, 0);
      float bias = b1g[f];
#pragma unroll
      for (int r = 0; r < 4; r++) {
        float hv = fmaxf(hacc[r] + bias, 0.f);
        myh[(quad * 4 + r) * 40 + nt * 16 + col] = f2b(hv);  // A[m][klocal]
      }
    }
    // y += h @ W2^T over this wave's K=32 (own h region, lgkmcnt only)
    bf16x8 pa = *(const bf16x8*)&myh[col * 40 + quad * 8];
#pragma unroll
    for (int nt = 0; nt < 3; nt++) {
      int n = nt * 16 + col;
      bf16x8 wb = *(const bf16x8*)&w2p[(size_t)n * FF + fbase + quad * 8];
      acc3[nt] = __builtin_amdgcn_mfma_f32_16x16x32_bf16(pa, wb, acc3[nt], 0, 0, 0);
    }
  }

  // 4-way cross-wave reduce + bias + residual + LN2
#pragma unroll
  for (int nt = 0; nt < 3; nt++)
#pragma unroll
    for (int r = 0; r < 4; r++)
      yred[w][quad * 4 + r][nt * 16 + col] = acc3[nt][r];
  __syncthreads();
  if (w == 0) {
    float yv[3][4];
    float s1[4] = {0.f, 0.f, 0.f, 0.f}, s2[4] = {0.f, 0.f, 0.f, 0.f};
#pragma unroll
    for (int nt = 0; nt < 3; nt++) {
      int d = nt * 16 + col;
      bool valid = d < DD;
      float b2v = valid ? b2g[d] : 0.f;
#pragma unroll
      for (int r = 0; r < 4; r++) {
        int row = quad * 4 + r;
        float v = yred[0][row][nt * 16 + col] + yred[1][row][nt * 16 + col]
                + yred[2][row][nt * 16 + col] + yred[3][row][nt * 16 + col];
        v = valid ? (v + b2v + sxF[row][d]) : 0.f;
        yv[nt][r] = v;
        s1[r] += v;
        s2[r] += v * v;
      }
    }
#pragma unroll
    for (int msk = 1; msk <= 8; msk <<= 1)
#pragma unroll
      for (int r = 0; r < 4; r++) {
        s1[r] += __shfl_xor(s1[r], msk);
        s2[r] += __shfl_xor(s2[r], msk);
      }
#pragma unroll
    for (int r = 0; r < 4; r++) {
      int row = quad * 4 + r;
      if (row >= nr) continue;
      float mean = s1[r] * (1.f / DD);
      float var = s2[r] * (1.f / DD) - mean * mean;
      float rs = rsqrtf(var + EPSF);
#pragma unroll
      for (int nt = 0; nt < 3; nt++) {
        int d = nt * 16 + col;
        if (d < DD)
          x[(size_t)(r0 + row) * DD + d] = (yv[nt][r] - mean) * rs * g[d] + bb[d];
      }
    }
  }
}

// ---------------- final ----------------
__global__ __launch_bounds__(64) void final_kernel(
    const float* __restrict__ x, const int* __restrict__ aidx, float* __restrict__ out) {
  int d = threadIdx.x;
  if (d >= DD) return;
  int start = (*aidx) * HW;
  float acc = 0.f;
  for (int j = 0; j < HW; j++) acc += x[(size_t)(start + j) * DD + d];
  out[d] = acc * (1.f / HW);
}

extern "C" void kernel_launch(void* const* d_in, const int* in_sizes, int n_in,
                              void* d_out, int out_size, void* d_ws, size_t ws_size,
                              hipStream_t stream) {
  const float* obs = (const float*)d_in[0];
  const float* c1w = (const float*)d_in[1];
  const float* c1b = (const float*)d_in[2];
  const float* c2w = (const float*)d_in[3];
  const float* c2b = (const float*)d_in[4];
  const float* ipw = (const float*)d_in[5];
  const float* ipb = (const float*)d_in[6];
  const float* opw = (const float*)d_in[7];
  const float* opb = (const float*)d_in[8];
  const float* l1w = (const float*)d_in[9];
  const float* l1b = (const float*)d_in[10];
  const float* l2w = (const float*)d_in[11];
  const float* l2b = (const float*)d_in[12];
  const float* g1 = (const float*)d_in[13];
  const float* b1 = (const float*)d_in[14];
  const float* g2 = (const float*)d_in[15];
  const float* b2 = (const float*)d_in[16];
  float* out = (float*)d_out;

  float* ws = (float*)d_ws;
  size_t off = 0;
  float* x     = ws + off; off += SS * DD;
  float* qkv   = ws + off; off += SS * 102;
  float* cell  = ws + off; off += HW * CC;
  int*   aidx  = (int*)(ws + off); off += 1;
  off = (off + 3) & ~(size_t)3;
  float* opart = ws + off; off += (size_t)NSPLIT * NHEAD * SS * HD;
  float* lpart = ws + off; off += (size_t)NSPLIT * NHEAD * SS;
  off = (off + 3) & ~(size_t)3;
  unsigned short* kfp  = (unsigned short*)(ws + off); off += (NHEAD * NTILES * 8 * 512) / 2;
  unsigned short* vfp  = (unsigned short*)(ws + off); off += (NHEAD * NTILES * 4 * 512) / 2;
  float* v16 = ws + off; off += NHEAD * NTILES * 128;
  unsigned short* ipwp = (unsigned short*)(ws + off); off += 7168 / 2;
  unsigned short* opwp = (unsigned short*)(ws + off); off += 3072 / 2;
  unsigned short* w1p  = (unsigned short*)(ws + off); off += (FF * 64) / 2;
  unsigned short* w2p  = (unsigned short*)(ws + off); off += (48 * FF) / 2;

  prep_kernel<<<1, 256, 0, stream>>>(obs, c1w, c1b, c2w, c2b, cell, aidx);
  tokens_kernel<<<(SS * DD + 255) / 256, 256, 0, stream>>>(cell, x);

  const int row32_blocks = (SS + 31) / 32;   // 206
  const int row16_blocks = (SS + 15) / 16;   // 411
  const int q64_blocks = (SS + QB - 1) / QB; // 103
  const int lprep_blocks = (7168 + 3072 + FF * 64 + 48 * FF + 255) / 256;
  const int kvprep_elems = NHEAD * NTILES * (8 * 512 + 4 * 512 + 128);
  const int kvprep_blocks = (kvprep_elems + 255) / 256;
  for (int l = 0; l < 2; l++) {
    lprep_kernel<<<lprep_blocks, 256, 0, stream>>>(
        ipw + (size_t)l * 102 * DD, opw + (size_t)l * DD * DD,
        l1w + (size_t)l * FF * DD, l2w + (size_t)l * DD * FF,
        ipwp, opwp, w1p, w2p);
    qkv_mfma_kernel<<<row32_blocks, 256, 0, stream>>>(
        x, ipwp, ipb + (size_t)l * 102, qkv);
    kvprep_kernel<<<kvprep_blocks, 256, 0, stream>>>(qkv, kfp, vfp, v16);
    dim3 ag(q64_blocks, NHEAD, NSPLIT);
    attn_split_kernel<<<ag, 256, 0, stream>>>(qkv, kfp, vfp, v16, opart, lpart);
    proj_ln1_kernel<<<row32_blocks, 256, 0, stream>>>(
        opart, lpart, opwp, opb + (size_t)l * DD,
        g1 + (size_t)l * DD, b1 + (size_t)l * DD, x);
    ff_mfma_kernel<<<row16_blocks, 256, 0, stream>>>(
        x, w1p, w2p, l1b + (size_t)l * FF,
        l2b + (size_t)l * DD, g2 + (size_t)l * DD, b2 + (size_t)l * DD);
  }
  final_kernel<<<1, 64, 0, stream>>>(x, aidx, out);
}

// Round 9
// 259.096 us; speedup vs baseline: 11.3921x; 1.2850x over previous
//
#include <hip/hip_runtime.h>
#include <hip/hip_bf16.h>

#define HH 9
#define WW 9
#define HW 81
#define CC 16
#define DD 34
#define SS 6561
#define NHEAD 2
#define HD 17
#define FF 2048
#define EPSF 1e-5f

#define NTILES 52
#define NSPLIT2 26
#define QB 64

typedef __attribute__((ext_vector_type(8))) short bf16x8;
typedef __attribute__((ext_vector_type(4))) float f32x4;

__device__ __forceinline__ unsigned short f2b(float f) {
  unsigned int u = __float_as_uint(f);
  u += 0x7fffu + ((u >> 16) & 1u);
  return (unsigned short)(u >> 16);
}

// ---------------- conv1 + conv2 + argmax (LDS-staged) ----------------
__global__ __launch_bounds__(256) void prep_kernel(
    const float* __restrict__ obs, const float* __restrict__ w1, const float* __restrict__ b1,
    const float* __restrict__ w2, const float* __restrict__ b2,
    float* __restrict__ cell, int* __restrict__ aidx) {
  __shared__ float s_obs[2 * HW];
  __shared__ float s_w1[288];
  __shared__ float s_w2[2304];
  __shared__ float s_b1[16], s_b2[16];
  __shared__ float y1[CC][HW];
  int t = threadIdx.x;
  for (int i = t; i < 2 * HW; i += 256) s_obs[i] = obs[i];
  for (int i = t; i < 288; i += 256) s_w1[i] = w1[i];
  for (int i = t; i < 2304; i += 256) s_w2[i] = w2[i];
  if (t < 16) { s_b1[t] = b1[t]; s_b2[t] = b2[t]; }
  __syncthreads();
  if (t == 0) {
    int best = 0; float bv = s_obs[0];
    for (int i = 1; i < HW; i++) { float v = s_obs[i]; if (v > bv) { bv = v; best = i; } }
    *aidx = best;
  }
  for (int idx = t; idx < CC * HW; idx += 256) {
    int c = idx / HW, p = idx % HW;
    int i = p / WW, j = p % WW;
    float acc = s_b1[c];
    for (int ic = 0; ic < 2; ic++)
      for (int di = 0; di < 3; di++) {
        int ii = i + di - 1; if (ii < 0 || ii >= HH) continue;
        for (int dj = 0; dj < 3; dj++) {
          int jj = j + dj - 1; if (jj < 0 || jj >= WW) continue;
          acc += s_obs[ic * HW + ii * WW + jj] * s_w1[((c * 2 + ic) * 3 + di) * 3 + dj];
        }
      }
    y1[c][p] = fmaxf(acc, 0.f);
  }
  __syncthreads();
  for (int idx = t; idx < CC * HW; idx += 256) {
    int c = idx / HW, p = idx % HW;
    int i = p / WW, j = p % WW;
    float acc = s_b2[c];
    for (int ic = 0; ic < CC; ic++)
      for (int di = 0; di < 3; di++) {
        int ii = i + di - 1; if (ii < 0 || ii >= HH) continue;
        for (int dj = 0; dj < 3; dj++) {
          int jj = j + dj - 1; if (jj < 0 || jj >= WW) continue;
          acc += y1[ic][ii * WW + jj] * s_w2[((c * CC + ic) * 3 + di) * 3 + dj];
        }
      }
    cell[p * CC + c] = fmaxf(acc, 0.f);
  }
}

// ---------------- token build ----------------
__global__ __launch_bounds__(256) void tokens_kernel(
    const float* __restrict__ cell, float* __restrict__ x) {
  int idx = blockIdx.x * 256 + threadIdx.x;
  if (idx >= SS * DD) return;
  int row = idx / DD, d = idx - row * DD;
  int i = row / HW, j = row - i * HW;
  float v;
  if (d < CC) v = cell[i * CC + d];
  else if (d < 2 * CC) v = cell[j * CC + (d - CC)];
  else if (d == 32) v = (float)((i / WW) - (j / WW)) * 0.25f;
  else v = (float)((i % WW) - (j % WW)) * 0.25f;
  x[idx] = v;
}

// ---------------- per-layer weight pack ----------------
__global__ __launch_bounds__(256) void lprep_kernel(
    const float* __restrict__ ipw, const float* __restrict__ opw,
    const float* __restrict__ w1, const float* __restrict__ w2,
    unsigned short* __restrict__ ipwp, unsigned short* __restrict__ opwp,
    unsigned short* __restrict__ w1p, unsigned short* __restrict__ w2p) {
  int i = blockIdx.x * 256 + threadIdx.x;
  if (i < 7168) {
    int n = i >> 6, k = i & 63;
    ipwp[i] = (n < 102 && k < DD) ? f2b(ipw[n * DD + k]) : (unsigned short)0;
  } else if (i < 10240) {
    int ii = i - 7168;
    int n = ii >> 6, k = ii & 63;
    opwp[ii] = (n < DD && k < DD) ? f2b(opw[n * DD + k]) : (unsigned short)0;
  } else if (i < 141312) {
    int ii = i - 10240;
    int f = ii >> 6, k = ii & 63;
    w1p[ii] = (k < DD) ? f2b(w1[f * DD + k]) : (unsigned short)0;
  } else {
    int ii = i - 141312;
    if (ii < 48 * FF) {
      int d = ii >> 11, kk = ii & 2047;
      w2p[ii] = (d < DD) ? f2b(w2[d * FF + kk]) : (unsigned short)0;
    }
  }
}

// ---------------- layer-1 separable qkv tables ----------------
// Pt[part][a][n]: part0 = i-side (bias + rel+), part1 = j-side (rel-)
// qkv[t][n] = Pt[0][i][n] + Pt[1][j][n] exactly (token structure is separable).
__global__ __launch_bounds__(256) void cellkv_kernel(
    const float* __restrict__ cell, const float* __restrict__ ipw,
    const float* __restrict__ ipb, float* __restrict__ Pt) {
  int idx = blockIdx.x * 256 + threadIdx.x;
  if (idx >= 2 * HW * 102) return;
  int part = idx / (HW * 102);
  int rem = idx % (HW * 102);
  int a = rem / 102, n = rem % 102;
  float ra = (float)(a / WW) * 0.25f, ca = (float)(a % WW) * 0.25f;
  float acc;
  if (part == 0) {
    acc = ipb[n] + ipw[n * DD + 32] * ra + ipw[n * DD + 33] * ca;
    for (int f = 0; f < CC; f++) acc += ipw[n * DD + f] * cell[a * CC + f];
  } else {
    acc = -(ipw[n * DD + 32] * ra + ipw[n * DD + 33] * ca);
    for (int f = 0; f < CC; f++) acc += ipw[n * DD + CC + f] * cell[a * CC + f];
  }
  Pt[idx] = acc;
}

// ---------------- layer-1 attention via separability ----------------
// score(t,(a,b)) = sigma(t,a)+tau(t,b)  =>  O_t = softmax(sigma)V1 + softmax(tau)V2.
// grid (206, NHEAD); 256 thr = 32 t x (2 parts x 4 a-chunks). Exact fp32.
__global__ __launch_bounds__(256) void attn1_kernel(
    const float* __restrict__ Pt, float* __restrict__ o) {
  __shared__ float sq[2][HW][20], sk[2][HW][20], sv[2][HW][20];
  int t = threadIdx.x;
  int h = blockIdx.y;
  int t0 = blockIdx.x * 32;
  for (int idx = t; idx < 2 * HW * HD; idx += 256) {
    int part = idx / (HW * HD), rem = idx % (HW * HD);
    int a = rem / HD, d = rem % HD;
    const float* base = Pt + (size_t)part * HW * 102 + a * 102;
    sq[part][a][d] = base[h * HD + d];
    sk[part][a][d] = base[DD + h * HD + d];
    sv[part][a][d] = base[2 * DD + h * HD + d];
  }
  __syncthreads();
  int tl = t >> 3, sub = t & 7;
  int p = sub & 1, asp = sub >> 1;
  int tg = t0 + tl;
  int tc = tg < SS ? tg : SS - 1;
  int i = tc / HW, j = tc % HW;
  const float scale = 0.24253562503633297f;
  float q[HD];
#pragma unroll
  for (int d = 0; d < HD; d++) q[d] = (sq[0][i][d] + sq[1][j][d]) * scale;
  float S = 0.f, EV[HD];
#pragma unroll
  for (int d = 0; d < HD; d++) EV[d] = 0.f;
  for (int a = asp; a < HW; a += 4) {
    float s = 0.f;
#pragma unroll
    for (int d = 0; d < HD; d++) s += q[d] * sk[p][a][d];
    float e = __expf(fminf(s, 70.f));
    S += e;
#pragma unroll
    for (int d = 0; d < HD; d++) EV[d] += e * sv[p][a][d];
  }
  // reduce over a-chunks (lane bits 1,2)
  S += __shfl_xor(S, 2); S += __shfl_xor(S, 4);
#pragma unroll
  for (int d = 0; d < HD; d++) { EV[d] += __shfl_xor(EV[d], 2); EV[d] += __shfl_xor(EV[d], 4); }
  // cross-part exchange (lane bit 0) BEFORE any divergent guard
  float So = __shfl_xor(S, 1);
  float EVo[HD];
#pragma unroll
  for (int d = 0; d < HD; d++) EVo[d] = __shfl_xor(EV[d], 1);
  float inv = 1.f / S, invo = 1.f / So;
  if (sub == 0 && tg < SS) {
#pragma unroll
    for (int d = 0; d < HD; d++)
      o[(size_t)tg * DD + h * HD + d] = EV[d] * inv + EVo[d] * invo;
  }
}

// ---------------- layer-2 qkv: K,V cols (34..101) for ALL rows ----------------
__global__ __launch_bounds__(256) void qkv_kv_kernel(
    const float* __restrict__ x, const unsigned short* __restrict__ ipwp,
    const float* __restrict__ ipb, float* __restrict__ qkv) {
  __shared__ __align__(16) unsigned short sxA[32 * 72];
  int t = threadIdx.x;
  int w = t >> 6, lane = t & 63, quad = lane >> 4, col = lane & 15;
  int m0 = (w & 1) * 16, half = w >> 1;
  int row0 = blockIdx.x * 32;
  int nr = min(32, SS - row0);
  for (int i = t; i < 32 * 72; i += 256) sxA[i] = 0;
  __syncthreads();
  for (int i = t; i < nr * DD; i += 256) {
    int r = i / DD, d = i - r * DD;
    sxA[r * 72 + d] = f2b(x[(size_t)row0 * DD + i]);
  }
  __syncthreads();
  bf16x8 a0 = *(const bf16x8*)&sxA[(m0 + col) * 72 + quad * 8];
  bf16x8 a1 = *(const bf16x8*)&sxA[(m0 + col) * 72 + 32 + quad * 8];
  int ntc = half ? 2 : 3;
  for (int nt2 = 0; nt2 < ntc; nt2++) {
    int nt = half * 3 + nt2;           // 0..2 / 3..4
    int n = DD + nt * 16 + col;        // 34..113
    int nc = n < 112 ? n : 111;        // ipwp has 112 rows
    bf16x8 b0 = *(const bf16x8*)&ipwp[nc * 64 + quad * 8];
    bf16x8 b1 = *(const bf16x8*)&ipwp[nc * 64 + 32 + quad * 8];
    f32x4 acc = {0.f, 0.f, 0.f, 0.f};
    acc = __builtin_amdgcn_mfma_f32_16x16x32_bf16(a0, b0, acc, 0, 0, 0);
    acc = __builtin_amdgcn_mfma_f32_16x16x32_bf16(a1, b1, acc, 0, 0, 0);
    if (n < 102) {
      float bias = ipb[n];
#pragma unroll
      for (int r = 0; r < 4; r++) {
        int m = m0 + quad * 4 + r;
        if (m < nr) qkv[(size_t)(row0 + m) * 102 + n] = acc[r] + bias;
      }
    }
  }
}

// ---------------- layer-2 qkv: Q cols (0..33) for 128 rows at runtime base ----------------
__global__ __launch_bounds__(256) void qkv_q_kernel(
    const float* __restrict__ x, const unsigned short* __restrict__ ipwp,
    const float* __restrict__ ipb, const int* __restrict__ abase,
    float* __restrict__ qkv) {
  __shared__ __align__(16) unsigned short sxA[32 * 72];
  int t = threadIdx.x;
  int w = t >> 6, lane = t & 63, quad = lane >> 4, col = lane & 15;
  int m0 = (w & 1) * 16, half = w >> 1;
  int row0 = abase[0] * HW + blockIdx.x * 32;
  for (int i = t; i < 32 * 72; i += 256) sxA[i] = 0;
  __syncthreads();
  for (int i = t; i < 32 * DD; i += 256) {
    int r = i / DD, d = i - r * DD;
    int rr = row0 + r;
    if (rr < SS) sxA[r * 72 + d] = f2b(x[(size_t)rr * DD + d]);
  }
  __syncthreads();
  bf16x8 a0 = *(const bf16x8*)&sxA[(m0 + col) * 72 + quad * 8];
  bf16x8 a1 = *(const bf16x8*)&sxA[(m0 + col) * 72 + 32 + quad * 8];
  int ntc = half ? 1 : 2;
  for (int nt2 = 0; nt2 < ntc; nt2++) {
    int nt = half * 2 + nt2;           // 0,1 / 2
    int n = nt * 16 + col;             // 0..47
    bf16x8 b0 = *(const bf16x8*)&ipwp[n * 64 + quad * 8];
    bf16x8 b1 = *(const bf16x8*)&ipwp[n * 64 + 32 + quad * 8];
    f32x4 acc = {0.f, 0.f, 0.f, 0.f};
    acc = __builtin_amdgcn_mfma_f32_16x16x32_bf16(a0, b0, acc, 0, 0, 0);
    acc = __builtin_amdgcn_mfma_f32_16x16x32_bf16(a1, b1, acc, 0, 0, 0);
    if (n < DD) {
      float bias = ipb[n];
#pragma unroll
      for (int r = 0; r < 4; r++) {
        int m = row0 + m0 + quad * 4 + r;
        if (m < SS) qkv[(size_t)m * 102 + n] = acc[r] + bias;
      }
    }
  }
}

// ---------------- K/V fragment pre-pack (layer 2) ----------------
__global__ __launch_bounds__(256) void kvprep_kernel(
    const float* __restrict__ qkv, unsigned short* __restrict__ kfp,
    unsigned short* __restrict__ vfp, float* __restrict__ v16) {
  const int NK = NHEAD * NTILES * 8 * 512;
  const int NV = NHEAD * NTILES * 4 * 512;
  const int NV16 = NHEAD * NTILES * 128;
  int i = blockIdx.x * 256 + threadIdx.x;
  if (i < NK) {
    int j = i & 7, l = (i >> 3) & 63, nt = (i >> 9) & 7, rest = i >> 12;
    int T = rest % NTILES, h = rest / NTILES;
    int colf = l & 15, quadf = l >> 4;
    int tok = T * 128 + colf * 8 + nt;
    int d = quadf * 8 + j;
    unsigned short v = 0;
    if (tok < SS && d < HD) v = f2b(qkv[(size_t)tok * 102 + DD + h * HD + d]);
    kfp[i] = v;
  } else if (i < NK + NV) {
    int ii = i - NK;
    int j = ii & 7, l = (ii >> 3) & 63, c = (ii >> 9) & 3, rest = ii >> 11;
    int T = rest % NTILES, h = rest / NTILES;
    int colf = l & 15, quadf = l >> 4;
    int tok = T * 128 + c * 32 + quadf * 8 + j;
    unsigned short v = 0;
    if (tok < SS) v = f2b(qkv[(size_t)tok * 102 + 2 * DD + h * HD + colf]);
    vfp[ii] = v;
  } else {
    int ii = i - NK - NV;
    if (ii < NV16) {
      int tl = ii % (NTILES * 128), h = ii / (NTILES * 128);
      v16[ii] = (tl < SS) ? qkv[(size_t)tl * 102 + 2 * DD + h * HD + 16] : 0.f;
    }
  }
}

// ---------------- layer-2 attention: 81 queries at runtime base ----------------
__global__ __launch_bounds__(256) void attn2_kernel(
    const float* __restrict__ qkv, const unsigned short* __restrict__ kfp,
    const unsigned short* __restrict__ vfp, const float* __restrict__ v16,
    const int* __restrict__ abase,
    float* __restrict__ opart, float* __restrict__ lpart) {
  __shared__ __align__(16) unsigned short scb[4][16 * 136];
  int t = threadIdx.x, w = t >> 6, lane = t & 63, quad = lane >> 4, col = lane & 15;
  int h = blockIdx.y, sp = blockIdx.z;
  int base = abase[0] * HW;
  int q0 = blockIdx.x * QB;
  const float scale = 0.24253562503633297f;
  const unsigned short* kf = kfp + (size_t)h * (NTILES * 8 * 512);
  const unsigned short* vf = vfp + (size_t)h * (NTILES * 4 * 512);
  const float* v16h = v16 + (size_t)h * (NTILES * 128);
  unsigned short* myscb = &scb[w][0];

  int mq = base + q0 + w * 16 + col;
  int qc = mq < SS ? mq : SS - 1;
  bf16x8 aq;
#pragma unroll
  for (int j = 0; j < 8; j++) {
    int d = quad * 8 + j;
    aq[j] = (short)((d < HD) ? f2b(qkv[(size_t)qc * 102 + h * HD + d] * scale) : 0);
  }

  f32x4 oacc = {0.f, 0.f, 0.f, 0.f};
  float o16a[4] = {0.f, 0.f, 0.f, 0.f};
  float lreg[4] = {0.f, 0.f, 0.f, 0.f};

  for (int tile = sp; tile < NTILES; tile += NSPLIT2) {
    int k0 = tile * 128;
    const unsigned short* kt = kf + (size_t)tile * (8 * 512);
    f32x4 s[8];
#pragma unroll
    for (int nt = 0; nt < 8; nt++) {
      bf16x8 kb = *(const bf16x8*)(kt + nt * 512 + lane * 8);
      f32x4 z = {0.f, 0.f, 0.f, 0.f};
      s[nt] = __builtin_amdgcn_mfma_f32_16x16x32_bf16(aq, kb, z, 0, 0, 0);
    }
    if (k0 + 128 > SS) {
#pragma unroll
      for (int nt = 0; nt < 8; nt++)
        if (k0 + col * 8 + nt >= SS) {
          s[nt][0] = -1e30f; s[nt][1] = -1e30f; s[nt][2] = -1e30f; s[nt][3] = -1e30f;
        }
    }
#pragma unroll
    for (int r = 0; r < 4; r++) {
      bf16x8 pv;
      float psl = 0.f;
#pragma unroll
      for (int nt = 0; nt < 8; nt++) {
        float p = __expf(fminf(s[nt][r], 70.f));
        s[nt][r] = p;
        psl += p;
        pv[nt] = (short)f2b(p);
      }
      lreg[r] += psl;
      *(bf16x8*)(myscb + (quad * 4 + r) * 136 + col * 8) = pv;
    }
    f32x4 va = *(const f32x4*)(v16h + k0 + col * 8);
    f32x4 vb4 = *(const f32x4*)(v16h + k0 + col * 8 + 4);
#pragma unroll
    for (int r = 0; r < 4; r++) {
      o16a[r] += s[0][r] * va[0] + s[1][r] * va[1] + s[2][r] * va[2] + s[3][r] * va[3]
               + s[4][r] * vb4[0] + s[5][r] * vb4[1] + s[6][r] * vb4[2] + s[7][r] * vb4[3];
    }
    const unsigned short* vt = vf + (size_t)tile * (4 * 512);
#pragma unroll
    for (int c = 0; c < 4; c++) {
      bf16x8 pa = *(const bf16x8*)(myscb + col * 136 + c * 32 + quad * 8);
      bf16x8 vbf = *(const bf16x8*)(vt + c * 512 + lane * 8);
      oacc = __builtin_amdgcn_mfma_f32_16x16x32_bf16(pa, vbf, oacc, 0, 0, 0);
    }
  }
#pragma unroll
  for (int msk = 1; msk <= 8; msk <<= 1)
#pragma unroll
    for (int r = 0; r < 4; r++) {
      o16a[r] += __shfl_xor(o16a[r], msk);
      lreg[r] += __shfl_xor(lreg[r], msk);
    }
  size_t obase = ((size_t)sp * NHEAD + h) * 128;
#pragma unroll
  for (int r = 0; r < 4; r++) {
    int ql = q0 + w * 16 + quad * 4 + r;
    if (ql < HW) {
      opart[(obase + ql) * HD + col] = oacc[r];
      if (col == 0) {
        opart[(obase + ql) * HD + 16] = o16a[r];
        lpart[obase + ql] = lreg[r];
      }
    }
  }
}

// ---------------- layer-1: out_proj (MFMA) + residual + LN1, all rows ----------------
__global__ __launch_bounds__(256) void proj_ln1_l1_kernel(
    const float* __restrict__ o, const unsigned short* __restrict__ opwp,
    const float* __restrict__ opb, const float* __restrict__ g,
    const float* __restrict__ b, float* __restrict__ x) {
  __shared__ __align__(16) unsigned short soA[32 * 72];
  int t = threadIdx.x;
  int w = t >> 6, lane = t & 63, quad = lane >> 4, col = lane & 15;
  int r0 = blockIdx.x * 32;
  int nr = min(32, SS - r0);
  for (int i = t; i < 32 * 72; i += 256) soA[i] = 0;
  __syncthreads();
  for (int i = t; i < nr * DD; i += 256) {
    int r = i / DD, rem = i - r * DD;
    soA[r * 72 + rem] = f2b(o[(size_t)(r0 + r) * DD + rem]);
  }
  __syncthreads();
  if (w < 2) {
    int m0 = w * 16;
    bf16x8 a0 = *(const bf16x8*)&soA[(m0 + col) * 72 + quad * 8];
    bf16x8 a1 = *(const bf16x8*)&soA[(m0 + col) * 72 + 32 + quad * 8];
    f32x4 y[3];
#pragma unroll
    for (int nt = 0; nt < 3; nt++) {
      int n = nt * 16 + col;
      bf16x8 b0 = *(const bf16x8*)&opwp[n * 64 + quad * 8];
      bf16x8 b1 = *(const bf16x8*)&opwp[n * 64 + 32 + quad * 8];
      f32x4 acc = {0.f, 0.f, 0.f, 0.f};
      acc = __builtin_amdgcn_mfma_f32_16x16x32_bf16(a0, b0, acc, 0, 0, 0);
      y[nt] = __builtin_amdgcn_mfma_f32_16x16x32_bf16(a1, b1, acc, 0, 0, 0);
    }
    float yv[3][4];
    float s1[4] = {0.f, 0.f, 0.f, 0.f}, s2[4] = {0.f, 0.f, 0.f, 0.f};
#pragma unroll
    for (int nt = 0; nt < 3; nt++) {
      int d = nt * 16 + col;
      bool vd = d < DD;
      float ob = vd ? opb[d] : 0.f;
#pragma unroll
      for (int r = 0; r < 4; r++) {
        int row = r0 + m0 + quad * 4 + r;
        float v = 0.f;
        if (vd && row < SS) v = y[nt][r] + ob + x[(size_t)row * DD + d];
        yv[nt][r] = v;
        s1[r] += v;
        s2[r] += v * v;
      }
    }
#pragma unroll
    for (int msk = 1; msk <= 8; msk <<= 1)
#pragma unroll
      for (int r = 0; r < 4; r++) {
        s1[r] += __shfl_xor(s1[r], msk);
        s2[r] += __shfl_xor(s2[r], msk);
      }
#pragma unroll
    for (int r = 0; r < 4; r++) {
      int row = r0 + m0 + quad * 4 + r;
      if (row >= SS) continue;
      float mean = s1[r] * (1.f / DD);
      float var = s2[r] * (1.f / DD) - mean * mean;
      float rs = rsqrtf(var + EPSF);
#pragma unroll
      for (int nt = 0; nt < 3; nt++) {
        int d = nt * 16 + col;
        if (d < DD)
          x[(size_t)row * DD + d] = (yv[nt][r] - mean) * rs * g[d] + b[d];
      }
    }
  }
}

// ---------------- layer-2: combine(26) + out_proj + residual + LN1, 81 rows ----------------
__global__ __launch_bounds__(256) void proj_ln1_l2_kernel(
    const float* __restrict__ opart, const float* __restrict__ lpart,
    const unsigned short* __restrict__ opwp, const float* __restrict__ opb,
    const float* __restrict__ g, const float* __restrict__ b,
    const int* __restrict__ abase, float* __restrict__ x) {
  __shared__ __align__(16) unsigned short soA[32 * 72];
  int t = threadIdx.x;
  int w = t >> 6, lane = t & 63, quad = lane >> 4, col = lane & 15;
  int base = abase[0] * HW;
  int ql0 = blockIdx.x * 32;
  int nr = min(32, HW - ql0);
  int r0 = base + ql0;
  for (int i = t; i < 32 * 72; i += 256) soA[i] = 0;
  __syncthreads();
  for (int i = t; i < nr * DD; i += 256) {
    int r = i / DD, rem = i - r * DD;
    int ql = ql0 + r;
    int h = rem / HD, d = rem - h * HD;
    float L = 0.f, O = 0.f;
#pragma unroll
    for (int s = 0; s < NSPLIT2; s++) {
      L += lpart[((size_t)s * NHEAD + h) * 128 + ql];
      O += opart[(((size_t)s * NHEAD + h) * 128 + ql) * HD + d];
    }
    soA[r * 72 + rem] = f2b(O / L);
  }
  __syncthreads();
  if (w < 2) {
    int m0 = w * 16;
    bf16x8 a0 = *(const bf16x8*)&soA[(m0 + col) * 72 + quad * 8];
    bf16x8 a1 = *(const bf16x8*)&soA[(m0 + col) * 72 + 32 + quad * 8];
    f32x4 y[3];
#pragma unroll
    for (int nt = 0; nt < 3; nt++) {
      int n = nt * 16 + col;
      bf16x8 b0 = *(const bf16x8*)&opwp[n * 64 + quad * 8];
      bf16x8 b1 = *(const bf16x8*)&opwp[n * 64 + 32 + quad * 8];
      f32x4 acc = {0.f, 0.f, 0.f, 0.f};
      acc = __builtin_amdgcn_mfma_f32_16x16x32_bf16(a0, b0, acc, 0, 0, 0);
      y[nt] = __builtin_amdgcn_mfma_f32_16x16x32_bf16(a1, b1, acc, 0, 0, 0);
    }
    float yv[3][4];
    float s1[4] = {0.f, 0.f, 0.f, 0.f}, s2[4] = {0.f, 0.f, 0.f, 0.f};
#pragma unroll
    for (int nt = 0; nt < 3; nt++) {
      int d = nt * 16 + col;
      bool vd = d < DD;
      float ob = vd ? opb[d] : 0.f;
#pragma unroll
      for (int r = 0; r < 4; r++) {
        int lr = m0 + quad * 4 + r;
        float v = 0.f;
        if (vd && lr < nr) v = y[nt][r] + ob + x[(size_t)(r0 + lr) * DD + d];
        yv[nt][r] = v;
        s1[r] += v;
        s2[r] += v * v;
      }
    }
#pragma unroll
    for (int msk = 1; msk <= 8; msk <<= 1)
#pragma unroll
      for (int r = 0; r < 4; r++) {
        s1[r] += __shfl_xor(s1[r], msk);
        s2[r] += __shfl_xor(s2[r], msk);
      }
#pragma unroll
    for (int r = 0; r < 4; r++) {
      int lr = m0 + quad * 4 + r;
      if (lr >= nr) continue;
      float mean = s1[r] * (1.f / DD);
      float var = s2[r] * (1.f / DD) - mean * mean;
      float rs = rsqrtf(var + EPSF);
#pragma unroll
      for (int nt = 0; nt < 3; nt++) {
        int d = nt * 16 + col;
        if (d < DD)
          x[(size_t)(r0 + lr) * DD + d] = (yv[nt][r] - mean) * rs * g[d] + b[d];
      }
    }
  }
}

// ---------------- MFMA FF + residual + LN2 (full or 81-row slice) ----------------
__global__ __launch_bounds__(256) void ff_mfma_kernel(
    float* __restrict__ x, const unsigned short* __restrict__ w1p,
    const unsigned short* __restrict__ w2p, const float* __restrict__ b1g,
    const float* __restrict__ b2g, const float* __restrict__ g,
    const float* __restrict__ bb, const int* __restrict__ abase) {
  __shared__ __align__(16) unsigned short sxA[16 * 72];
  __shared__ float sxF[16][35];
  __shared__ __align__(16) unsigned short hw_[4][16 * 40];
  __shared__ float yred[4][16][49];
  int t = threadIdx.x;
  int w = t >> 6, lane = t & 63, quad = lane >> 4, col = lane & 15;
  int b0 = abase ? abase[0] * HW : 0;
  int limit = abase ? HW : SS;
  int ql0 = blockIdx.x * 16;
  int nr = min(16, limit - ql0);
  int r0 = b0 + ql0;

  for (int i = t; i < 16 * 72; i += 256) sxA[i] = 0;
  for (int i = t; i < 16 * 35; i += 256) ((float*)sxF)[i] = 0.f;
  __syncthreads();
  for (int i = t; i < nr * DD; i += 256) {
    int r = i / DD, d = i - r * DD;
    float v = x[(size_t)(r0 + r) * DD + d];
    sxF[r][d] = v;
    sxA[r * 72 + d] = f2b(v);
  }
  __syncthreads();

  bf16x8 a0 = *(const bf16x8*)&sxA[col * 72 + quad * 8];
  bf16x8 a1 = *(const bf16x8*)&sxA[col * 72 + 32 + quad * 8];
  unsigned short* myh = &hw_[w][0];
  f32x4 acc3[3];
#pragma unroll
  for (int nt = 0; nt < 3; nt++) acc3[nt] = (f32x4){0.f, 0.f, 0.f, 0.f};

  for (int kt = 0; kt < 16; kt++) {
    int fbase = kt * 128 + w * 32;
#pragma unroll
    for (int nt = 0; nt < 2; nt++) {
      int f = fbase + nt * 16 + col;
      bf16x8 b0f = *(const bf16x8*)&w1p[f * 64 + quad * 8];
      bf16x8 b1f = *(const bf16x8*)&w1p[f * 64 + 32 + quad * 8];
      f32x4 hacc = {0.f, 0.f, 0.f, 0.f};
      hacc = __builtin_amdgcn_mfma_f32_16x16x32_bf16(a0, b0f, hacc, 0, 0, 0);
      hacc = __builtin_amdgcn_mfma_f32_16x16x32_bf16(a1, b1f, hacc, 0, 0, 0);
      float bias = b1g[f];
#pragma unroll
      for (int r = 0; r < 4; r++) {
        float hv = fmaxf(hacc[r] + bias, 0.f);
        myh[(quad * 4 + r) * 40 + nt * 16 + col] = f2b(hv);
      }
    }
    bf16x8 pa = *(const bf16x8*)&myh[col * 40 + quad * 8];
#pragma unroll
    for (int nt = 0; nt < 3; nt++) {
      int n = nt * 16 + col;
      bf16x8 wb = *(const bf16x8*)&w2p[(size_t)n * FF + fbase + quad * 8];
      acc3[nt] = __builtin_amdgcn_mfma_f32_16x16x32_bf16(pa, wb, acc3[nt], 0, 0, 0);
    }
  }

#pragma unroll
  for (int nt = 0; nt < 3; nt++)
#pragma unroll
    for (int r = 0; r < 4; r++)
      yred[w][quad * 4 + r][nt * 16 + col] = acc3[nt][r];
  __syncthreads();
  if (w == 0) {
    float yv[3][4];
    float s1[4] = {0.f, 0.f, 0.f, 0.f}, s2[4] = {0.f, 0.f, 0.f, 0.f};
#pragma unroll
    for (int nt = 0; nt < 3; nt++) {
      int d = nt * 16 + col;
      bool valid = d < DD;
      float b2v = valid ? b2g[d] : 0.f;
#pragma unroll
      for (int r = 0; r < 4; r++) {
        int row = quad * 4 + r;
        float v = yred[0][row][nt * 16 + col] + yred[1][row][nt * 16 + col]
                + yred[2][row][nt * 16 + col] + yred[3][row][nt * 16 + col];
        v = valid ? (v + b2v + sxF[row][d]) : 0.f;
        yv[nt][r] = v;
        s1[r] += v;
        s2[r] += v * v;
      }
    }
#pragma unroll
    for (int msk = 1; msk <= 8; msk <<= 1)
#pragma unroll
      for (int r = 0; r < 4; r++) {
        s1[r] += __shfl_xor(s1[r], msk);
        s2[r] += __shfl_xor(s2[r], msk);
      }
#pragma unroll
    for (int r = 0; r < 4; r++) {
      int row = quad * 4 + r;
      if (row >= nr) continue;
      float mean = s1[r] * (1.f / DD);
      float var = s2[r] * (1.f / DD) - mean * mean;
      float rs = rsqrtf(var + EPSF);
#pragma unroll
      for (int nt = 0; nt < 3; nt++) {
        int d = nt * 16 + col;
        if (d < DD)
          x[(size_t)(r0 + row) * DD + d] = (yv[nt][r] - mean) * rs * g[d] + bb[d];
      }
    }
  }
}

// ---------------- final ----------------
__global__ __launch_bounds__(64) void final_kernel(
    const float* __restrict__ x, const int* __restrict__ aidx, float* __restrict__ out) {
  int d = threadIdx.x;
  if (d >= DD) return;
  int start = (*aidx) * HW;
  float acc = 0.f;
  for (int j = 0; j < HW; j++) acc += x[(size_t)(start + j) * DD + d];
  out[d] = acc * (1.f / HW);
}

extern "C" void kernel_launch(void* const* d_in, const int* in_sizes, int n_in,
                              void* d_out, int out_size, void* d_ws, size_t ws_size,
                              hipStream_t stream) {
  const float* obs = (const float*)d_in[0];
  const float* c1w = (const float*)d_in[1];
  const float* c1b = (const float*)d_in[2];
  const float* c2w = (const float*)d_in[3];
  const float* c2b = (const float*)d_in[4];
  const float* ipw = (const float*)d_in[5];
  const float* ipb = (const float*)d_in[6];
  const float* opw = (const float*)d_in[7];
  const float* opb = (const float*)d_in[8];
  const float* l1w = (const float*)d_in[9];
  const float* l1b = (const float*)d_in[10];
  const float* l2w = (const float*)d_in[11];
  const float* l2b = (const float*)d_in[12];
  const float* g1 = (const float*)d_in[13];
  const float* b1 = (const float*)d_in[14];
  const float* g2 = (const float*)d_in[15];
  const float* b2 = (const float*)d_in[16];
  float* out = (float*)d_out;

  float* ws = (float*)d_ws;
  size_t off = 0;
  float* x     = ws + off; off += SS * DD;
  float* qkv   = ws + off; off += SS * 102;
  float* cell  = ws + off; off += HW * CC;
  int*   aidx  = (int*)(ws + off); off += 1;
  off = (off + 3) & ~(size_t)3;
  float* o     = ws + off; off += SS * DD;
  float* Pt    = ws + off; off += 2 * HW * 102;
  float* opart = ws + off; off += (size_t)NSPLIT2 * NHEAD * 128 * HD;
  float* lpart = ws + off; off += (size_t)NSPLIT2 * NHEAD * 128;
  off = (off + 3) & ~(size_t)3;
  unsigned short* kfp  = (unsigned short*)(ws + off); off += (NHEAD * NTILES * 8 * 512) / 2;
  unsigned short* vfp  = (unsigned short*)(ws + off); off += (NHEAD * NTILES * 4 * 512) / 2;
  float* v16 = ws + off; off += NHEAD * NTILES * 128;
  unsigned short* ipwp = (unsigned short*)(ws + off); off += 7168 / 2;
  unsigned short* opwp = (unsigned short*)(ws + off); off += 3072 / 2;
  unsigned short* w1p  = (unsigned short*)(ws + off); off += (FF * 64) / 2;
  unsigned short* w2p  = (unsigned short*)(ws + off); off += (48 * FF) / 2;

  const int row32_blocks = (SS + 31) / 32;   // 206
  const int row16_blocks = (SS + 15) / 16;   // 411
  const int lprep_blocks = (7168 + 3072 + FF * 64 + 48 * FF + 255) / 256;
  const int kvprep_elems = NHEAD * NTILES * (8 * 512 + 4 * 512 + 128);
  const int kvprep_blocks = (kvprep_elems + 255) / 256;
  const int cellkv_blocks = (2 * HW * 102 + 255) / 256;  // 65

  prep_kernel<<<1, 256, 0, stream>>>(obs, c1w, c1b, c2w, c2b, cell, aidx);
  tokens_kernel<<<(SS * DD + 255) / 256, 256, 0, stream>>>(cell, x);

  // ---- layer 1 (separable attention; no full qkv needed) ----
  lprep_kernel<<<lprep_blocks, 256, 0, stream>>>(
      ipw, opw, l1w, l2w, ipwp, opwp, w1p, w2p);
  cellkv_kernel<<<cellkv_blocks, 256, 0, stream>>>(cell, ipw, ipb, Pt);
  dim3 a1g(row32_blocks, NHEAD);
  attn1_kernel<<<a1g, 256, 0, stream>>>(Pt, o);
  proj_ln1_l1_kernel<<<row32_blocks, 256, 0, stream>>>(
      o, opwp, opb, g1, b1, x);
  ff_mfma_kernel<<<row16_blocks, 256, 0, stream>>>(
      x, w1p, w2p, l1b, l2b, g2, b2, (const int*)nullptr);

  // ---- layer 2 (output-sliced: 81 queries / 81 rows) ----
  lprep_kernel<<<lprep_blocks, 256, 0, stream>>>(
      ipw + (size_t)102 * DD, opw + (size_t)DD * DD,
      l1w + (size_t)FF * DD, l2w + (size_t)DD * FF, ipwp, opwp, w1p, w2p);
  qkv_kv_kernel<<<row32_blocks, 256, 0, stream>>>(x, ipwp, ipb + 102, qkv);
  qkv_q_kernel<<<4, 256, 0, stream>>>(x, ipwp, ipb + 102, aidx, qkv);
  kvprep_kernel<<<kvprep_blocks, 256, 0, stream>>>(qkv, kfp, vfp, v16);
  dim3 a2g(2, NHEAD, NSPLIT2);
  attn2_kernel<<<a2g, 256, 0, stream>>>(qkv, kfp, vfp, v16, aidx, opart, lpart);
  proj_ln1_l2_kernel<<<3, 256, 0, stream>>>(
      opart, lpart, opwp, opb + DD, g1 + DD, b1 + DD, aidx, x);
  ff_mfma_kernel<<<6, 256, 0, stream>>>(
      x, w1p, w2p, l1b + FF, l2b + DD, g2 + DD, b2 + DD, aidx);

  final_kernel<<<1, 64, 0, stream>>>(x, aidx, out);
}

// Round 10
// 230.316 us; speedup vs baseline: 12.8156x; 1.1250x over previous
//
#include <hip/hip_runtime.h>
#include <hip/hip_bf16.h>

#define HH 9
#define WW 9
#define HW 81
#define CC 16
#define DD 34
#define SS 6561
#define NHEAD 2
#define HD 17
#define FF 2048
#define EPSF 1e-5f

#define NTILES 52
#define NSPLIT2 26
#define QB 64

// per-layer packed-weight sizes (shorts)
#define NIP 7168     // 112 x 64
#define NOP 3072     // 48 x 64
#define NW1 131072   // 2048 x 64
#define NW2 98304    // 48 x 2048
#define NLTOT (NIP + NOP + NW1 + NW2)

typedef __attribute__((ext_vector_type(8))) short bf16x8;
typedef __attribute__((ext_vector_type(4))) float f32x4;

__device__ __forceinline__ unsigned short f2b(float f) {
  unsigned int u = __float_as_uint(f);
  u += 0x7fffu + ((u >> 16) & 1u);
  return (unsigned short)(u >> 16);
}

// ---------------- conv1 + conv2 + argmax: branch-free via zero halos ----------------
__global__ __launch_bounds__(256) void prep_kernel(
    const float* __restrict__ obs, const float* __restrict__ w1, const float* __restrict__ b1,
    const float* __restrict__ w2, const float* __restrict__ b2,
    float* __restrict__ cell, int* __restrict__ aidx) {
  __shared__ float s_obs[2][11][11];   // zero halo -> SAME padding, no branches
  __shared__ float s_w1[288];
  __shared__ float s_w2[2304];
  __shared__ float s_b1[16], s_b2[16];
  __shared__ float y1[CC][121];        // padded 11x11
  int t = threadIdx.x;
  for (int i = t; i < 2 * 121; i += 256) ((float*)s_obs)[i] = 0.f;
  for (int i = t; i < CC * 121; i += 256) ((float*)y1)[i] = 0.f;
  for (int i = t; i < 288; i += 256) s_w1[i] = w1[i];
  for (int i = t; i < 2304; i += 256) s_w2[i] = w2[i];
  if (t < 16) { s_b1[t] = b1[t]; s_b2[t] = b2[t]; }
  __syncthreads();
  for (int i = t; i < 2 * HW; i += 256) {
    int ic = i / HW, p = i % HW;
    s_obs[ic][1 + p / WW][1 + p % WW] = obs[i];
  }
  __syncthreads();
  if (t == 0) {  // first-max argmax (order matters for ties)
    int best = 0; float bv = s_obs[0][1][1];
    for (int p = 1; p < HW; p++) {
      float v = s_obs[0][1 + p / WW][1 + p % WW];
      if (v > bv) { bv = v; best = p; }
    }
    *aidx = best;
  }
  for (int idx = t; idx < CC * HW; idx += 256) {
    int c = idx / HW, p = idx % HW;
    int i = p / WW, j = p % WW;
    float acc = s_b1[c];
#pragma unroll
    for (int ic = 0; ic < 2; ic++)
#pragma unroll
      for (int di = 0; di < 3; di++)
#pragma unroll
        for (int dj = 0; dj < 3; dj++)
          acc += s_obs[ic][i + di][j + dj] * s_w1[((c * 2 + ic) * 3 + di) * 3 + dj];
    y1[c][(i + 1) * 11 + (j + 1)] = fmaxf(acc, 0.f);
  }
  __syncthreads();
  for (int idx = t; idx < CC * HW; idx += 256) {
    int c = idx / HW, p = idx % HW;
    int i = p / WW, j = p % WW;
    float acc = s_b2[c];
#pragma unroll
    for (int ic = 0; ic < CC; ic++)
#pragma unroll
      for (int di = 0; di < 3; di++)
#pragma unroll
        for (int dj = 0; dj < 3; dj++)
          acc += y1[ic][(i + di) * 11 + (j + dj)] * s_w2[((c * CC + ic) * 3 + di) * 3 + dj];
    cell[p * CC + c] = fmaxf(acc, 0.f);
  }
}

// ---------------- token build + layer-1 separable qkv tables (merged) ----------------
__global__ __launch_bounds__(256) void tokcell_kernel(
    const float* __restrict__ cell, const float* __restrict__ ipw,
    const float* __restrict__ ipb, float* __restrict__ x, float* __restrict__ Pt) {
  int idx = blockIdx.x * 256 + threadIdx.x;
  if (idx < SS * DD) {
    int row = idx / DD, d = idx - row * DD;
    int i = row / HW, j = row - i * HW;
    float v;
    if (d < CC) v = cell[i * CC + d];
    else if (d < 2 * CC) v = cell[j * CC + (d - CC)];
    else if (d == 32) v = (float)((i / WW) - (j / WW)) * 0.25f;
    else v = (float)((i % WW) - (j % WW)) * 0.25f;
    x[idx] = v;
    return;
  }
  int pidx = idx - SS * DD;
  if (pidx >= 2 * HW * 102) return;
  int part = pidx / (HW * 102);
  int rem = pidx % (HW * 102);
  int a = rem / 102, n = rem % 102;
  float ra = (float)(a / WW) * 0.25f, ca = (float)(a % WW) * 0.25f;
  float acc;
  if (part == 0) {
    acc = ipb[n] + ipw[n * DD + 32] * ra + ipw[n * DD + 33] * ca;
    for (int f = 0; f < CC; f++) acc += ipw[n * DD + f] * cell[a * CC + f];
  } else {
    acc = -(ipw[n * DD + 32] * ra + ipw[n * DD + 33] * ca);
    for (int f = 0; f < CC; f++) acc += ipw[n * DD + CC + f] * cell[a * CC + f];
  }
  Pt[pidx] = acc;
}

// ---------------- both-layer weight pack (single launch) ----------------
__global__ __launch_bounds__(256) void lprep_kernel(
    const float* __restrict__ ipw, const float* __restrict__ opw,
    const float* __restrict__ w1, const float* __restrict__ w2,
    unsigned short* __restrict__ ipwp, unsigned short* __restrict__ opwp,
    unsigned short* __restrict__ w1p, unsigned short* __restrict__ w2p) {
  int i = blockIdx.x * 256 + threadIdx.x;
  if (i >= 2 * NLTOT) return;
  int layer = i / NLTOT;
  int r = i % NLTOT;
  if (r < NIP) {
    int n = r >> 6, k = r & 63;
    ipwp[layer * NIP + r] =
        (n < 102 && k < DD) ? f2b(ipw[(size_t)layer * 102 * DD + n * DD + k]) : (unsigned short)0;
  } else if (r < NIP + NOP) {
    int rr = r - NIP;
    int n = rr >> 6, k = rr & 63;
    opwp[layer * NOP + rr] =
        (n < DD && k < DD) ? f2b(opw[(size_t)layer * DD * DD + n * DD + k]) : (unsigned short)0;
  } else if (r < NIP + NOP + NW1) {
    int rr = r - NIP - NOP;
    int f = rr >> 6, k = rr & 63;
    w1p[layer * NW1 + rr] =
        (k < DD) ? f2b(w1[(size_t)layer * FF * DD + f * DD + k]) : (unsigned short)0;
  } else {
    int rr = r - NIP - NOP - NW1;
    int d = rr >> 11, kk = rr & 2047;
    w2p[layer * NW2 + rr] =
        (d < DD) ? f2b(w2[(size_t)layer * DD * FF + d * FF + kk]) : (unsigned short)0;
  }
}

// ---------------- layer-1 attention via separability (exact fp32) ----------------
__global__ __launch_bounds__(256) void attn1_kernel(
    const float* __restrict__ Pt, float* __restrict__ o) {
  __shared__ float sq[2][HW][20], sk[2][HW][20], sv[2][HW][20];
  int t = threadIdx.x;
  int h = blockIdx.y;
  int t0 = blockIdx.x * 32;
  for (int idx = t; idx < 2 * HW * HD; idx += 256) {
    int part = idx / (HW * HD), rem = idx % (HW * HD);
    int a = rem / HD, d = rem % HD;
    const float* base = Pt + (size_t)part * HW * 102 + a * 102;
    sq[part][a][d] = base[h * HD + d];
    sk[part][a][d] = base[DD + h * HD + d];
    sv[part][a][d] = base[2 * DD + h * HD + d];
  }
  __syncthreads();
  int tl = t >> 3, sub = t & 7;
  int p = sub & 1, asp = sub >> 1;
  int tg = t0 + tl;
  int tc = tg < SS ? tg : SS - 1;
  int i = tc / HW, j = tc % HW;
  const float scale = 0.24253562503633297f;
  float q[HD];
#pragma unroll
  for (int d = 0; d < HD; d++) q[d] = (sq[0][i][d] + sq[1][j][d]) * scale;
  float S = 0.f, EV[HD];
#pragma unroll
  for (int d = 0; d < HD; d++) EV[d] = 0.f;
  for (int a = asp; a < HW; a += 4) {
    float s = 0.f;
#pragma unroll
    for (int d = 0; d < HD; d++) s += q[d] * sk[p][a][d];
    float e = __expf(fminf(s, 70.f));
    S += e;
#pragma unroll
    for (int d = 0; d < HD; d++) EV[d] += e * sv[p][a][d];
  }
  S += __shfl_xor(S, 2); S += __shfl_xor(S, 4);
#pragma unroll
  for (int d = 0; d < HD; d++) { EV[d] += __shfl_xor(EV[d], 2); EV[d] += __shfl_xor(EV[d], 4); }
  float So = __shfl_xor(S, 1);
  float EVo[HD];
#pragma unroll
  for (int d = 0; d < HD; d++) EVo[d] = __shfl_xor(EV[d], 1);
  float inv = 1.f / S, invo = 1.f / So;
  if (sub == 0 && tg < SS) {
#pragma unroll
    for (int d = 0; d < HD; d++)
      o[(size_t)tg * DD + h * HD + d] = EV[d] * inv + EVo[d] * invo;
  }
}

// ---------------- layer-2 qkv merged: KV all rows (blocks 0..205) + Q 128 rows (206..209) ----
__global__ __launch_bounds__(256) void qkv2_kernel(
    const float* __restrict__ x, const unsigned short* __restrict__ ipwp,
    const float* __restrict__ ipb, const int* __restrict__ abase,
    float* __restrict__ qkv) {
  __shared__ __align__(16) unsigned short sxA[32 * 72];
  int t = threadIdx.x;
  int w = t >> 6, lane = t & 63, quad = lane >> 4, col = lane & 15;
  int m0 = (w & 1) * 16, half = w >> 1;
  bool qpart = blockIdx.x >= 206;
  int row0 = qpart ? (abase[0] * HW + (blockIdx.x - 206) * 32) : blockIdx.x * 32;
  int nr = min(32, SS - row0);
  for (int i = t; i < 32 * 72; i += 256) sxA[i] = 0;
  __syncthreads();
  for (int i = t; i < nr * DD; i += 256) {
    int r = i / DD, d = i - r * DD;
    sxA[r * 72 + d] = f2b(x[(size_t)(row0 + r) * DD + d]);
  }
  __syncthreads();
  bf16x8 a0 = *(const bf16x8*)&sxA[(m0 + col) * 72 + quad * 8];
  bf16x8 a1 = *(const bf16x8*)&sxA[(m0 + col) * 72 + 32 + quad * 8];
  if (!qpart) {
    int ntc = half ? 2 : 3;
    for (int nt2 = 0; nt2 < ntc; nt2++) {
      int nt = half * 3 + nt2;
      int n = DD + nt * 16 + col;       // 34..113
      int nc = n < 112 ? n : 111;
      bf16x8 b0 = *(const bf16x8*)&ipwp[nc * 64 + quad * 8];
      bf16x8 b1 = *(const bf16x8*)&ipwp[nc * 64 + 32 + quad * 8];
      f32x4 acc = {0.f, 0.f, 0.f, 0.f};
      acc = __builtin_amdgcn_mfma_f32_16x16x32_bf16(a0, b0, acc, 0, 0, 0);
      acc = __builtin_amdgcn_mfma_f32_16x16x32_bf16(a1, b1, acc, 0, 0, 0);
      if (n < 102) {
        float bias = ipb[n];
#pragma unroll
        for (int r = 0; r < 4; r++) {
          int m = m0 + quad * 4 + r;
          if (m < nr) qkv[(size_t)(row0 + m) * 102 + n] = acc[r] + bias;
        }
      }
    }
  } else {
    int ntc = half ? 1 : 2;
    for (int nt2 = 0; nt2 < ntc; nt2++) {
      int nt = half * 2 + nt2;
      int n = nt * 16 + col;            // 0..47
      bf16x8 b0 = *(const bf16x8*)&ipwp[n * 64 + quad * 8];
      bf16x8 b1 = *(const bf16x8*)&ipwp[n * 64 + 32 + quad * 8];
      f32x4 acc = {0.f, 0.f, 0.f, 0.f};
      acc = __builtin_amdgcn_mfma_f32_16x16x32_bf16(a0, b0, acc, 0, 0, 0);
      acc = __builtin_amdgcn_mfma_f32_16x16x32_bf16(a1, b1, acc, 0, 0, 0);
      if (n < DD) {
        float bias = ipb[n];
#pragma unroll
        for (int r = 0; r < 4; r++) {
          int m = row0 + m0 + quad * 4 + r;
          if (m < SS) qkv[(size_t)m * 102 + n] = acc[r] + bias;
        }
      }
    }
  }
}

// ---------------- K/V fragment pre-pack (layer 2) ----------------
__global__ __launch_bounds__(256) void kvprep_kernel(
    const float* __restrict__ qkv, unsigned short* __restrict__ kfp,
    unsigned short* __restrict__ vfp, float* __restrict__ v16) {
  const int NK = NHEAD * NTILES * 8 * 512;
  const int NV = NHEAD * NTILES * 4 * 512;
  const int NV16 = NHEAD * NTILES * 128;
  int i = blockIdx.x * 256 + threadIdx.x;
  if (i < NK) {
    int j = i & 7, l = (i >> 3) & 63, nt = (i >> 9) & 7, rest = i >> 12;
    int T = rest % NTILES, h = rest / NTILES;
    int colf = l & 15, quadf = l >> 4;
    int tok = T * 128 + colf * 8 + nt;
    int d = quadf * 8 + j;
    unsigned short v = 0;
    if (tok < SS && d < HD) v = f2b(qkv[(size_t)tok * 102 + DD + h * HD + d]);
    kfp[i] = v;
  } else if (i < NK + NV) {
    int ii = i - NK;
    int j = ii & 7, l = (ii >> 3) & 63, c = (ii >> 9) & 3, rest = ii >> 11;
    int T = rest % NTILES, h = rest / NTILES;
    int colf = l & 15, quadf = l >> 4;
    int tok = T * 128 + c * 32 + quadf * 8 + j;
    unsigned short v = 0;
    if (tok < SS) v = f2b(qkv[(size_t)tok * 102 + 2 * DD + h * HD + colf]);
    vfp[ii] = v;
  } else {
    int ii = i - NK - NV;
    if (ii < NV16) {
      int tl = ii % (NTILES * 128), h = ii / (NTILES * 128);
      v16[ii] = (tl < SS) ? qkv[(size_t)tl * 102 + 2 * DD + h * HD + 16] : 0.f;
    }
  }
}

// ---------------- layer-2 attention: 81 queries at runtime base ----------------
__global__ __launch_bounds__(256) void attn2_kernel(
    const float* __restrict__ qkv, const unsigned short* __restrict__ kfp,
    const unsigned short* __restrict__ vfp, const float* __restrict__ v16,
    const int* __restrict__ abase,
    float* __restrict__ opart, float* __restrict__ lpart) {
  __shared__ __align__(16) unsigned short scb[4][16 * 136];
  int t = threadIdx.x, w = t >> 6, lane = t & 63, quad = lane >> 4, col = lane & 15;
  int h = blockIdx.y, sp = blockIdx.z;
  int base = abase[0] * HW;
  int q0 = blockIdx.x * QB;
  const float scale = 0.24253562503633297f;
  const unsigned short* kf = kfp + (size_t)h * (NTILES * 8 * 512);
  const unsigned short* vf = vfp + (size_t)h * (NTILES * 4 * 512);
  const float* v16h = v16 + (size_t)h * (NTILES * 128);
  unsigned short* myscb = &scb[w][0];

  int mq = base + q0 + w * 16 + col;
  int qc = mq < SS ? mq : SS - 1;
  bf16x8 aq;
#pragma unroll
  for (int j = 0; j < 8; j++) {
    int d = quad * 8 + j;
    aq[j] = (short)((d < HD) ? f2b(qkv[(size_t)qc * 102 + h * HD + d] * scale) : 0);
  }

  f32x4 oacc = {0.f, 0.f, 0.f, 0.f};
  float o16a[4] = {0.f, 0.f, 0.f, 0.f};
  float lreg[4] = {0.f, 0.f, 0.f, 0.f};

  for (int tile = sp; tile < NTILES; tile += NSPLIT2) {
    int k0 = tile * 128;
    const unsigned short* kt = kf + (size_t)tile * (8 * 512);
    f32x4 s[8];
#pragma unroll
    for (int nt = 0; nt < 8; nt++) {
      bf16x8 kb = *(const bf16x8*)(kt + nt * 512 + lane * 8);
      f32x4 z = {0.f, 0.f, 0.f, 0.f};
      s[nt] = __builtin_amdgcn_mfma_f32_16x16x32_bf16(aq, kb, z, 0, 0, 0);
    }
    if (k0 + 128 > SS) {
#pragma unroll
      for (int nt = 0; nt < 8; nt++)
        if (k0 + col * 8 + nt >= SS) {
          s[nt][0] = -1e30f; s[nt][1] = -1e30f; s[nt][2] = -1e30f; s[nt][3] = -1e30f;
        }
    }
#pragma unroll
    for (int r = 0; r < 4; r++) {
      bf16x8 pv;
      float psl = 0.f;
#pragma unroll
      for (int nt = 0; nt < 8; nt++) {
        float p = __expf(fminf(s[nt][r], 70.f));
        s[nt][r] = p;
        psl += p;
        pv[nt] = (short)f2b(p);
      }
      lreg[r] += psl;
      *(bf16x8*)(myscb + (quad * 4 + r) * 136 + col * 8) = pv;
    }
    f32x4 va = *(const f32x4*)(v16h + k0 + col * 8);
    f32x4 vb4 = *(const f32x4*)(v16h + k0 + col * 8 + 4);
#pragma unroll
    for (int r = 0; r < 4; r++) {
      o16a[r] += s[0][r] * va[0] + s[1][r] * va[1] + s[2][r] * va[2] + s[3][r] * va[3]
               + s[4][r] * vb4[0] + s[5][r] * vb4[1] + s[6][r] * vb4[2] + s[7][r] * vb4[3];
    }
    const unsigned short* vt = vf + (size_t)tile * (4 * 512);
#pragma unroll
    for (int c = 0; c < 4; c++) {
      bf16x8 pa = *(const bf16x8*)(myscb + col * 136 + c * 32 + quad * 8);
      bf16x8 vbf = *(const bf16x8*)(vt + c * 512 + lane * 8);
      oacc = __builtin_amdgcn_mfma_f32_16x16x32_bf16(pa, vbf, oacc, 0, 0, 0);
    }
  }
#pragma unroll
  for (int msk = 1; msk <= 8; msk <<= 1)
#pragma unroll
    for (int r = 0; r < 4; r++) {
      o16a[r] += __shfl_xor(o16a[r], msk);
      lreg[r] += __shfl_xor(lreg[r], msk);
    }
  size_t obase = ((size_t)sp * NHEAD + h) * 128;
#pragma unroll
  for (int r = 0; r < 4; r++) {
    int ql = q0 + w * 16 + quad * 4 + r;
    if (ql < HW) {
      opart[(obase + ql) * HD + col] = oacc[r];
      if (col == 0) {
        opart[(obase + ql) * HD + 16] = o16a[r];
        lpart[obase + ql] = lreg[r];
      }
    }
  }
}

// ---------------- layer-1: out_proj (MFMA) + residual + LN1, all rows ----------------
__global__ __launch_bounds__(256) void proj_ln1_l1_kernel(
    const float* __restrict__ o, const unsigned short* __restrict__ opwp,
    const float* __restrict__ opb, const float* __restrict__ g,
    const float* __restrict__ b, float* __restrict__ x) {
  __shared__ __align__(16) unsigned short soA[32 * 72];
  int t = threadIdx.x;
  int w = t >> 6, lane = t & 63, quad = lane >> 4, col = lane & 15;
  int r0 = blockIdx.x * 32;
  int nr = min(32, SS - r0);
  for (int i = t; i < 32 * 72; i += 256) soA[i] = 0;
  __syncthreads();
  for (int i = t; i < nr * DD; i += 256) {
    int r = i / DD, rem = i - r * DD;
    soA[r * 72 + rem] = f2b(o[(size_t)(r0 + r) * DD + rem]);
  }
  __syncthreads();
  if (w < 2) {
    int m0 = w * 16;
    bf16x8 a0 = *(const bf16x8*)&soA[(m0 + col) * 72 + quad * 8];
    bf16x8 a1 = *(const bf16x8*)&soA[(m0 + col) * 72 + 32 + quad * 8];
    f32x4 y[3];
#pragma unroll
    for (int nt = 0; nt < 3; nt++) {
      int n = nt * 16 + col;
      bf16x8 b0 = *(const bf16x8*)&opwp[n * 64 + quad * 8];
      bf16x8 b1 = *(const bf16x8*)&opwp[n * 64 + 32 + quad * 8];
      f32x4 acc = {0.f, 0.f, 0.f, 0.f};
      acc = __builtin_amdgcn_mfma_f32_16x16x32_bf16(a0, b0, acc, 0, 0, 0);
      y[nt] = __builtin_amdgcn_mfma_f32_16x16x32_bf16(a1, b1, acc, 0, 0, 0);
    }
    float yv[3][4];
    float s1[4] = {0.f, 0.f, 0.f, 0.f}, s2[4] = {0.f, 0.f, 0.f, 0.f};
#pragma unroll
    for (int nt = 0; nt < 3; nt++) {
      int d = nt * 16 + col;
      bool vd = d < DD;
      float ob = vd ? opb[d] : 0.f;
#pragma unroll
      for (int r = 0; r < 4; r++) {
        int row = r0 + m0 + quad * 4 + r;
        float v = 0.f;
        if (vd && row < SS) v = y[nt][r] + ob + x[(size_t)row * DD + d];
        yv[nt][r] = v;
        s1[r] += v;
        s2[r] += v * v;
      }
    }
#pragma unroll
    for (int msk = 1; msk <= 8; msk <<= 1)
#pragma unroll
      for (int r = 0; r < 4; r++) {
        s1[r] += __shfl_xor(s1[r], msk);
        s2[r] += __shfl_xor(s2[r], msk);
      }
#pragma unroll
    for (int r = 0; r < 4; r++) {
      int row = r0 + m0 + quad * 4 + r;
      if (row >= SS) continue;
      float mean = s1[r] * (1.f / DD);
      float var = s2[r] * (1.f / DD) - mean * mean;
      float rs = rsqrtf(var + EPSF);
#pragma unroll
      for (int nt = 0; nt < 3; nt++) {
        int d = nt * 16 + col;
        if (d < DD)
          x[(size_t)row * DD + d] = (yv[nt][r] - mean) * rs * g[d] + b[d];
      }
    }
  }
}

// ---------------- layer-2: combine(26) + out_proj + residual + LN1, 81 rows ----------------
__global__ __launch_bounds__(256) void proj_ln1_l2_kernel(
    const float* __restrict__ opart, const float* __restrict__ lpart,
    const unsigned short* __restrict__ opwp, const float* __restrict__ opb,
    const float* __restrict__ g, const float* __restrict__ b,
    const int* __restrict__ abase, float* __restrict__ x) {
  __shared__ __align__(16) unsigned short soA[32 * 72];
  int t = threadIdx.x;
  int w = t >> 6, lane = t & 63, quad = lane >> 4, col = lane & 15;
  int base = abase[0] * HW;
  int ql0 = blockIdx.x * 32;
  int nr = min(32, HW - ql0);
  int r0 = base + ql0;
  for (int i = t; i < 32 * 72; i += 256) soA[i] = 0;
  __syncthreads();
  for (int i = t; i < nr * DD; i += 256) {
    int r = i / DD, rem = i - r * DD;
    int ql = ql0 + r;
    int h = rem / HD, d = rem - h * HD;
    float L = 0.f, O = 0.f;
#pragma unroll
    for (int s = 0; s < NSPLIT2; s++) {
      L += lpart[((size_t)s * NHEAD + h) * 128 + ql];
      O += opart[(((size_t)s * NHEAD + h) * 128 + ql) * HD + d];
    }
    soA[r * 72 + rem] = f2b(O / L);
  }
  __syncthreads();
  if (w < 2) {
    int m0 = w * 16;
    bf16x8 a0 = *(const bf16x8*)&soA[(m0 + col) * 72 + quad * 8];
    bf16x8 a1 = *(const bf16x8*)&soA[(m0 + col) * 72 + 32 + quad * 8];
    f32x4 y[3];
#pragma unroll
    for (int nt = 0; nt < 3; nt++) {
      int n = nt * 16 + col;
      bf16x8 b0 = *(const bf16x8*)&opwp[n * 64 + quad * 8];
      bf16x8 b1 = *(const bf16x8*)&opwp[n * 64 + 32 + quad * 8];
      f32x4 acc = {0.f, 0.f, 0.f, 0.f};
      acc = __builtin_amdgcn_mfma_f32_16x16x32_bf16(a0, b0, acc, 0, 0, 0);
      y[nt] = __builtin_amdgcn_mfma_f32_16x16x32_bf16(a1, b1, acc, 0, 0, 0);
    }
    float yv[3][4];
    float s1[4] = {0.f, 0.f, 0.f, 0.f}, s2[4] = {0.f, 0.f, 0.f, 0.f};
#pragma unroll
    for (int nt = 0; nt < 3; nt++) {
      int d = nt * 16 + col;
      bool vd = d < DD;
      float ob = vd ? opb[d] : 0.f;
#pragma unroll
      for (int r = 0; r < 4; r++) {
        int lr = m0 + quad * 4 + r;
        float v = 0.f;
        if (vd && lr < nr) v = y[nt][r] + ob + x[(size_t)(r0 + lr) * DD + d];
        yv[nt][r] = v;
        s1[r] += v;
        s2[r] += v * v;
      }
    }
#pragma unroll
    for (int msk = 1; msk <= 8; msk <<= 1)
#pragma unroll
      for (int r = 0; r < 4; r++) {
        s1[r] += __shfl_xor(s1[r], msk);
        s2[r] += __shfl_xor(s2[r], msk);
      }
#pragma unroll
    for (int r = 0; r < 4; r++) {
      int lr = m0 + quad * 4 + r;
      if (lr >= nr) continue;
      float mean = s1[r] * (1.f / DD);
      float var = s2[r] * (1.f / DD) - mean * mean;
      float rs = rsqrtf(var + EPSF);
#pragma unroll
      for (int nt = 0; nt < 3; nt++) {
        int d = nt * 16 + col;
        if (d < DD)
          x[(size_t)(r0 + lr) * DD + d] = (yv[nt][r] - mean) * rs * g[d] + b[d];
      }
    }
  }
}

// ---------------- MFMA FF + residual + LN2 (full or 81-row slice) ----------------
__global__ __launch_bounds__(256) void ff_mfma_kernel(
    float* __restrict__ x, const unsigned short* __restrict__ w1p,
    const unsigned short* __restrict__ w2p, const float* __restrict__ b1g,
    const float* __restrict__ b2g, const float* __restrict__ g,
    const float* __restrict__ bb, const int* __restrict__ abase) {
  __shared__ __align__(16) unsigned short sxA[16 * 72];
  __shared__ float sxF[16][35];
  __shared__ __align__(16) unsigned short hw_[4][16 * 40];
  __shared__ float yred[4][16][49];
  int t = threadIdx.x;
  int w = t >> 6, lane = t & 63, quad = lane >> 4, col = lane & 15;
  int b0 = abase ? abase[0] * HW : 0;
  int limit = abase ? HW : SS;
  int ql0 = blockIdx.x * 16;
  int nr = min(16, limit - ql0);
  int r0 = b0 + ql0;

  for (int i = t; i < 16 * 72; i += 256) sxA[i] = 0;
  for (int i = t; i < 16 * 35; i += 256) ((float*)sxF)[i] = 0.f;
  __syncthreads();
  for (int i = t; i < nr * DD; i += 256) {
    int r = i / DD, d = i - r * DD;
    float v = x[(size_t)(r0 + r) * DD + d];
    sxF[r][d] = v;
    sxA[r * 72 + d] = f2b(v);
  }
  __syncthreads();

  bf16x8 a0 = *(const bf16x8*)&sxA[col * 72 + quad * 8];
  bf16x8 a1 = *(const bf16x8*)&sxA[col * 72 + 32 + quad * 8];
  unsigned short* myh = &hw_[w][0];
  f32x4 acc3[3];
#pragma unroll
  for (int nt = 0; nt < 3; nt++) acc3[nt] = (f32x4){0.f, 0.f, 0.f, 0.f};

  for (int kt = 0; kt < 16; kt++) {
    int fbase = kt * 128 + w * 32;
#pragma unroll
    for (int nt = 0; nt < 2; nt++) {
      int f = fbase + nt * 16 + col;
      bf16x8 b0f = *(const bf16x8*)&w1p[f * 64 + quad * 8];
      bf16x8 b1f = *(const bf16x8*)&w1p[f * 64 + 32 + quad * 8];
      f32x4 hacc = {0.f, 0.f, 0.f, 0.f};
      hacc = __builtin_amdgcn_mfma_f32_16x16x32_bf16(a0, b0f, hacc, 0, 0, 0);
      hacc = __builtin_amdgcn_mfma_f32_16x16x32_bf16(a1, b1f, hacc, 0, 0, 0);
      float bias = b1g[f];
#pragma unroll
      for (int r = 0; r < 4; r++) {
        float hv = fmaxf(hacc[r] + bias, 0.f);
        myh[(quad * 4 + r) * 40 + nt * 16 + col] = f2b(hv);
      }
    }
    bf16x8 pa = *(const bf16x8*)&myh[col * 40 + quad * 8];
#pragma unroll
    for (int nt = 0; nt < 3; nt++) {
      int n = nt * 16 + col;
      bf16x8 wb = *(const bf16x8*)&w2p[(size_t)n * FF + fbase + quad * 8];
      acc3[nt] = __builtin_amdgcn_mfma_f32_16x16x32_bf16(pa, wb, acc3[nt], 0, 0, 0);
    }
  }

#pragma unroll
  for (int nt = 0; nt < 3; nt++)
#pragma unroll
    for (int r = 0; r < 4; r++)
      yred[w][quad * 4 + r][nt * 16 + col] = acc3[nt][r];
  __syncthreads();
  if (w == 0) {
    float yv[3][4];
    float s1[4] = {0.f, 0.f, 0.f, 0.f}, s2[4] = {0.f, 0.f, 0.f, 0.f};
#pragma unroll
    for (int nt = 0; nt < 3; nt++) {
      int d = nt * 16 + col;
      bool valid = d < DD;
      float b2v = valid ? b2g[d] : 0.f;
#pragma unroll
      for (int r = 0; r < 4; r++) {
        int row = quad * 4 + r;
        float v = yred[0][row][nt * 16 + col] + yred[1][row][nt * 16 + col]
                + yred[2][row][nt * 16 + col] + yred[3][row][nt * 16 + col];
        v = valid ? (v + b2v + sxF[row][d]) : 0.f;
        yv[nt][r] = v;
        s1[r] += v;
        s2[r] += v * v;
      }
    }
#pragma unroll
    for (int msk = 1; msk <= 8; msk <<= 1)
#pragma unroll
      for (int r = 0; r < 4; r++) {
        s1[r] += __shfl_xor(s1[r], msk);
        s2[r] += __shfl_xor(s2[r], msk);
      }
#pragma unroll
    for (int r = 0; r < 4; r++) {
      int row = quad * 4 + r;
      if (row >= nr) continue;
      float mean = s1[r] * (1.f / DD);
      float var = s2[r] * (1.f / DD) - mean * mean;
      float rs = rsqrtf(var + EPSF);
#pragma unroll
      for (int nt = 0; nt < 3; nt++) {
        int d = nt * 16 + col;
        if (d < DD)
          x[(size_t)(r0 + row) * DD + d] = (yv[nt][r] - mean) * rs * g[d] + bb[d];
      }
    }
  }
}

// ---------------- final ----------------
__global__ __launch_bounds__(64) void final_kernel(
    const float* __restrict__ x, const int* __restrict__ aidx, float* __restrict__ out) {
  int d = threadIdx.x;
  if (d >= DD) return;
  int start = (*aidx) * HW;
  float acc = 0.f;
  for (int j = 0; j < HW; j++) acc += x[(size_t)(start + j) * DD + d];
  out[d] = acc * (1.f / HW);
}

extern "C" void kernel_launch(void* const* d_in, const int* in_sizes, int n_in,
                              void* d_out, int out_size, void* d_ws, size_t ws_size,
                              hipStream_t stream) {
  const float* obs = (const float*)d_in[0];
  const float* c1w = (const float*)d_in[1];
  const float* c1b = (const float*)d_in[2];
  const float* c2w = (const float*)d_in[3];
  const float* c2b = (const float*)d_in[4];
  const float* ipw = (const float*)d_in[5];
  const float* ipb = (const float*)d_in[6];
  const float* opw = (const float*)d_in[7];
  const float* opb = (const float*)d_in[8];
  const float* l1w = (const float*)d_in[9];
  const float* l1b = (const float*)d_in[10];
  const float* l2w = (const float*)d_in[11];
  const float* l2b = (const float*)d_in[12];
  const float* g1 = (const float*)d_in[13];
  const float* b1 = (const float*)d_in[14];
  const float* g2 = (const float*)d_in[15];
  const float* b2 = (const float*)d_in[16];
  float* out = (float*)d_out;

  float* ws = (float*)d_ws;
  size_t off = 0;
  float* x     = ws + off; off += SS * DD;
  float* qkv   = ws + off; off += SS * 102;
  float* cell  = ws + off; off += HW * CC;
  int*   aidx  = (int*)(ws + off); off += 1;
  off = (off + 3) & ~(size_t)3;
  float* o     = ws + off; off += SS * DD;
  float* Pt    = ws + off; off += 2 * HW * 102;
  float* opart = ws + off; off += (size_t)NSPLIT2 * NHEAD * 128 * HD;
  float* lpart = ws + off; off += (size_t)NSPLIT2 * NHEAD * 128;
  off = (off + 3) & ~(size_t)3;
  unsigned short* kfp  = (unsigned short*)(ws + off); off += (NHEAD * NTILES * 8 * 512) / 2;
  unsigned short* vfp  = (unsigned short*)(ws + off); off += (NHEAD * NTILES * 4 * 512) / 2;
  float* v16 = ws + off; off += NHEAD * NTILES * 128;
  unsigned short* ipwp = (unsigned short*)(ws + off); off += 2 * NIP / 2;
  unsigned short* opwp = (unsigned short*)(ws + off); off += 2 * NOP / 2;
  unsigned short* w1p  = (unsigned short*)(ws + off); off += 2 * NW1 / 2;
  unsigned short* w2p  = (unsigned short*)(ws + off); off += 2 * NW2 / 2;

  const int row32_blocks = (SS + 31) / 32;   // 206
  const int row16_blocks = (SS + 15) / 16;   // 411
  const int lprep_blocks = (2 * NLTOT + 255) / 256;
  const int tokcell_blocks = (SS * DD + 2 * HW * 102 + 255) / 256;
  const int kvprep_elems = NHEAD * NTILES * (8 * 512 + 4 * 512 + 128);
  const int kvprep_blocks = (kvprep_elems + 255) / 256;

  prep_kernel<<<1, 256, 0, stream>>>(obs, c1w, c1b, c2w, c2b, cell, aidx);
  tokcell_kernel<<<tokcell_blocks, 256, 0, stream>>>(cell, ipw, ipb, x, Pt);
  lprep_kernel<<<lprep_blocks, 256, 0, stream>>>(ipw, opw, l1w, l2w, ipwp, opwp, w1p, w2p);

  // ---- layer 1 ----
  dim3 a1g(row32_blocks, NHEAD);
  attn1_kernel<<<a1g, 256, 0, stream>>>(Pt, o);
  proj_ln1_l1_kernel<<<row32_blocks, 256, 0, stream>>>(o, opwp, opb, g1, b1, x);
  ff_mfma_kernel<<<row16_blocks, 256, 0, stream>>>(
      x, w1p, w2p, l1b, l2b, g2, b2, (const int*)nullptr);

  // ---- layer 2 (output-sliced) ----
  qkv2_kernel<<<210, 256, 0, stream>>>(x, ipwp + NIP, ipb + 102, aidx, qkv);
  kvprep_kernel<<<kvprep_blocks, 256, 0, stream>>>(qkv, kfp, vfp, v16);
  dim3 a2g(2, NHEAD, NSPLIT2);
  attn2_kernel<<<a2g, 256, 0, stream>>>(qkv, kfp, vfp, v16, aidx, opart, lpart);
  proj_ln1_l2_kernel<<<3, 256, 0, stream>>>(
      opart, lpart, opwp + NOP, opb + DD, g1 + DD, b1 + DD, aidx, x);
  ff_mfma_kernel<<<6, 256, 0, stream>>>(
      x, w1p + NW1, w2p + NW2, l1b + FF, l2b + DD, g2 + DD, b2 + DD, aidx);

  final_kernel<<<1, 64, 0, stream>>>(x, aidx, out);
}

// Round 11
// 203.174 us; speedup vs baseline: 14.5276x; 1.1336x over previous
//
#include <hip/hip_runtime.h>
#include <hip/hip_bf16.h>

#define HH 9
#define WW 9
#define HW 81
#define CC 16
#define DD 34
#define SS 6561
#define NHEAD 2
#define HD 17
#define FF 2048
#define EPSF 1e-5f

#define NTILES 52
#define NSPLIT2 26
#define QB 64

#define NIP 7168
#define NOP 3072
#define NW1 131072
#define NW2 98304
#define NLTOT (NIP + NOP + NW1 + NW2)   // 239616
#define LPREP_BLOCKS 1872               // 2*NLTOT/256
#define NKF 425984                      // kfp shorts
#define NVF 212992                      // vfp shorts
#define NV16 13312                      // v16 floats
#define ZERO_WORDS 332800               // NKF/2 + NVF/2 + NV16
#define ZERO_BLOCKS 1300

typedef __attribute__((ext_vector_type(8))) short bf16x8;
typedef __attribute__((ext_vector_type(4))) float f32x4;

__device__ __forceinline__ unsigned short f2b(float f) {
  unsigned int u = __float_as_uint(f);
  u += 0x7fffu + ((u >> 16) & 1u);
  return (unsigned short)(u >> 16);
}

// ---- dispatch 1: block 0 = conv1+conv2+argmax; 1..1872 = weight pack; rest zero kfp/vfp/v16 ----
__global__ __launch_bounds__(256) void prep_kernel(
    const float* __restrict__ obs, const float* __restrict__ w1, const float* __restrict__ b1,
    const float* __restrict__ w2, const float* __restrict__ b2,
    float* __restrict__ cell, int* __restrict__ aidx,
    const float* __restrict__ ipw, const float* __restrict__ opw,
    const float* __restrict__ l1w, const float* __restrict__ l2w,
    unsigned short* __restrict__ ipwp, unsigned short* __restrict__ opwp,
    unsigned short* __restrict__ w1p, unsigned short* __restrict__ w2p,
    unsigned short* __restrict__ kfp, unsigned short* __restrict__ vfp,
    float* __restrict__ v16) {
  int bx = blockIdx.x;
  int t = threadIdx.x;
  if (bx == 0) {
    __shared__ float s_obs[2][11][11];
    __shared__ float s_w1[288];
    __shared__ float s_w2[2304];
    __shared__ float s_b1[16], s_b2[16];
    __shared__ float y1[CC][121];
    for (int i = t; i < 2 * 121; i += 256) ((float*)s_obs)[i] = 0.f;
    for (int i = t; i < CC * 121; i += 256) ((float*)y1)[i] = 0.f;
    for (int i = t; i < 288; i += 256) s_w1[i] = w1[i];
    for (int i = t; i < 2304; i += 256) s_w2[i] = w2[i];
    if (t < 16) { s_b1[t] = b1[t]; s_b2[t] = b2[t]; }
    __syncthreads();
    for (int i = t; i < 2 * HW; i += 256) {
      int ic = i / HW, p = i % HW;
      s_obs[ic][1 + p / WW][1 + p % WW] = obs[i];
    }
    __syncthreads();
    if (t == 0) {
      int best = 0; float bv = s_obs[0][1][1];
      for (int p = 1; p < HW; p++) {
        float v = s_obs[0][1 + p / WW][1 + p % WW];
        if (v > bv) { bv = v; best = p; }
      }
      *aidx = best;
    }
    for (int idx = t; idx < CC * HW; idx += 256) {
      int c = idx / HW, p = idx % HW;
      int i = p / WW, j = p % WW;
      float acc = s_b1[c];
#pragma unroll
      for (int ic = 0; ic < 2; ic++)
#pragma unroll
        for (int di = 0; di < 3; di++)
#pragma unroll
          for (int dj = 0; dj < 3; dj++)
            acc += s_obs[ic][i + di][j + dj] * s_w1[((c * 2 + ic) * 3 + di) * 3 + dj];
      y1[c][(i + 1) * 11 + (j + 1)] = fmaxf(acc, 0.f);
    }
    __syncthreads();
    for (int idx = t; idx < CC * HW; idx += 256) {
      int c = idx / HW, p = idx % HW;
      int i = p / WW, j = p % WW;
      float acc = s_b2[c];
#pragma unroll
      for (int ic = 0; ic < CC; ic++)
#pragma unroll
        for (int di = 0; di < 3; di++)
#pragma unroll
          for (int dj = 0; dj < 3; dj++)
            acc += y1[ic][(i + di) * 11 + (j + dj)] * s_w2[((c * CC + ic) * 3 + di) * 3 + dj];
      cell[p * CC + c] = fmaxf(acc, 0.f);
    }
  } else if (bx <= LPREP_BLOCKS) {
    int i = (bx - 1) * 256 + t;
    int layer = i / NLTOT;
    int r = i % NLTOT;
    if (r < NIP) {
      int n = r >> 6, k = r & 63;
      ipwp[layer * NIP + r] =
          (n < 102 && k < DD) ? f2b(ipw[(size_t)layer * 102 * DD + n * DD + k]) : (unsigned short)0;
    } else if (r < NIP + NOP) {
      int rr = r - NIP;
      int n = rr >> 6, k = rr & 63;
      opwp[layer * NOP + rr] =
          (n < DD && k < DD) ? f2b(opw[(size_t)layer * DD * DD + n * DD + k]) : (unsigned short)0;
    } else if (r < NIP + NOP + NW1) {
      int rr = r - NIP - NOP;
      int f = rr >> 6, k = rr & 63;
      w1p[layer * NW1 + rr] =
          (k < DD) ? f2b(l1w[(size_t)layer * FF * DD + f * DD + k]) : (unsigned short)0;
    } else {
      int rr = r - NIP - NOP - NW1;
      int d = rr >> 11, kk = rr & 2047;
      w2p[layer * NW2 + rr] =
          (d < DD) ? f2b(l2w[(size_t)layer * DD * FF + d * FF + kk]) : (unsigned short)0;
    }
  } else {
    int zi = (bx - 1 - LPREP_BLOCKS) * 256 + t;
    if (zi < NKF / 2) ((unsigned int*)kfp)[zi] = 0u;
    else if (zi < NKF / 2 + NVF / 2) ((unsigned int*)vfp)[zi - NKF / 2] = 0u;
    else if (zi < ZERO_WORDS) v16[zi - NKF / 2 - NVF / 2] = 0.f;
  }
}

// ---- dispatch 2: layer-1 separable qkv tables ----
__global__ __launch_bounds__(256) void ptprep_kernel(
    const float* __restrict__ cell, const float* __restrict__ ipw,
    const float* __restrict__ ipb, float* __restrict__ Pt) {
  int idx = blockIdx.x * 256 + threadIdx.x;
  if (idx >= 2 * HW * 102) return;
  int part = idx / (HW * 102);
  int rem = idx % (HW * 102);
  int a = rem / 102, n = rem % 102;
  float ra = (float)(a / WW) * 0.25f, ca = (float)(a % WW) * 0.25f;
  float acc;
  if (part == 0) {
    acc = ipb[n] + ipw[n * DD + 32] * ra + ipw[n * DD + 33] * ca;
    for (int f = 0; f < CC; f++) acc += ipw[n * DD + f] * cell[a * CC + f];
  } else {
    acc = -(ipw[n * DD + 32] * ra + ipw[n * DD + 33] * ca);
    for (int f = 0; f < CC; f++) acc += ipw[n * DD + CC + f] * cell[a * CC + f];
  }
  Pt[idx] = acc;
}

// ---- dispatch 3: fused layer-1: tokens + separable attn + proj + LN1 + FF + LN2 ----
// 411 blocks x 16 rows.
__global__ __launch_bounds__(256) void fl1_kernel(
    const float* __restrict__ cell, const float* __restrict__ Pt,
    const unsigned short* __restrict__ opwp, const float* __restrict__ opb,
    const float* __restrict__ g1v, const float* __restrict__ b1v,
    const unsigned short* __restrict__ w1p, const unsigned short* __restrict__ w2p,
    const float* __restrict__ fb1, const float* __restrict__ fb2,
    const float* __restrict__ g2v, const float* __restrict__ b2v,
    float* __restrict__ x) {
  __shared__ float sk[2][2][HW][20];   // [h][part][a][d]
  __shared__ float sv[2][2][HW][20];
  __shared__ __align__(16) unsigned short soA[16 * 72];
  __shared__ float sxF[16][35];
  __shared__ __align__(16) unsigned short sxA2[16 * 72];
  __shared__ float sxF2[16][35];
  __shared__ __align__(16) unsigned short hw_[4][16 * 40];
  __shared__ float yred[4][16][49];
  int t = threadIdx.x;
  int w = t >> 6, lane = t & 63, quad = lane >> 4, col = lane & 15;
  int r0 = blockIdx.x * 16;
  int nr = min(16, SS - r0);

  for (int i = t; i < 16 * 72; i += 256) { soA[i] = 0; sxA2[i] = 0; }
  for (int i = t; i < 16 * 35; i += 256) { ((float*)sxF)[i] = 0.f; ((float*)sxF2)[i] = 0.f; }
  for (int i = t; i < 2 * 2 * HW * HD; i += 256) {
    int d = i % HD, a = (i / HD) % HW, part = (i / (HD * HW)) & 1, h = i / (HD * HW * 2);
    const float* base = Pt + (size_t)part * HW * 102 + a * 102;
    sk[h][part][a][d] = base[DD + h * HD + d];
    sv[h][part][a][d] = base[2 * DD + h * HD + d];
  }
  for (int i = t; i < nr * DD; i += 256) {
    int r = i / DD, d = i - r * DD;
    int row = r0 + r;
    int ii = row / HW, jj = row - ii * HW;
    float v;
    if (d < CC) v = cell[ii * CC + d];
    else if (d < 2 * CC) v = cell[jj * CC + (d - CC)];
    else if (d == 32) v = (float)((ii / WW) - (jj / WW)) * 0.25f;
    else v = (float)((ii % WW) - (jj % WW)) * 0.25f;
    sxF[r][d] = v;
  }
  __syncthreads();

  // attention: 16 rows x 16 sub-lanes (bit3=h, bit2=part, bits0-1=a-chunk)
  {
    int tl = t >> 4, sub = t & 15;
    int h = (sub >> 3) & 1, p = (sub >> 2) & 1, asp = sub & 3;
    int row = r0 + tl;
    int tc = row < SS ? row : SS - 1;
    int ii = tc / HW, jj = tc % HW;
    const float scale = 0.24253562503633297f;
    const float* p0 = Pt + ii * 102 + h * HD;
    const float* p1 = Pt + (size_t)HW * 102 + jj * 102 + h * HD;
    float q[HD];
#pragma unroll
    for (int d = 0; d < HD; d++) q[d] = (p0[d] + p1[d]) * scale;
    float S = 0.f, EV[HD];
#pragma unroll
    for (int d = 0; d < HD; d++) EV[d] = 0.f;
    for (int a = asp; a < HW; a += 4) {
      float s = 0.f;
#pragma unroll
      for (int d = 0; d < HD; d++) s += q[d] * sk[h][p][a][d];
      float e = __expf(fminf(s, 70.f));
      S += e;
#pragma unroll
      for (int d = 0; d < HD; d++) EV[d] += e * sv[h][p][a][d];
    }
    S += __shfl_xor(S, 1); S += __shfl_xor(S, 2);
#pragma unroll
    for (int d = 0; d < HD; d++) { EV[d] += __shfl_xor(EV[d], 1); EV[d] += __shfl_xor(EV[d], 2); }
    float So = __shfl_xor(S, 4);
    float EVo[HD];
#pragma unroll
    for (int d = 0; d < HD; d++) EVo[d] = __shfl_xor(EV[d], 4);
    float inv = 1.f / S, invo = 1.f / So;
    if ((sub & 7) == 0 && tl < nr) {
#pragma unroll
      for (int d = 0; d < HD; d++)
        soA[tl * 72 + h * HD + d] = f2b(EV[d] * inv + EVo[d] * invo);
    }
  }
  __syncthreads();

  // proj + residual + LN1 (wave 0), writes sxA2/sxF2
  if (w == 0) {
    bf16x8 a0 = *(const bf16x8*)&soA[col * 72 + quad * 8];
    bf16x8 a1 = *(const bf16x8*)&soA[col * 72 + 32 + quad * 8];
    f32x4 y[3];
#pragma unroll
    for (int nt = 0; nt < 3; nt++) {
      int n = nt * 16 + col;
      bf16x8 b0 = *(const bf16x8*)&opwp[n * 64 + quad * 8];
      bf16x8 b1 = *(const bf16x8*)&opwp[n * 64 + 32 + quad * 8];
      f32x4 acc = {0.f, 0.f, 0.f, 0.f};
      acc = __builtin_amdgcn_mfma_f32_16x16x32_bf16(a0, b0, acc, 0, 0, 0);
      y[nt] = __builtin_amdgcn_mfma_f32_16x16x32_bf16(a1, b1, acc, 0, 0, 0);
    }
    float yv[3][4];
    float s1[4] = {0.f, 0.f, 0.f, 0.f}, s2[4] = {0.f, 0.f, 0.f, 0.f};
#pragma unroll
    for (int nt = 0; nt < 3; nt++) {
      int d = nt * 16 + col;
      bool vd = d < DD;
      float ob = vd ? opb[d] : 0.f;
#pragma unroll
      for (int r = 0; r < 4; r++) {
        int row = quad * 4 + r;
        float v = vd ? (y[nt][r] + ob + sxF[row][d]) : 0.f;
        yv[nt][r] = v;
        s1[r] += v;
        s2[r] += v * v;
      }
    }
#pragma unroll
    for (int msk = 1; msk <= 8; msk <<= 1)
#pragma unroll
      for (int r = 0; r < 4; r++) {
        s1[r] += __shfl_xor(s1[r], msk);
        s2[r] += __shfl_xor(s2[r], msk);
      }
#pragma unroll
    for (int r = 0; r < 4; r++) {
      int row = quad * 4 + r;
      float mean = s1[r] * (1.f / DD);
      float var = s2[r] * (1.f / DD) - mean * mean;
      float rs = rsqrtf(var + EPSF);
#pragma unroll
      for (int nt = 0; nt < 3; nt++) {
        int d = nt * 16 + col;
        if (d < DD) {
          float o = (yv[nt][r] - mean) * rs * g1v[d] + b1v[d];
          sxF2[row][d] = o;
          sxA2[row * 72 + d] = f2b(o);
        }
      }
    }
  }
  __syncthreads();

  // FF (all 4 waves, barrier-free K-loop) + LN2, write x
  bf16x8 a0 = *(const bf16x8*)&sxA2[col * 72 + quad * 8];
  bf16x8 a1 = *(const bf16x8*)&sxA2[col * 72 + 32 + quad * 8];
  unsigned short* myh = &hw_[w][0];
  f32x4 acc3[3];
#pragma unroll
  for (int nt = 0; nt < 3; nt++) acc3[nt] = (f32x4){0.f, 0.f, 0.f, 0.f};
  for (int kt = 0; kt < 16; kt++) {
    int fbase = kt * 128 + w * 32;
#pragma unroll
    for (int nt = 0; nt < 2; nt++) {
      int f = fbase + nt * 16 + col;
      bf16x8 b0f = *(const bf16x8*)&w1p[f * 64 + quad * 8];
      bf16x8 b1f = *(const bf16x8*)&w1p[f * 64 + 32 + quad * 8];
      f32x4 hacc = {0.f, 0.f, 0.f, 0.f};
      hacc = __builtin_amdgcn_mfma_f32_16x16x32_bf16(a0, b0f, hacc, 0, 0, 0);
      hacc = __builtin_amdgcn_mfma_f32_16x16x32_bf16(a1, b1f, hacc, 0, 0, 0);
      float bias = fb1[f];
#pragma unroll
      for (int r = 0; r < 4; r++) {
        float hv = fmaxf(hacc[r] + bias, 0.f);
        myh[(quad * 4 + r) * 40 + nt * 16 + col] = f2b(hv);
      }
    }
    bf16x8 pa = *(const bf16x8*)&myh[col * 40 + quad * 8];
#pragma unroll
    for (int nt = 0; nt < 3; nt++) {
      int n = nt * 16 + col;
      bf16x8 wb = *(const bf16x8*)&w2p[(size_t)n * FF + fbase + quad * 8];
      acc3[nt] = __builtin_amdgcn_mfma_f32_16x16x32_bf16(pa, wb, acc3[nt], 0, 0, 0);
    }
  }
#pragma unroll
  for (int nt = 0; nt < 3; nt++)
#pragma unroll
    for (int r = 0; r < 4; r++)
      yred[w][quad * 4 + r][nt * 16 + col] = acc3[nt][r];
  __syncthreads();
  if (w == 0) {
    float yv[3][4];
    float s1[4] = {0.f, 0.f, 0.f, 0.f}, s2[4] = {0.f, 0.f, 0.f, 0.f};
#pragma unroll
    for (int nt = 0; nt < 3; nt++) {
      int d = nt * 16 + col;
      bool valid = d < DD;
      float b2x = valid ? fb2[d] : 0.f;
#pragma unroll
      for (int r = 0; r < 4; r++) {
        int row = quad * 4 + r;
        float v = yred[0][row][nt * 16 + col] + yred[1][row][nt * 16 + col]
                + yred[2][row][nt * 16 + col] + yred[3][row][nt * 16 + col];
        v = valid ? (v + b2x + sxF2[row][d]) : 0.f;
        yv[nt][r] = v;
        s1[r] += v;
        s2[r] += v * v;
      }
    }
#pragma unroll
    for (int msk = 1; msk <= 8; msk <<= 1)
#pragma unroll
      for (int r = 0; r < 4; r++) {
        s1[r] += __shfl_xor(s1[r], msk);
        s2[r] += __shfl_xor(s2[r], msk);
      }
#pragma unroll
    for (int r = 0; r < 4; r++) {
      int row = quad * 4 + r;
      if (row >= nr) continue;
      float mean = s1[r] * (1.f / DD);
      float var = s2[r] * (1.f / DD) - mean * mean;
      float rs = rsqrtf(var + EPSF);
#pragma unroll
      for (int nt = 0; nt < 3; nt++) {
        int d = nt * 16 + col;
        if (d < DD)
          x[(size_t)(r0 + row) * DD + d] = (yv[nt][r] - mean) * rs * g2v[d] + b2v[d];
      }
    }
  }
}

// ---- dispatch 4: layer-2 qkv. Blocks 0..205: K/V all rows, DIRECT fragment-packed
//      scatter writes. Blocks 206..209: Q for 128 rows at runtime base -> qkv. ----
__global__ __launch_bounds__(256) void qkv2_kernel(
    const float* __restrict__ x, const unsigned short* __restrict__ ipwp,
    const float* __restrict__ ipb, const int* __restrict__ abase,
    float* __restrict__ qkv, unsigned short* __restrict__ kfp,
    unsigned short* __restrict__ vfp, float* __restrict__ v16) {
  __shared__ __align__(16) unsigned short sxA[32 * 72];
  int t = threadIdx.x;
  int w = t >> 6, lane = t & 63, quad = lane >> 4, col = lane & 15;
  int m0 = (w & 1) * 16, half = w >> 1;
  bool qpart = blockIdx.x >= 206;
  int row0 = qpart ? (abase[0] * HW + (blockIdx.x - 206) * 32) : blockIdx.x * 32;
  int nr = min(32, SS - row0);
  for (int i = t; i < 32 * 72; i += 256) sxA[i] = 0;
  __syncthreads();
  for (int i = t; i < nr * DD; i += 256) {
    int r = i / DD, d = i - r * DD;
    sxA[r * 72 + d] = f2b(x[(size_t)(row0 + r) * DD + d]);
  }
  __syncthreads();
  bf16x8 a0 = *(const bf16x8*)&sxA[(m0 + col) * 72 + quad * 8];
  bf16x8 a1 = *(const bf16x8*)&sxA[(m0 + col) * 72 + 32 + quad * 8];
  if (!qpart) {
    int ntc = half ? 2 : 3;
    for (int nt2 = 0; nt2 < ntc; nt2++) {
      int nt = half * 3 + nt2;
      int n = DD + nt * 16 + col;       // 34..113
      int nc = n < 112 ? n : 111;
      bf16x8 b0 = *(const bf16x8*)&ipwp[nc * 64 + quad * 8];
      bf16x8 b1 = *(const bf16x8*)&ipwp[nc * 64 + 32 + quad * 8];
      f32x4 acc = {0.f, 0.f, 0.f, 0.f};
      acc = __builtin_amdgcn_mfma_f32_16x16x32_bf16(a0, b0, acc, 0, 0, 0);
      acc = __builtin_amdgcn_mfma_f32_16x16x32_bf16(a1, b1, acc, 0, 0, 0);
      if (n < 102) {
        float bias = ipb[n];
        int kd = n - DD;                // 0..67
#pragma unroll
        for (int r = 0; r < 4; r++) {
          int m = m0 + quad * 4 + r;
          if (m >= nr) continue;
          int tok = row0 + m;
          float val = acc[r] + bias;
          int T = tok >> 7, tl = tok & 127;
          if (kd < 2 * HD) {            // K
            int h = kd >= HD;
            int d = kd - h * HD;
            int colf = tl >> 3, ntk = tl & 7;
            kfp[(((size_t)h * NTILES + T) * 8 + ntk) * 512 +
                ((d >> 3) * 16 + colf) * 8 + (d & 7)] = f2b(val);
          } else {                      // V
            int vd = kd - 2 * HD;
            int h = vd >= HD;
            int d = vd - h * HD;
            if (d < 16) {
              int c = tl >> 5, qf = (tl >> 3) & 3, j = tl & 7;
              vfp[(((size_t)h * NTILES + T) * 4 + c) * 512 +
                  (qf * 16 + d) * 8 + j] = f2b(val);
            } else {
              v16[(size_t)h * (NTILES * 128) + tok] = val;
            }
          }
        }
      }
    }
  } else {
    int ntc = half ? 1 : 2;
    for (int nt2 = 0; nt2 < ntc; nt2++) {
      int nt = half * 2 + nt2;
      int n = nt * 16 + col;            // 0..47
      bf16x8 b0 = *(const bf16x8*)&ipwp[n * 64 + quad * 8];
      bf16x8 b1 = *(const bf16x8*)&ipwp[n * 64 + 32 + quad * 8];
      f32x4 acc = {0.f, 0.f, 0.f, 0.f};
      acc = __builtin_amdgcn_mfma_f32_16x16x32_bf16(a0, b0, acc, 0, 0, 0);
      acc = __builtin_amdgcn_mfma_f32_16x16x32_bf16(a1, b1, acc, 0, 0, 0);
      if (n < DD) {
        float bias = ipb[n];
#pragma unroll
        for (int r = 0; r < 4; r++) {
          int m = row0 + m0 + quad * 4 + r;
          if (m < SS) qkv[(size_t)m * 102 + n] = acc[r] + bias;
        }
      }
    }
  }
}

// ---- dispatch 5: layer-2 attention (81 queries, split-K 26) ----
__global__ __launch_bounds__(256) void attn2_kernel(
    const float* __restrict__ qkv, const unsigned short* __restrict__ kfp,
    const unsigned short* __restrict__ vfp, const float* __restrict__ v16,
    const int* __restrict__ abase,
    float* __restrict__ opart, float* __restrict__ lpart) {
  __shared__ __align__(16) unsigned short scb[4][16 * 136];
  int t = threadIdx.x, w = t >> 6, lane = t & 63, quad = lane >> 4, col = lane & 15;
  int h = blockIdx.y, sp = blockIdx.z;
  int base = abase[0] * HW;
  int q0 = blockIdx.x * QB;
  const float scale = 0.24253562503633297f;
  const unsigned short* kf = kfp + (size_t)h * (NTILES * 8 * 512);
  const unsigned short* vf = vfp + (size_t)h * (NTILES * 4 * 512);
  const float* v16h = v16 + (size_t)h * (NTILES * 128);
  unsigned short* myscb = &scb[w][0];

  int mq = base + q0 + w * 16 + col;
  int qc = mq < SS ? mq : SS - 1;
  bf16x8 aq;
#pragma unroll
  for (int j = 0; j < 8; j++) {
    int d = quad * 8 + j;
    aq[j] = (short)((d < HD) ? f2b(qkv[(size_t)qc * 102 + h * HD + d] * scale) : 0);
  }

  f32x4 oacc = {0.f, 0.f, 0.f, 0.f};
  float o16a[4] = {0.f, 0.f, 0.f, 0.f};
  float lreg[4] = {0.f, 0.f, 0.f, 0.f};

  for (int tile = sp; tile < NTILES; tile += NSPLIT2) {
    int k0 = tile * 128;
    const unsigned short* kt = kf + (size_t)tile * (8 * 512);
    f32x4 s[8];
#pragma unroll
    for (int nt = 0; nt < 8; nt++) {
      bf16x8 kb = *(const bf16x8*)(kt + nt * 512 + lane * 8);
      f32x4 z = {0.f, 0.f, 0.f, 0.f};
      s[nt] = __builtin_amdgcn_mfma_f32_16x16x32_bf16(aq, kb, z, 0, 0, 0);
    }
    if (k0 + 128 > SS) {
#pragma unroll
      for (int nt = 0; nt < 8; nt++)
        if (k0 + col * 8 + nt >= SS) {
          s[nt][0] = -1e30f; s[nt][1] = -1e30f; s[nt][2] = -1e30f; s[nt][3] = -1e30f;
        }
    }
#pragma unroll
    for (int r = 0; r < 4; r++) {
      bf16x8 pv;
      float psl = 0.f;
#pragma unroll
      for (int nt = 0; nt < 8; nt++) {
        float p = __expf(fminf(s[nt][r], 70.f));
        s[nt][r] = p;
        psl += p;
        pv[nt] = (short)f2b(p);
      }
      lreg[r] += psl;
      *(bf16x8*)(myscb + (quad * 4 + r) * 136 + col * 8) = pv;
    }
    f32x4 va = *(const f32x4*)(v16h + k0 + col * 8);
    f32x4 vb4 = *(const f32x4*)(v16h + k0 + col * 8 + 4);
#pragma unroll
    for (int r = 0; r < 4; r++) {
      o16a[r] += s[0][r] * va[0] + s[1][r] * va[1] + s[2][r] * va[2] + s[3][r] * va[3]
               + s[4][r] * vb4[0] + s[5][r] * vb4[1] + s[6][r] * vb4[2] + s[7][r] * vb4[3];
    }
    const unsigned short* vt = vf + (size_t)tile * (4 * 512);
#pragma unroll
    for (int c = 0; c < 4; c++) {
      bf16x8 pa = *(const bf16x8*)(myscb + col * 136 + c * 32 + quad * 8);
      bf16x8 vbf = *(const bf16x8*)(vt + c * 512 + lane * 8);
      oacc = __builtin_amdgcn_mfma_f32_16x16x32_bf16(pa, vbf, oacc, 0, 0, 0);
    }
  }
#pragma unroll
  for (int msk = 1; msk <= 8; msk <<= 1)
#pragma unroll
    for (int r = 0; r < 4; r++) {
      o16a[r] += __shfl_xor(o16a[r], msk);
      lreg[r] += __shfl_xor(lreg[r], msk);
    }
  size_t obase = ((size_t)sp * NHEAD + h) * 128;
#pragma unroll
  for (int r = 0; r < 4; r++) {
    int ql = q0 + w * 16 + quad * 4 + r;
    if (ql < HW) {
      opart[(obase + ql) * HD + col] = oacc[r];
      if (col == 0) {
        opart[(obase + ql) * HD + 16] = o16a[r];
        lpart[obase + ql] = lreg[r];
      }
    }
  }
}

// ---- dispatch 6: fused layer-2 tail: combine + proj + LN1 + FF + LN2 (6 blocks x 16 rows) ----
__global__ __launch_bounds__(256) void fl2_kernel(
    const float* __restrict__ opart, const float* __restrict__ lpart,
    const unsigned short* __restrict__ opwp, const float* __restrict__ opb,
    const float* __restrict__ g1v, const float* __restrict__ b1v,
    const unsigned short* __restrict__ w1p, const unsigned short* __restrict__ w2p,
    const float* __restrict__ fb1, const float* __restrict__ fb2,
    const float* __restrict__ g2v, const float* __restrict__ b2v,
    const int* __restrict__ abase, float* __restrict__ x) {
  __shared__ __align__(16) unsigned short soA[16 * 72];
  __shared__ float sxF[16][35];
  __shared__ __align__(16) unsigned short sxA2[16 * 72];
  __shared__ float sxF2[16][35];
  __shared__ __align__(16) unsigned short hw_[4][16 * 40];
  __shared__ float yred[4][16][49];
  int t = threadIdx.x;
  int w = t >> 6, lane = t & 63, quad = lane >> 4, col = lane & 15;
  int base = abase[0] * HW;
  int ql0 = blockIdx.x * 16;
  int nr = min(16, HW - ql0);
  int r0 = base + ql0;

  for (int i = t; i < 16 * 72; i += 256) { soA[i] = 0; sxA2[i] = 0; }
  for (int i = t; i < 16 * 35; i += 256) { ((float*)sxF)[i] = 0.f; ((float*)sxF2)[i] = 0.f; }
  __syncthreads();
  for (int i = t; i < nr * DD; i += 256) {
    int r = i / DD, rem = i - r * DD;
    sxF[r][rem] = x[(size_t)(r0 + r) * DD + rem];
    int ql = ql0 + r;
    int h = rem / HD, d = rem - h * HD;
    float L = 0.f, O = 0.f;
#pragma unroll
    for (int s = 0; s < NSPLIT2; s++) {
      L += lpart[((size_t)s * NHEAD + h) * 128 + ql];
      O += opart[(((size_t)s * NHEAD + h) * 128 + ql) * HD + d];
    }
    soA[r * 72 + rem] = f2b(O / L);
  }
  __syncthreads();
  if (w == 0) {
    bf16x8 a0 = *(const bf16x8*)&soA[col * 72 + quad * 8];
    bf16x8 a1 = *(const bf16x8*)&soA[col * 72 + 32 + quad * 8];
    f32x4 y[3];
#pragma unroll
    for (int nt = 0; nt < 3; nt++) {
      int n = nt * 16 + col;
      bf16x8 b0 = *(const bf16x8*)&opwp[n * 64 + quad * 8];
      bf16x8 b1 = *(const bf16x8*)&opwp[n * 64 + 32 + quad * 8];
      f32x4 acc = {0.f, 0.f, 0.f, 0.f};
      acc = __builtin_amdgcn_mfma_f32_16x16x32_bf16(a0, b0, acc, 0, 0, 0);
      y[nt] = __builtin_amdgcn_mfma_f32_16x16x32_bf16(a1, b1, acc, 0, 0, 0);
    }
    float yv[3][4];
    float s1[4] = {0.f, 0.f, 0.f, 0.f}, s2[4] = {0.f, 0.f, 0.f, 0.f};
#pragma unroll
    for (int nt = 0; nt < 3; nt++) {
      int d = nt * 16 + col;
      bool vd = d < DD;
      float ob = vd ? opb[d] : 0.f;
#pragma unroll
      for (int r = 0; r < 4; r++) {
        int row = quad * 4 + r;
        float v = vd ? (y[nt][r] + ob + sxF[row][d]) : 0.f;
        yv[nt][r] = v;
        s1[r] += v;
        s2[r] += v * v;
      }
    }
#pragma unroll
    for (int msk = 1; msk <= 8; msk <<= 1)
#pragma unroll
      for (int r = 0; r < 4; r++) {
        s1[r] += __shfl_xor(s1[r], msk);
        s2[r] += __shfl_xor(s2[r], msk);
      }
#pragma unroll
    for (int r = 0; r < 4; r++) {
      int row = quad * 4 + r;
      float mean = s1[r] * (1.f / DD);
      float var = s2[r] * (1.f / DD) - mean * mean;
      float rs = rsqrtf(var + EPSF);
#pragma unroll
      for (int nt = 0; nt < 3; nt++) {
        int d = nt * 16 + col;
        if (d < DD) {
          float o = (yv[nt][r] - mean) * rs * g1v[d] + b1v[d];
          sxF2[row][d] = o;
          sxA2[row * 72 + d] = f2b(o);
        }
      }
    }
  }
  __syncthreads();
  bf16x8 a0 = *(const bf16x8*)&sxA2[col * 72 + quad * 8];
  bf16x8 a1 = *(const bf16x8*)&sxA2[col * 72 + 32 + quad * 8];
  unsigned short* myh = &hw_[w][0];
  f32x4 acc3[3];
#pragma unroll
  for (int nt = 0; nt < 3; nt++) acc3[nt] = (f32x4){0.f, 0.f, 0.f, 0.f};
  for (int kt = 0; kt < 16; kt++) {
    int fbase = kt * 128 + w * 32;
#pragma unroll
    for (int nt = 0; nt < 2; nt++) {
      int f = fbase + nt * 16 + col;
      bf16x8 b0f = *(const bf16x8*)&w1p[f * 64 + quad * 8];
      bf16x8 b1f = *(const bf16x8*)&w1p[f * 64 + 32 + quad * 8];
      f32x4 hacc = {0.f, 0.f, 0.f, 0.f};
      hacc = __builtin_amdgcn_mfma_f32_16x16x32_bf16(a0, b0f, hacc, 0, 0, 0);
      hacc = __builtin_amdgcn_mfma_f32_16x16x32_bf16(a1, b1f, hacc, 0, 0, 0);
      float bias = fb1[f];
#pragma unroll
      for (int r = 0; r < 4; r++) {
        float hv = fmaxf(hacc[r] + bias, 0.f);
        myh[(quad * 4 + r) * 40 + nt * 16 + col] = f2b(hv);
      }
    }
    bf16x8 pa = *(const bf16x8*)&myh[col * 40 + quad * 8];
#pragma unroll
    for (int nt = 0; nt < 3; nt++) {
      int n = nt * 16 + col;
      bf16x8 wb = *(const bf16x8*)&w2p[(size_t)n * FF + fbase + quad * 8];
      acc3[nt] = __builtin_amdgcn_mfma_f32_16x16x32_bf16(pa, wb, acc3[nt], 0, 0, 0);
    }
  }
#pragma unroll
  for (int nt = 0; nt < 3; nt++)
#pragma unroll
    for (int r = 0; r < 4; r++)
      yred[w][quad * 4 + r][nt * 16 + col] = acc3[nt][r];
  __syncthreads();
  if (w == 0) {
    float yv[3][4];
    float s1[4] = {0.f, 0.f, 0.f, 0.f}, s2[4] = {0.f, 0.f, 0.f, 0.f};
#pragma unroll
    for (int nt = 0; nt < 3; nt++) {
      int d = nt * 16 + col;
      bool valid = d < DD;
      float b2x = valid ? fb2[d] : 0.f;
#pragma unroll
      for (int r = 0; r < 4; r++) {
        int row = quad * 4 + r;
        float v = yred[0][row][nt * 16 + col] + yred[1][row][nt * 16 + col]
                + yred[2][row][nt * 16 + col] + yred[3][row][nt * 16 + col];
        v = valid ? (v + b2x + sxF2[row][d]) : 0.f;
        yv[nt][r] = v;
        s1[r] += v;
        s2[r] += v * v;
      }
    }
#pragma unroll
    for (int msk = 1; msk <= 8; msk <<= 1)
#pragma unroll
      for (int r = 0; r < 4; r++) {
        s1[r] += __shfl_xor(s1[r], msk);
        s2[r] += __shfl_xor(s2[r], msk);
      }
#pragma unroll
    for (int r = 0; r < 4; r++) {
      int row = quad * 4 + r;
      if (row >= nr) continue;
      float mean = s1[r] * (1.f / DD);
      float var = s2[r] * (1.f / DD) - mean * mean;
      float rs = rsqrtf(var + EPSF);
#pragma unroll
      for (int nt = 0; nt < 3; nt++) {
        int d = nt * 16 + col;
        if (d < DD)
          x[(size_t)(r0 + row) * DD + d] = (yv[nt][r] - mean) * rs * g2v[d] + b2v[d];
      }
    }
  }
}

// ---- dispatch 7: final ----
__global__ __launch_bounds__(64) void final_kernel(
    const float* __restrict__ x, const int* __restrict__ aidx, float* __restrict__ out) {
  int d = threadIdx.x;
  if (d >= DD) return;
  int start = (*aidx) * HW;
  float acc = 0.f;
  for (int j = 0; j < HW; j++) acc += x[(size_t)(start + j) * DD + d];
  out[d] = acc * (1.f / HW);
}

extern "C" void kernel_launch(void* const* d_in, const int* in_sizes, int n_in,
                              void* d_out, int out_size, void* d_ws, size_t ws_size,
                              hipStream_t stream) {
  const float* obs = (const float*)d_in[0];
  const float* c1w = (const float*)d_in[1];
  const float* c1b = (const float*)d_in[2];
  const float* c2w = (const float*)d_in[3];
  const float* c2b = (const float*)d_in[4];
  const float* ipw = (const float*)d_in[5];
  const float* ipb = (const float*)d_in[6];
  const float* opw = (const float*)d_in[7];
  const float* opb = (const float*)d_in[8];
  const float* l1w = (const float*)d_in[9];
  const float* l1b = (const float*)d_in[10];
  const float* l2w = (const float*)d_in[11];
  const float* l2b = (const float*)d_in[12];
  const float* g1 = (const float*)d_in[13];
  const float* b1 = (const float*)d_in[14];
  const float* g2 = (const float*)d_in[15];
  const float* b2 = (const float*)d_in[16];
  float* out = (float*)d_out;

  float* ws = (float*)d_ws;
  size_t off = 0;
  float* x     = ws + off; off += SS * DD;
  float* qkv   = ws + off; off += SS * 102;
  float* cell  = ws + off; off += HW * CC;
  int*   aidx  = (int*)(ws + off); off += 1;
  off = (off + 3) & ~(size_t)3;
  float* Pt    = ws + off; off += 2 * HW * 102;
  float* opart = ws + off; off += (size_t)NSPLIT2 * NHEAD * 128 * HD;
  float* lpart = ws + off; off += (size_t)NSPLIT2 * NHEAD * 128;
  off = (off + 3) & ~(size_t)3;
  unsigned short* kfp  = (unsigned short*)(ws + off); off += NKF / 2;
  unsigned short* vfp  = (unsigned short*)(ws + off); off += NVF / 2;
  float* v16 = ws + off; off += NV16;
  unsigned short* ipwp = (unsigned short*)(ws + off); off += 2 * NIP / 2;
  unsigned short* opwp = (unsigned short*)(ws + off); off += 2 * NOP / 2;
  unsigned short* w1p  = (unsigned short*)(ws + off); off += 2 * NW1 / 2;
  unsigned short* w2p  = (unsigned short*)(ws + off); off += 2 * NW2 / 2;

  const int prep_grid = 1 + LPREP_BLOCKS + ZERO_BLOCKS;  // 3173
  const int pt_blocks = (2 * HW * 102 + 255) / 256;      // 65
  const int fl1_blocks = (SS + 15) / 16;                 // 411

  prep_kernel<<<prep_grid, 256, 0, stream>>>(
      obs, c1w, c1b, c2w, c2b, cell, aidx,
      ipw, opw, l1w, l2w, ipwp, opwp, w1p, w2p, kfp, vfp, v16);
  ptprep_kernel<<<pt_blocks, 256, 0, stream>>>(cell, ipw, ipb, Pt);
  fl1_kernel<<<fl1_blocks, 256, 0, stream>>>(
      cell, Pt, opwp, opb, g1, b1, w1p, w2p, l1b, l2b, g2, b2, x);
  qkv2_kernel<<<210, 256, 0, stream>>>(
      x, ipwp + NIP, ipb + 102, aidx, qkv, kfp, vfp, v16);
  dim3 a2g(2, NHEAD, NSPLIT2);
  attn2_kernel<<<a2g, 256, 0, stream>>>(qkv, kfp, vfp, v16, aidx, opart, lpart);
  fl2_kernel<<<6, 256, 0, stream>>>(
      opart, lpart, opwp + NOP, opb + DD, g1 + DD, b1 + DD,
      w1p + NW1, w2p + NW2, l1b + FF, l2b + DD, g2 + DD, b2 + DD, aidx, x);
  final_kernel<<<1, 64, 0, stream>>>(x, aidx, out);
}

// Round 12
// 195.505 us; speedup vs baseline: 15.0975x; 1.0392x over previous
//
#include <hip/hip_runtime.h>
#include <hip/hip_bf16.h>

#define HH 9
#define WW 9
#define HW 81
#define CC 16
#define DD 34
#define SS 6561
#define NHEAD 2
#define HD 17
#define FF 2048
#define EPSF 1e-5f

#define NTILES 52
#define NSPLIT2 26
#define QB 64

#define NIP 7168
#define NOP 3072
#define NW1 131072
#define NW2 98304
#define NLTOT (NIP + NOP + NW1 + NW2)   // 239616
#define LPREP_BLOCKS 1872               // 2*NLTOT/256
#define NKF 425984                      // kfp shorts
#define NVF 212992                      // vfp shorts
#define NV16 13312                      // v16 floats
#define ZERO_WORDS 332800               // NKF/2 + NVF/2 + NV16
#define ZERO_BLOCKS 1300

#define NEAB 124416                     // 2h x 2p x 2(A,B) x 81 x 96 floats
#define NVFL1 12288                     // 2h x 2p x 32 x 96 shorts

typedef __attribute__((ext_vector_type(8))) short bf16x8;
typedef __attribute__((ext_vector_type(4))) float f32x4;

__device__ __forceinline__ unsigned short f2b(float f) {
  unsigned int u = __float_as_uint(f);
  u += 0x7fffu + ((u >> 16) & 1u);
  return (unsigned short)(u >> 16);
}

// ---- dispatch 1: block 0 = conv1+conv2+argmax; 1..1872 = weight pack; rest zero kfp/vfp/v16 ----
__global__ __launch_bounds__(256) void prep_kernel(
    const float* __restrict__ obs, const float* __restrict__ w1, const float* __restrict__ b1,
    const float* __restrict__ w2, const float* __restrict__ b2,
    float* __restrict__ cell, int* __restrict__ aidx,
    const float* __restrict__ ipw, const float* __restrict__ opw,
    const float* __restrict__ l1w, const float* __restrict__ l2w,
    unsigned short* __restrict__ ipwp, unsigned short* __restrict__ opwp,
    unsigned short* __restrict__ w1p, unsigned short* __restrict__ w2p,
    unsigned short* __restrict__ kfp, unsigned short* __restrict__ vfp,
    float* __restrict__ v16) {
  int bx = blockIdx.x;
  int t = threadIdx.x;
  if (bx == 0) {
    __shared__ float s_obs[2][11][11];
    __shared__ float s_w1[288];
    __shared__ float s_w2[2304];
    __shared__ float s_b1[16], s_b2[16];
    __shared__ float y1[CC][121];
    for (int i = t; i < 2 * 121; i += 256) ((float*)s_obs)[i] = 0.f;
    for (int i = t; i < CC * 121; i += 256) ((float*)y1)[i] = 0.f;
    for (int i = t; i < 288; i += 256) s_w1[i] = w1[i];
    for (int i = t; i < 2304; i += 256) s_w2[i] = w2[i];
    if (t < 16) { s_b1[t] = b1[t]; s_b2[t] = b2[t]; }
    __syncthreads();
    for (int i = t; i < 2 * HW; i += 256) {
      int ic = i / HW, p = i % HW;
      s_obs[ic][1 + p / WW][1 + p % WW] = obs[i];
    }
    __syncthreads();
    if (t == 0) {
      int best = 0; float bv = s_obs[0][1][1];
      for (int p = 1; p < HW; p++) {
        float v = s_obs[0][1 + p / WW][1 + p % WW];
        if (v > bv) { bv = v; best = p; }
      }
      *aidx = best;
    }
    for (int idx = t; idx < CC * HW; idx += 256) {
      int c = idx / HW, p = idx % HW;
      int i = p / WW, j = p % WW;
      float acc = s_b1[c];
#pragma unroll
      for (int ic = 0; ic < 2; ic++)
#pragma unroll
        for (int di = 0; di < 3; di++)
#pragma unroll
          for (int dj = 0; dj < 3; dj++)
            acc += s_obs[ic][i + di][j + dj] * s_w1[((c * 2 + ic) * 3 + di) * 3 + dj];
      y1[c][(i + 1) * 11 + (j + 1)] = fmaxf(acc, 0.f);
    }
    __syncthreads();
    for (int idx = t; idx < CC * HW; idx += 256) {
      int c = idx / HW, p = idx % HW;
      int i = p / WW, j = p % WW;
      float acc = s_b2[c];
#pragma unroll
      for (int ic = 0; ic < CC; ic++)
#pragma unroll
        for (int di = 0; di < 3; di++)
#pragma unroll
          for (int dj = 0; dj < 3; dj++)
            acc += y1[ic][(i + di) * 11 + (j + dj)] * s_w2[((c * CC + ic) * 3 + di) * 3 + dj];
      cell[p * CC + c] = fmaxf(acc, 0.f);
    }
  } else if (bx <= LPREP_BLOCKS) {
    int i = (bx - 1) * 256 + t;
    int layer = i / NLTOT;
    int r = i % NLTOT;
    if (r < NIP) {
      int n = r >> 6, k = r & 63;
      ipwp[layer * NIP + r] =
          (n < 102 && k < DD) ? f2b(ipw[(size_t)layer * 102 * DD + n * DD + k]) : (unsigned short)0;
    } else if (r < NIP + NOP) {
      int rr = r - NIP;
      int n = rr >> 6, k = rr & 63;
      opwp[layer * NOP + rr] =
          (n < DD && k < DD) ? f2b(opw[(size_t)layer * DD * DD + n * DD + k]) : (unsigned short)0;
    } else if (r < NIP + NOP + NW1) {
      int rr = r - NIP - NOP;
      int f = rr >> 6, k = rr & 63;
      w1p[layer * NW1 + rr] =
          (k < DD) ? f2b(l1w[(size_t)layer * FF * DD + f * DD + k]) : (unsigned short)0;
    } else {
      int rr = r - NIP - NOP - NW1;
      int d = rr >> 11, kk = rr & 2047;
      w2p[layer * NW2 + rr] =
          (d < DD) ? f2b(l2w[(size_t)layer * DD * FF + d * FF + kk]) : (unsigned short)0;
    }
  } else {
    int zi = (bx - 1 - LPREP_BLOCKS) * 256 + t;
    if (zi < NKF / 2) ((unsigned int*)kfp)[zi] = 0u;
    else if (zi < NKF / 2 + NVF / 2) ((unsigned int*)vfp)[zi - NKF / 2] = 0u;
    else if (zi < ZERO_WORDS) v16[zi - NKF / 2 - NVF / 2] = 0.f;
  }
}

// ---- dispatch 2: layer-1 separable qkv tables ----
__global__ __launch_bounds__(256) void ptprep_kernel(
    const float* __restrict__ cell, const float* __restrict__ ipw,
    const float* __restrict__ ipb, float* __restrict__ Pt) {
  int idx = blockIdx.x * 256 + threadIdx.x;
  if (idx >= 2 * HW * 102) return;
  int part = idx / (HW * 102);
  int rem = idx % (HW * 102);
  int a = rem / 102, n = rem % 102;
  float ra = (float)(a / WW) * 0.25f, ca = (float)(a % WW) * 0.25f;
  float acc;
  if (part == 0) {
    acc = ipb[n] + ipw[n * DD + 32] * ra + ipw[n * DD + 33] * ca;
    for (int f = 0; f < CC; f++) acc += ipw[n * DD + f] * cell[a * CC + f];
  } else {
    acc = -(ipw[n * DD + 32] * ra + ipw[n * DD + 33] * ca);
    for (int f = 0; f < CC; f++) acc += ipw[n * DD + CC + f] * cell[a * CC + f];
  }
  Pt[idx] = acc;
}

// ---- dispatch 3: exp-factorized score matrices + L1 V fragment table ----
// eAB[h][p][ab][row][96]: ab=0 -> eA (i-side, q=part0), ab=1 -> eB (j-side, q=part1)
//   e = exp(min(scale * q_row . k_row, 40)); exp(A+B) = eA*eB (softmax shift-invariance).
// vfragL1[h*2+p][n][96]: n<17 -> V[a][n], n==17 -> 1 (gives S column), else 0.
__global__ __launch_bounds__(256) void expprep_kernel(
    const float* __restrict__ Pt, float* __restrict__ eAB,
    unsigned short* __restrict__ vfragL1) {
  int idx = blockIdx.x * 256 + threadIdx.x;
  const float scale = 0.24253562503633297f;
  if (idx < NEAB) {
    int a = idx % 96; int rest = idx / 96;
    int row = rest % 81; rest /= 81;
    int ab = rest & 1, p = (rest >> 1) & 1, h = rest >> 2;
    float e = 0.f;
    if (a < HW) {
      const float* qrow = Pt + (size_t)ab * (HW * 102) + row * 102 + h * HD;
      const float* krow = Pt + (size_t)p * (HW * 102) + a * 102 + DD + h * HD;
      float dot = 0.f;
#pragma unroll
      for (int d = 0; d < HD; d++) dot += qrow[d] * krow[d];
      e = __expf(fminf(dot * scale, 40.f));
    }
    eAB[idx] = e;
  } else if (idx < NEAB + NVFL1) {
    int j = idx - NEAB;
    int a = j % 96; int rest = j / 96;
    int n = rest % 32; rest /= 32;
    int p = rest & 1, h = rest >> 1;
    float v = 0.f;
    if (a < HW) {
      if (n < HD) v = Pt[(size_t)p * (HW * 102) + a * 102 + 2 * DD + h * HD + n];
      else if (n == HD) v = 1.f;
    }
    vfragL1[((size_t)(h * 2 + p) * 32 + n) * 96 + a] = f2b(v);
  }
}

// ---- dispatch 4: fused layer-1: tokens + E-product MFMA attention + proj + LN1 + FF + LN2 ----
// 411 blocks x 16 rows. Wave w handles (h = w>>1, p = w&1) for attention.
__global__ __launch_bounds__(256) void fl1_kernel(
    const float* __restrict__ cell, const float* __restrict__ eAB,
    const unsigned short* __restrict__ vfragL1,
    const unsigned short* __restrict__ opwp, const float* __restrict__ opb,
    const float* __restrict__ g1v, const float* __restrict__ b1v,
    const unsigned short* __restrict__ w1p, const unsigned short* __restrict__ w2p,
    const float* __restrict__ fb1, const float* __restrict__ fb2,
    const float* __restrict__ g2v, const float* __restrict__ b2v,
    float* __restrict__ x) {
  __shared__ __align__(16) unsigned short sE[4][16 * 96];  // wave-private E = eA*eB
  __shared__ __align__(16) unsigned short soA[16 * 72];
  __shared__ float sxF[16][35];
  __shared__ __align__(16) unsigned short sxA2[16 * 72];
  __shared__ float sxF2[16][35];
  __shared__ __align__(16) unsigned short hw_[4][16 * 40];
  __shared__ float yred[4][16][49];
  int t = threadIdx.x;
  int w = t >> 6, lane = t & 63, quad = lane >> 4, col = lane & 15;
  int r0 = blockIdx.x * 16;
  int nr = min(16, SS - r0);

  for (int i = t; i < 16 * 72; i += 256) { soA[i] = 0; sxA2[i] = 0; }
  for (int i = t; i < 16 * 35; i += 256) { ((float*)sxF)[i] = 0.f; ((float*)sxF2)[i] = 0.f; }
  for (int i = t; i < nr * DD; i += 256) {
    int r = i / DD, d = i - r * DD;
    int row = r0 + r;
    int ii = row / HW, jj = row - ii * HW;
    float v;
    if (d < CC) v = cell[ii * CC + d];
    else if (d < 2 * CC) v = cell[jj * CC + (d - CC)];
    else if (d == 32) v = (float)((ii / WW) - (jj / WW)) * 0.25f;
    else v = (float)((ii % WW) - (jj % WW)) * 0.25f;
    sxF[r][d] = v;
  }

  // ---- attention: E[t][a] = eA[i_t][a]*eB[j_t][a]; [EV|V16|S] = E @ vfrag ----
  {
    int h = w >> 1, p = w & 1;
    const float* eA = eAB + ((size_t)((h * 2 + p) * 2 + 0) * 81) * 96;
    const float* eB = eAB + ((size_t)((h * 2 + p) * 2 + 1) * 81) * 96;
    int tl = lane >> 2, asub = lane & 3;
    int row = r0 + tl;
    int tc = row < SS ? row : SS - 1;
    int it = tc / HW, jt = tc - it * HW;
    const float* eAr = eA + it * 96 + asub * 24;
    const float* eBr = eB + jt * 96 + asub * 24;
    unsigned short etmp[24];
#pragma unroll
    for (int k = 0; k < 24; k++) etmp[k] = f2b(eAr[k] * eBr[k]);
    unsigned short* Eb = &sE[w][tl * 96 + asub * 24];
#pragma unroll
    for (int k = 0; k < 3; k++)
      *(bf16x8*)(Eb + k * 8) = *(bf16x8*)(etmp + k * 8);
    // wave-private LDS: lgkmcnt only, no barrier needed
    const unsigned short* vf = vfragL1 + (size_t)(h * 2 + p) * 32 * 96;
    f32x4 acc0 = {0.f, 0.f, 0.f, 0.f}, acc1 = {0.f, 0.f, 0.f, 0.f};
#pragma unroll
    for (int c = 0; c < 3; c++) {
      bf16x8 ea = *(const bf16x8*)&sE[w][col * 96 + c * 32 + quad * 8];
      bf16x8 vb0 = *(const bf16x8*)&vf[col * 96 + c * 32 + quad * 8];
      bf16x8 vb1 = *(const bf16x8*)&vf[(16 + col) * 96 + c * 32 + quad * 8];
      acc0 = __builtin_amdgcn_mfma_f32_16x16x32_bf16(ea, vb0, acc0, 0, 0, 0);
      acc1 = __builtin_amdgcn_mfma_f32_16x16x32_bf16(ea, vb1, acc1, 0, 0, 0);
    }
    // S lives in C column 17 (acc1, lanes col==1); broadcast within quad
    float Sr[4];
#pragma unroll
    for (int r = 0; r < 4; r++) Sr[r] = __shfl(acc1[r], (lane & 48) + 1);
#pragma unroll
    for (int r = 0; r < 4; r++) {
      int rr = quad * 4 + r;
      float inv = 1.f / Sr[r];
      yred[w][rr][col] = acc0[r] * inv;            // d = col (0..15)
      if (col == 0) yred[w][rr][16] = acc1[r] * inv;  // d = 16 (V16 column)
    }
  }
  __syncthreads();
  // combine parts: O[t][h*17+d] = O_p0 + O_p1
  for (int i = t; i < 16 * DD; i += 256) {
    int r = i / DD, dd = i - r * DD;
    int h2 = dd / HD, d2 = dd - h2 * HD;
    soA[r * 72 + dd] = f2b(yred[2 * h2][r][d2] + yred[2 * h2 + 1][r][d2]);
  }
  __syncthreads();

  // proj + residual + LN1 (wave 0), writes sxA2/sxF2
  if (w == 0) {
    bf16x8 a0 = *(const bf16x8*)&soA[col * 72 + quad * 8];
    bf16x8 a1 = *(const bf16x8*)&soA[col * 72 + 32 + quad * 8];
    f32x4 y[3];
#pragma unroll
    for (int nt = 0; nt < 3; nt++) {
      int n = nt * 16 + col;
      bf16x8 b0 = *(const bf16x8*)&opwp[n * 64 + quad * 8];
      bf16x8 b1 = *(const bf16x8*)&opwp[n * 64 + 32 + quad * 8];
      f32x4 acc = {0.f, 0.f, 0.f, 0.f};
      acc = __builtin_amdgcn_mfma_f32_16x16x32_bf16(a0, b0, acc, 0, 0, 0);
      y[nt] = __builtin_amdgcn_mfma_f32_16x16x32_bf16(a1, b1, acc, 0, 0, 0);
    }
    float yv[3][4];
    float s1[4] = {0.f, 0.f, 0.f, 0.f}, s2[4] = {0.f, 0.f, 0.f, 0.f};
#pragma unroll
    for (int nt = 0; nt < 3; nt++) {
      int d = nt * 16 + col;
      bool vd = d < DD;
      float ob = vd ? opb[d] : 0.f;
#pragma unroll
      for (int r = 0; r < 4; r++) {
        int row = quad * 4 + r;
        float v = vd ? (y[nt][r] + ob + sxF[row][d]) : 0.f;
        yv[nt][r] = v;
        s1[r] += v;
        s2[r] += v * v;
      }
    }
#pragma unroll
    for (int msk = 1; msk <= 8; msk <<= 1)
#pragma unroll
      for (int r = 0; r < 4; r++) {
        s1[r] += __shfl_xor(s1[r], msk);
        s2[r] += __shfl_xor(s2[r], msk);
      }
#pragma unroll
    for (int r = 0; r < 4; r++) {
      int row = quad * 4 + r;
      float mean = s1[r] * (1.f / DD);
      float var = s2[r] * (1.f / DD) - mean * mean;
      float rs = rsqrtf(var + EPSF);
#pragma unroll
      for (int nt = 0; nt < 3; nt++) {
        int d = nt * 16 + col;
        if (d < DD) {
          float o = (yv[nt][r] - mean) * rs * g1v[d] + b1v[d];
          sxF2[row][d] = o;
          sxA2[row * 72 + d] = f2b(o);
        }
      }
    }
  }
  __syncthreads();

  // FF (all 4 waves, barrier-free K-loop) + LN2, write x
  bf16x8 a0 = *(const bf16x8*)&sxA2[col * 72 + quad * 8];
  bf16x8 a1 = *(const bf16x8*)&sxA2[col * 72 + 32 + quad * 8];
  unsigned short* myh = &hw_[w][0];
  f32x4 acc3[3];
#pragma unroll
  for (int nt = 0; nt < 3; nt++) acc3[nt] = (f32x4){0.f, 0.f, 0.f, 0.f};
  for (int kt = 0; kt < 16; kt++) {
    int fbase = kt * 128 + w * 32;
#pragma unroll
    for (int nt = 0; nt < 2; nt++) {
      int f = fbase + nt * 16 + col;
      bf16x8 b0f = *(const bf16x8*)&w1p[f * 64 + quad * 8];
      bf16x8 b1f = *(const bf16x8*)&w1p[f * 64 + 32 + quad * 8];
      f32x4 hacc = {0.f, 0.f, 0.f, 0.f};
      hacc = __builtin_amdgcn_mfma_f32_16x16x32_bf16(a0, b0f, hacc, 0, 0, 0);
      hacc = __builtin_amdgcn_mfma_f32_16x16x32_bf16(a1, b1f, hacc, 0, 0, 0);
      float bias = fb1[f];
#pragma unroll
      for (int r = 0; r < 4; r++) {
        float hv = fmaxf(hacc[r] + bias, 0.f);
        myh[(quad * 4 + r) * 40 + nt * 16 + col] = f2b(hv);
      }
    }
    bf16x8 pa = *(const bf16x8*)&myh[col * 40 + quad * 8];
#pragma unroll
    for (int nt = 0; nt < 3; nt++) {
      int n = nt * 16 + col;
      bf16x8 wb = *(const bf16x8*)&w2p[(size_t)n * FF + fbase + quad * 8];
      acc3[nt] = __builtin_amdgcn_mfma_f32_16x16x32_bf16(pa, wb, acc3[nt], 0, 0, 0);
    }
  }
#pragma unroll
  for (int nt = 0; nt < 3; nt++)
#pragma unroll
    for (int r = 0; r < 4; r++)
      yred[w][quad * 4 + r][nt * 16 + col] = acc3[nt][r];
  __syncthreads();
  if (w == 0) {
    float yv[3][4];
    float s1[4] = {0.f, 0.f, 0.f, 0.f}, s2[4] = {0.f, 0.f, 0.f, 0.f};
#pragma unroll
    for (int nt = 0; nt < 3; nt++) {
      int d = nt * 16 + col;
      bool valid = d < DD;
      float b2x = valid ? fb2[d] : 0.f;
#pragma unroll
      for (int r = 0; r < 4; r++) {
        int row = quad * 4 + r;
        float v = yred[0][row][nt * 16 + col] + yred[1][row][nt * 16 + col]
                + yred[2][row][nt * 16 + col] + yred[3][row][nt * 16 + col];
        v = valid ? (v + b2x + sxF2[row][d]) : 0.f;
        yv[nt][r] = v;
        s1[r] += v;
        s2[r] += v * v;
      }
    }
#pragma unroll
    for (int msk = 1; msk <= 8; msk <<= 1)
#pragma unroll
      for (int r = 0; r < 4; r++) {
        s1[r] += __shfl_xor(s1[r], msk);
        s2[r] += __shfl_xor(s2[r], msk);
      }
#pragma unroll
    for (int r = 0; r < 4; r++) {
      int row = quad * 4 + r;
      if (row >= nr) continue;
      float mean = s1[r] * (1.f / DD);
      float var = s2[r] * (1.f / DD) - mean * mean;
      float rs = rsqrtf(var + EPSF);
#pragma unroll
      for (int nt = 0; nt < 3; nt++) {
        int d = nt * 16 + col;
        if (d < DD)
          x[(size_t)(r0 + row) * DD + d] = (yv[nt][r] - mean) * rs * g2v[d] + b2v[d];
      }
    }
  }
}

// ---- dispatch 5: layer-2 qkv. Blocks 0..205: K/V all rows, fragment-packed scatter;
//      blocks 206..209: Q for 128 rows at runtime base -> qkv. ----
__global__ __launch_bounds__(256) void qkv2_kernel(
    const float* __restrict__ x, const unsigned short* __restrict__ ipwp,
    const float* __restrict__ ipb, const int* __restrict__ abase,
    float* __restrict__ qkv, unsigned short* __restrict__ kfp,
    unsigned short* __restrict__ vfp, float* __restrict__ v16) {
  __shared__ __align__(16) unsigned short sxA[32 * 72];
  int t = threadIdx.x;
  int w = t >> 6, lane = t & 63, quad = lane >> 4, col = lane & 15;
  int m0 = (w & 1) * 16, half = w >> 1;
  bool qpart = blockIdx.x >= 206;
  int row0 = qpart ? (abase[0] * HW + (blockIdx.x - 206) * 32) : blockIdx.x * 32;
  int nr = min(32, SS - row0);
  for (int i = t; i < 32 * 72; i += 256) sxA[i] = 0;
  __syncthreads();
  for (int i = t; i < nr * DD; i += 256) {
    int r = i / DD, d = i - r * DD;
    sxA[r * 72 + d] = f2b(x[(size_t)(row0 + r) * DD + d]);
  }
  __syncthreads();
  bf16x8 a0 = *(const bf16x8*)&sxA[(m0 + col) * 72 + quad * 8];
  bf16x8 a1 = *(const bf16x8*)&sxA[(m0 + col) * 72 + 32 + quad * 8];
  if (!qpart) {
    int ntc = half ? 2 : 3;
    for (int nt2 = 0; nt2 < ntc; nt2++) {
      int nt = half * 3 + nt2;
      int n = DD + nt * 16 + col;
      int nc = n < 112 ? n : 111;
      bf16x8 b0 = *(const bf16x8*)&ipwp[nc * 64 + quad * 8];
      bf16x8 b1 = *(const bf16x8*)&ipwp[nc * 64 + 32 + quad * 8];
      f32x4 acc = {0.f, 0.f, 0.f, 0.f};
      acc = __builtin_amdgcn_mfma_f32_16x16x32_bf16(a0, b0, acc, 0, 0, 0);
      acc = __builtin_amdgcn_mfma_f32_16x16x32_bf16(a1, b1, acc, 0, 0, 0);
      if (n < 102) {
        float bias = ipb[n];
        int kd = n - DD;
#pragma unroll
        for (int r = 0; r < 4; r++) {
          int m = m0 + quad * 4 + r;
          if (m >= nr) continue;
          int tok = row0 + m;
          float val = acc[r] + bias;
          int T = tok >> 7, tl = tok & 127;
          if (kd < 2 * HD) {
            int h = kd >= HD;
            int d = kd - h * HD;
            int colf = tl >> 3, ntk = tl & 7;
            kfp[(((size_t)h * NTILES + T) * 8 + ntk) * 512 +
                ((d >> 3) * 16 + colf) * 8 + (d & 7)] = f2b(val);
          } else {
            int vd = kd - 2 * HD;
            int h = vd >= HD;
            int d = vd - h * HD;
            if (d < 16) {
              int c = tl >> 5, qf = (tl >> 3) & 3, j = tl & 7;
              vfp[(((size_t)h * NTILES + T) * 4 + c) * 512 +
                  (qf * 16 + d) * 8 + j] = f2b(val);
            } else {
              v16[(size_t)h * (NTILES * 128) + tok] = val;
            }
          }
        }
      }
    }
  } else {
    int ntc = half ? 1 : 2;
    for (int nt2 = 0; nt2 < ntc; nt2++) {
      int nt = half * 2 + nt2;
      int n = nt * 16 + col;
      bf16x8 b0 = *(const bf16x8*)&ipwp[n * 64 + quad * 8];
      bf16x8 b1 = *(const bf16x8*)&ipwp[n * 64 + 32 + quad * 8];
      f32x4 acc = {0.f, 0.f, 0.f, 0.f};
      acc = __builtin_amdgcn_mfma_f32_16x16x32_bf16(a0, b0, acc, 0, 0, 0);
      acc = __builtin_amdgcn_mfma_f32_16x16x32_bf16(a1, b1, acc, 0, 0, 0);
      if (n < DD) {
        float bias = ipb[n];
#pragma unroll
        for (int r = 0; r < 4; r++) {
          int m = row0 + m0 + quad * 4 + r;
          if (m < SS) qkv[(size_t)m * 102 + n] = acc[r] + bias;
        }
      }
    }
  }
}

// ---- dispatch 6: layer-2 attention (81 queries, split-K 26) ----
__global__ __launch_bounds__(256) void attn2_kernel(
    const float* __restrict__ qkv, const unsigned short* __restrict__ kfp,
    const unsigned short* __restrict__ vfp, const float* __restrict__ v16,
    const int* __restrict__ abase,
    float* __restrict__ opart, float* __restrict__ lpart) {
  __shared__ __align__(16) unsigned short scb[4][16 * 136];
  int t = threadIdx.x, w = t >> 6, lane = t & 63, quad = lane >> 4, col = lane & 15;
  int h = blockIdx.y, sp = blockIdx.z;
  int base = abase[0] * HW;
  int q0 = blockIdx.x * QB;
  const float scale = 0.24253562503633297f;
  const unsigned short* kf = kfp + (size_t)h * (NTILES * 8 * 512);
  const unsigned short* vf = vfp + (size_t)h * (NTILES * 4 * 512);
  const float* v16h = v16 + (size_t)h * (NTILES * 128);
  unsigned short* myscb = &scb[w][0];

  int mq = base + q0 + w * 16 + col;
  int qc = mq < SS ? mq : SS - 1;
  bf16x8 aq;
#pragma unroll
  for (int j = 0; j < 8; j++) {
    int d = quad * 8 + j;
    aq[j] = (short)((d < HD) ? f2b(qkv[(size_t)qc * 102 + h * HD + d] * scale) : 0);
  }

  f32x4 oacc = {0.f, 0.f, 0.f, 0.f};
  float o16a[4] = {0.f, 0.f, 0.f, 0.f};
  float lreg[4] = {0.f, 0.f, 0.f, 0.f};

  for (int tile = sp; tile < NTILES; tile += NSPLIT2) {
    int k0 = tile * 128;
    const unsigned short* kt = kf + (size_t)tile * (8 * 512);
    f32x4 s[8];
#pragma unroll
    for (int nt = 0; nt < 8; nt++) {
      bf16x8 kb = *(const bf16x8*)(kt + nt * 512 + lane * 8);
      f32x4 z = {0.f, 0.f, 0.f, 0.f};
      s[nt] = __builtin_amdgcn_mfma_f32_16x16x32_bf16(aq, kb, z, 0, 0, 0);
    }
    if (k0 + 128 > SS) {
#pragma unroll
      for (int nt = 0; nt < 8; nt++)
        if (k0 + col * 8 + nt >= SS) {
          s[nt][0] = -1e30f; s[nt][1] = -1e30f; s[nt][2] = -1e30f; s[nt][3] = -1e30f;
        }
    }
#pragma unroll
    for (int r = 0; r < 4; r++) {
      bf16x8 pv;
      float psl = 0.f;
#pragma unroll
      for (int nt = 0; nt < 8; nt++) {
        float p = __expf(fminf(s[nt][r], 70.f));
        s[nt][r] = p;
        psl += p;
        pv[nt] = (short)f2b(p);
      }
      lreg[r] += psl;
      *(bf16x8*)(myscb + (quad * 4 + r) * 136 + col * 8) = pv;
    }
    f32x4 va = *(const f32x4*)(v16h + k0 + col * 8);
    f32x4 vb4 = *(const f32x4*)(v16h + k0 + col * 8 + 4);
#pragma unroll
    for (int r = 0; r < 4; r++) {
      o16a[r] += s[0][r] * va[0] + s[1][r] * va[1] + s[2][r] * va[2] + s[3][r] * va[3]
               + s[4][r] * vb4[0] + s[5][r] * vb4[1] + s[6][r] * vb4[2] + s[7][r] * vb4[3];
    }
    const unsigned short* vt = vf + (size_t)tile * (4 * 512);
#pragma unroll
    for (int c = 0; c < 4; c++) {
      bf16x8 pa = *(const bf16x8*)(myscb + col * 136 + c * 32 + quad * 8);
      bf16x8 vbf = *(const bf16x8*)(vt + c * 512 + lane * 8);
      oacc = __builtin_amdgcn_mfma_f32_16x16x32_bf16(pa, vbf, oacc, 0, 0, 0);
    }
  }
#pragma unroll
  for (int msk = 1; msk <= 8; msk <<= 1)
#pragma unroll
    for (int r = 0; r < 4; r++) {
      o16a[r] += __shfl_xor(o16a[r], msk);
      lreg[r] += __shfl_xor(lreg[r], msk);
    }
  size_t obase = ((size_t)sp * NHEAD + h) * 128;
#pragma unroll
  for (int r = 0; r < 4; r++) {
    int ql = q0 + w * 16 + quad * 4 + r;
    if (ql < HW) {
      opart[(obase + ql) * HD + col] = oacc[r];
      if (col == 0) {
        opart[(obase + ql) * HD + 16] = o16a[r];
        lpart[obase + ql] = lreg[r];
      }
    }
  }
}

// ---- dispatch 7: fused layer-2 tail: combine + proj + LN1 + FF + LN2 (6 blocks x 16 rows) ----
__global__ __launch_bounds__(256) void fl2_kernel(
    const float* __restrict__ opart, const float* __restrict__ lpart,
    const unsigned short* __restrict__ opwp, const float* __restrict__ opb,
    const float* __restrict__ g1v, const float* __restrict__ b1v,
    const unsigned short* __restrict__ w1p, const unsigned short* __restrict__ w2p,
    const float* __restrict__ fb1, const float* __restrict__ fb2,
    const float* __restrict__ g2v, const float* __restrict__ b2v,
    const int* __restrict__ abase, float* __restrict__ x) {
  __shared__ __align__(16) unsigned short soA[16 * 72];
  __shared__ float sxF[16][35];
  __shared__ __align__(16) unsigned short sxA2[16 * 72];
  __shared__ float sxF2[16][35];
  __shared__ __align__(16) unsigned short hw_[4][16 * 40];
  __shared__ float yred[4][16][49];
  int t = threadIdx.x;
  int w = t >> 6, lane = t & 63, quad = lane >> 4, col = lane & 15;
  int base = abase[0] * HW;
  int ql0 = blockIdx.x * 16;
  int nr = min(16, HW - ql0);
  int r0 = base + ql0;

  for (int i = t; i < 16 * 72; i += 256) { soA[i] = 0; sxA2[i] = 0; }
  for (int i = t; i < 16 * 35; i += 256) { ((float*)sxF)[i] = 0.f; ((float*)sxF2)[i] = 0.f; }
  __syncthreads();
  for (int i = t; i < nr * DD; i += 256) {
    int r = i / DD, rem = i - r * DD;
    sxF[r][rem] = x[(size_t)(r0 + r) * DD + rem];
    int ql = ql0 + r;
    int h = rem / HD, d = rem - h * HD;
    float L = 0.f, O = 0.f;
#pragma unroll
    for (int s = 0; s < NSPLIT2; s++) {
      L += lpart[((size_t)s * NHEAD + h) * 128 + ql];
      O += opart[(((size_t)s * NHEAD + h) * 128 + ql) * HD + d];
    }
    soA[r * 72 + rem] = f2b(O / L);
  }
  __syncthreads();
  if (w == 0) {
    bf16x8 a0 = *(const bf16x8*)&soA[col * 72 + quad * 8];
    bf16x8 a1 = *(const bf16x8*)&soA[col * 72 + 32 + quad * 8];
    f32x4 y[3];
#pragma unroll
    for (int nt = 0; nt < 3; nt++) {
      int n = nt * 16 + col;
      bf16x8 b0 = *(const bf16x8*)&opwp[n * 64 + quad * 8];
      bf16x8 b1 = *(const bf16x8*)&opwp[n * 64 + 32 + quad * 8];
      f32x4 acc = {0.f, 0.f, 0.f, 0.f};
      acc = __builtin_amdgcn_mfma_f32_16x16x32_bf16(a0, b0, acc, 0, 0, 0);
      y[nt] = __builtin_amdgcn_mfma_f32_16x16x32_bf16(a1, b1, acc, 0, 0, 0);
    }
    float yv[3][4];
    float s1[4] = {0.f, 0.f, 0.f, 0.f}, s2[4] = {0.f, 0.f, 0.f, 0.f};
#pragma unroll
    for (int nt = 0; nt < 3; nt++) {
      int d = nt * 16 + col;
      bool vd = d < DD;
      float ob = vd ? opb[d] : 0.f;
#pragma unroll
      for (int r = 0; r < 4; r++) {
        int row = quad * 4 + r;
        float v = vd ? (y[nt][r] + ob + sxF[row][d]) : 0.f;
        yv[nt][r] = v;
        s1[r] += v;
        s2[r] += v * v;
      }
    }
#pragma unroll
    for (int msk = 1; msk <= 8; msk <<= 1)
#pragma unroll
      for (int r = 0; r < 4; r++) {
        s1[r] += __shfl_xor(s1[r], msk);
        s2[r] += __shfl_xor(s2[r], msk);
      }
#pragma unroll
    for (int r = 0; r < 4; r++) {
      int row = quad * 4 + r;
      float mean = s1[r] * (1.f / DD);
      float var = s2[r] * (1.f / DD) - mean * mean;
      float rs = rsqrtf(var + EPSF);
#pragma unroll
      for (int nt = 0; nt < 3; nt++) {
        int d = nt * 16 + col;
        if (d < DD) {
          float o = (yv[nt][r] - mean) * rs * g1v[d] + b1v[d];
          sxF2[row][d] = o;
          sxA2[row * 72 + d] = f2b(o);
        }
      }
    }
  }
  __syncthreads();
  bf16x8 a0 = *(const bf16x8*)&sxA2[col * 72 + quad * 8];
  bf16x8 a1 = *(const bf16x8*)&sxA2[col * 72 + 32 + quad * 8];
  unsigned short* myh = &hw_[w][0];
  f32x4 acc3[3];
#pragma unroll
  for (int nt = 0; nt < 3; nt++) acc3[nt] = (f32x4){0.f, 0.f, 0.f, 0.f};
  for (int kt = 0; kt < 16; kt++) {
    int fbase = kt * 128 + w * 32;
#pragma unroll
    for (int nt = 0; nt < 2; nt++) {
      int f = fbase + nt * 16 + col;
      bf16x8 b0f = *(const bf16x8*)&w1p[f * 64 + quad * 8];
      bf16x8 b1f = *(const bf16x8*)&w1p[f * 64 + 32 + quad * 8];
      f32x4 hacc = {0.f, 0.f, 0.f, 0.f};
      hacc = __builtin_amdgcn_mfma_f32_16x16x32_bf16(a0, b0f, hacc, 0, 0, 0);
      hacc = __builtin_amdgcn_mfma_f32_16x16x32_bf16(a1, b1f, hacc, 0, 0, 0);
      float bias = fb1[f];
#pragma unroll
      for (int r = 0; r < 4; r++) {
        float hv = fmaxf(hacc[r] + bias, 0.f);
        myh[(quad * 4 + r) * 40 + nt * 16 + col] = f2b(hv);
      }
    }
    bf16x8 pa = *(const bf16x8*)&myh[col * 40 + quad * 8];
#pragma unroll
    for (int nt = 0; nt < 3; nt++) {
      int n = nt * 16 + col;
      bf16x8 wb = *(const bf16x8*)&w2p[(size_t)n * FF + fbase + quad * 8];
      acc3[nt] = __builtin_amdgcn_mfma_f32_16x16x32_bf16(pa, wb, acc3[nt], 0, 0, 0);
    }
  }
#pragma unroll
  for (int nt = 0; nt < 3; nt++)
#pragma unroll
    for (int r = 0; r < 4; r++)
      yred[w][quad * 4 + r][nt * 16 + col] = acc3[nt][r];
  __syncthreads();
  if (w == 0) {
    float yv[3][4];
    float s1[4] = {0.f, 0.f, 0.f, 0.f}, s2[4] = {0.f, 0.f, 0.f, 0.f};
#pragma unroll
    for (int nt = 0; nt < 3; nt++) {
      int d = nt * 16 + col;
      bool valid = d < DD;
      float b2x = valid ? fb2[d] : 0.f;
#pragma unroll
      for (int r = 0; r < 4; r++) {
        int row = quad * 4 + r;
        float v = yred[0][row][nt * 16 + col] + yred[1][row][nt * 16 + col]
                + yred[2][row][nt * 16 + col] + yred[3][row][nt * 16 + col];
        v = valid ? (v + b2x + sxF2[row][d]) : 0.f;
        yv[nt][r] = v;
        s1[r] += v;
        s2[r] += v * v;
      }
    }
#pragma unroll
    for (int msk = 1; msk <= 8; msk <<= 1)
#pragma unroll
      for (int r = 0; r < 4; r++) {
        s1[r] += __shfl_xor(s1[r], msk);
        s2[r] += __shfl_xor(s2[r], msk);
      }
#pragma unroll
    for (int r = 0; r < 4; r++) {
      int row = quad * 4 + r;
      if (row >= nr) continue;
      float mean = s1[r] * (1.f / DD);
      float var = s2[r] * (1.f / DD) - mean * mean;
      float rs = rsqrtf(var + EPSF);
#pragma unroll
      for (int nt = 0; nt < 3; nt++) {
        int d = nt * 16 + col;
        if (d < DD)
          x[(size_t)(r0 + row) * DD + d] = (yv[nt][r] - mean) * rs * g2v[d] + b2v[d];
      }
    }
  }
}

// ---- dispatch 8: final ----
__global__ __launch_bounds__(64) void final_kernel(
    const float* __restrict__ x, const int* __restrict__ aidx, float* __restrict__ out) {
  int d = threadIdx.x;
  if (d >= DD) return;
  int start = (*aidx) * HW;
  float acc = 0.f;
  for (int j = 0; j < HW; j++) acc += x[(size_t)(start + j) * DD + d];
  out[d] = acc * (1.f / HW);
}

extern "C" void kernel_launch(void* const* d_in, const int* in_sizes, int n_in,
                              void* d_out, int out_size, void* d_ws, size_t ws_size,
                              hipStream_t stream) {
  const float* obs = (const float*)d_in[0];
  const float* c1w = (const float*)d_in[1];
  const float* c1b = (const float*)d_in[2];
  const float* c2w = (const float*)d_in[3];
  const float* c2b = (const float*)d_in[4];
  const float* ipw = (const float*)d_in[5];
  const float* ipb = (const float*)d_in[6];
  const float* opw = (const float*)d_in[7];
  const float* opb = (const float*)d_in[8];
  const float* l1w = (const float*)d_in[9];
  const float* l1b = (const float*)d_in[10];
  const float* l2w = (const float*)d_in[11];
  const float* l2b = (const float*)d_in[12];
  const float* g1 = (const float*)d_in[13];
  const float* b1 = (const float*)d_in[14];
  const float* g2 = (const float*)d_in[15];
  const float* b2 = (const float*)d_in[16];
  float* out = (float*)d_out;

  float* ws = (float*)d_ws;
  size_t off = 0;
  float* x     = ws + off; off += SS * DD;
  float* qkv   = ws + off; off += SS * 102;
  float* cell  = ws + off; off += HW * CC;
  int*   aidx  = (int*)(ws + off); off += 1;
  off = (off + 3) & ~(size_t)3;
  float* Pt    = ws + off; off += 2 * HW * 102;
  float* opart = ws + off; off += (size_t)NSPLIT2 * NHEAD * 128 * HD;
  float* lpart = ws + off; off += (size_t)NSPLIT2 * NHEAD * 128;
  float* eAB   = ws + off; off += NEAB;
  off = (off + 3) & ~(size_t)3;
  unsigned short* vfragL1 = (unsigned short*)(ws + off); off += NVFL1 / 2;
  unsigned short* kfp  = (unsigned short*)(ws + off); off += NKF / 2;
  unsigned short* vfp  = (unsigned short*)(ws + off); off += NVF / 2;
  float* v16 = ws + off; off += NV16;
  unsigned short* ipwp = (unsigned short*)(ws + off); off += 2 * NIP / 2;
  unsigned short* opwp = (unsigned short*)(ws + off); off += 2 * NOP / 2;
  unsigned short* w1p  = (unsigned short*)(ws + off); off += 2 * NW1 / 2;
  unsigned short* w2p  = (unsigned short*)(ws + off); off += 2 * NW2 / 2;

  const int prep_grid = 1 + LPREP_BLOCKS + ZERO_BLOCKS;        // 3173
  const int pt_blocks = (2 * HW * 102 + 255) / 256;            // 65
  const int exp_blocks = (NEAB + NVFL1 + 255) / 256;           // 534
  const int fl1_blocks = (SS + 15) / 16;                       // 411

  prep_kernel<<<prep_grid, 256, 0, stream>>>(
      obs, c1w, c1b, c2w, c2b, cell, aidx,
      ipw, opw, l1w, l2w, ipwp, opwp, w1p, w2p, kfp, vfp, v16);
  ptprep_kernel<<<pt_blocks, 256, 0, stream>>>(cell, ipw, ipb, Pt);
  expprep_kernel<<<exp_blocks, 256, 0, stream>>>(Pt, eAB, vfragL1);
  fl1_kernel<<<fl1_blocks, 256, 0, stream>>>(
      cell, eAB, vfragL1, opwp, opb, g1, b1, w1p, w2p, l1b, l2b, g2, b2, x);
  qkv2_kernel<<<210, 256, 0, stream>>>(
      x, ipwp + NIP, ipb + 102, aidx, qkv, kfp, vfp, v16);
  dim3 a2g(2, NHEAD, NSPLIT2);
  attn2_kernel<<<a2g, 256, 0, stream>>>(qkv, kfp, vfp, v16, aidx, opart, lpart);
  fl2_kernel<<<6, 256, 0, stream>>>(
      opart, lpart, opwp + NOP, opb + DD, g1 + DD, b1 + DD,
      w1p + NW1, w2p + NW2, l1b + FF, l2b + DD, g2 + DD, b2 + DD, aidx, x);
  final_kernel<<<1, 64, 0, stream>>>(x, aidx, out);
}

// Round 13
// 187.508 us; speedup vs baseline: 15.7414x; 1.0427x over previous
//
#include <hip/hip_runtime.h>
#include <hip/hip_bf16.h>

#define HH 9
#define WW 9
#define HW 81
#define CC 16
#define DD 34
#define SS 6561
#define NHEAD 2
#define HD 17
#define FF 2048
#define EPSF 1e-5f

#define NTILES 52
#define NSPLIT2 26
#define QB 64

#define NIP 7168
#define NOP 3072
#define NW1 131072
#define NW2 98304
#define NLTOT (NIP + NOP + NW1 + NW2)   // 239616
#define LPREP_BLOCKS 1872
#define NKF 425984
#define NVF 212992
#define NV16 13312
#define ZERO_WORDS 332800
#define ZERO_BLOCKS 1300

#define NEAB 124416
#define NVFL1 12288
#define KSPLIT 8                         // fl2 FF K-splits (16 kt / 2 per block)

typedef __attribute__((ext_vector_type(8))) short bf16x8;
typedef __attribute__((ext_vector_type(4))) float f32x4;

__device__ __forceinline__ unsigned short f2b(float f) {
  unsigned int u = __float_as_uint(f);
  u += 0x7fffu + ((u >> 16) & 1u);
  return (unsigned short)(u >> 16);
}

// ---- dispatch 1: block 0 = conv; 1..1872 = weight pack; rest zero kfp/vfp/v16 ----
__global__ __launch_bounds__(256) void prep_kernel(
    const float* __restrict__ obs, const float* __restrict__ w1, const float* __restrict__ b1,
    const float* __restrict__ w2, const float* __restrict__ b2,
    float* __restrict__ cell, int* __restrict__ aidx,
    const float* __restrict__ ipw, const float* __restrict__ opw,
    const float* __restrict__ l1w, const float* __restrict__ l2w,
    unsigned short* __restrict__ ipwp, unsigned short* __restrict__ opwp,
    unsigned short* __restrict__ w1p, unsigned short* __restrict__ w2p,
    unsigned short* __restrict__ kfp, unsigned short* __restrict__ vfp,
    float* __restrict__ v16) {
  int bx = blockIdx.x;
  int t = threadIdx.x;
  if (bx == 0) {
    __shared__ float s_obs[2][11][11];
    __shared__ float s_w1[288];
    __shared__ float s_w2[2304];
    __shared__ float s_b1[16], s_b2[16];
    __shared__ float y1[CC][121];
    for (int i = t; i < 2 * 121; i += 256) ((float*)s_obs)[i] = 0.f;
    for (int i = t; i < CC * 121; i += 256) ((float*)y1)[i] = 0.f;
    for (int i = t; i < 288; i += 256) s_w1[i] = w1[i];
    for (int i = t; i < 2304; i += 256) s_w2[i] = w2[i];
    if (t < 16) { s_b1[t] = b1[t]; s_b2[t] = b2[t]; }
    __syncthreads();
    for (int i = t; i < 2 * HW; i += 256) {
      int ic = i / HW, p = i % HW;
      s_obs[ic][1 + p / WW][1 + p % WW] = obs[i];
    }
    __syncthreads();
    if (t == 0) {
      int best = 0; float bv = s_obs[0][1][1];
      for (int p = 1; p < HW; p++) {
        float v = s_obs[0][1 + p / WW][1 + p % WW];
        if (v > bv) { bv = v; best = p; }
      }
      *aidx = best;
    }
    for (int idx = t; idx < CC * HW; idx += 256) {
      int c = idx / HW, p = idx % HW;
      int i = p / WW, j = p % WW;
      float acc = s_b1[c];
#pragma unroll
      for (int ic = 0; ic < 2; ic++)
#pragma unroll
        for (int di = 0; di < 3; di++)
#pragma unroll
          for (int dj = 0; dj < 3; dj++)
            acc += s_obs[ic][i + di][j + dj] * s_w1[((c * 2 + ic) * 3 + di) * 3 + dj];
      y1[c][(i + 1) * 11 + (j + 1)] = fmaxf(acc, 0.f);
    }
    __syncthreads();
    for (int idx = t; idx < CC * HW; idx += 256) {
      int c = idx / HW, p = idx % HW;
      int i = p / WW, j = p % WW;
      float acc = s_b2[c];
#pragma unroll
      for (int ic = 0; ic < CC; ic++)
#pragma unroll
        for (int di = 0; di < 3; di++)
#pragma unroll
          for (int dj = 0; dj < 3; dj++)
            acc += y1[ic][(i + di) * 11 + (j + dj)] * s_w2[((c * CC + ic) * 3 + di) * 3 + dj];
      cell[p * CC + c] = fmaxf(acc, 0.f);
    }
  } else if (bx <= LPREP_BLOCKS) {
    int i = (bx - 1) * 256 + t;
    int layer = i / NLTOT;
    int r = i % NLTOT;
    if (r < NIP) {
      int n = r >> 6, k = r & 63;
      ipwp[layer * NIP + r] =
          (n < 102 && k < DD) ? f2b(ipw[(size_t)layer * 102 * DD + n * DD + k]) : (unsigned short)0;
    } else if (r < NIP + NOP) {
      int rr = r - NIP;
      int n = rr >> 6, k = rr & 63;
      opwp[layer * NOP + rr] =
          (n < DD && k < DD) ? f2b(opw[(size_t)layer * DD * DD + n * DD + k]) : (unsigned short)0;
    } else if (r < NIP + NOP + NW1) {
      int rr = r - NIP - NOP;
      int f = rr >> 6, k = rr & 63;
      w1p[layer * NW1 + rr] =
          (k < DD) ? f2b(l1w[(size_t)layer * FF * DD + f * DD + k]) : (unsigned short)0;
    } else {
      int rr = r - NIP - NOP - NW1;
      int d = rr >> 11, kk = rr & 2047;
      w2p[layer * NW2 + rr] =
          (d < DD) ? f2b(l2w[(size_t)layer * DD * FF + d * FF + kk]) : (unsigned short)0;
    }
  } else {
    int zi = (bx - 1 - LPREP_BLOCKS) * 256 + t;
    if (zi < NKF / 2) ((unsigned int*)kfp)[zi] = 0u;
    else if (zi < NKF / 2 + NVF / 2) ((unsigned int*)vfp)[zi - NKF / 2] = 0u;
    else if (zi < ZERO_WORDS) v16[zi - NKF / 2 - NVF / 2] = 0.f;
  }
}

// ---- dispatch 2: layer-1 separable qkv tables ----
__global__ __launch_bounds__(256) void ptprep_kernel(
    const float* __restrict__ cell, const float* __restrict__ ipw,
    const float* __restrict__ ipb, float* __restrict__ Pt) {
  int idx = blockIdx.x * 256 + threadIdx.x;
  if (idx >= 2 * HW * 102) return;
  int part = idx / (HW * 102);
  int rem = idx % (HW * 102);
  int a = rem / 102, n = rem % 102;
  float ra = (float)(a / WW) * 0.25f, ca = (float)(a % WW) * 0.25f;
  float acc;
  if (part == 0) {
    acc = ipb[n] + ipw[n * DD + 32] * ra + ipw[n * DD + 33] * ca;
    for (int f = 0; f < CC; f++) acc += ipw[n * DD + f] * cell[a * CC + f];
  } else {
    acc = -(ipw[n * DD + 32] * ra + ipw[n * DD + 33] * ca);
    for (int f = 0; f < CC; f++) acc += ipw[n * DD + CC + f] * cell[a * CC + f];
  }
  Pt[idx] = acc;
}

// ---- dispatch 3: exp-factorized score matrices + L1 V fragment table ----
__global__ __launch_bounds__(256) void expprep_kernel(
    const float* __restrict__ Pt, float* __restrict__ eAB,
    unsigned short* __restrict__ vfragL1) {
  int idx = blockIdx.x * 256 + threadIdx.x;
  const float scale = 0.24253562503633297f;
  if (idx < NEAB) {
    int a = idx % 96; int rest = idx / 96;
    int row = rest % 81; rest /= 81;
    int ab = rest & 1, p = (rest >> 1) & 1, h = rest >> 2;
    float e = 0.f;
    if (a < HW) {
      const float* qrow = Pt + (size_t)ab * (HW * 102) + row * 102 + h * HD;
      const float* krow = Pt + (size_t)p * (HW * 102) + a * 102 + DD + h * HD;
      float dot = 0.f;
#pragma unroll
      for (int d = 0; d < HD; d++) dot += qrow[d] * krow[d];
      e = __expf(fminf(dot * scale, 40.f));
    }
    eAB[idx] = e;
  } else if (idx < NEAB + NVFL1) {
    int j = idx - NEAB;
    int a = j % 96; int rest = j / 96;
    int n = rest % 32; rest /= 32;
    int p = rest & 1, h = rest >> 1;
    float v = 0.f;
    if (a < HW) {
      if (n < HD) v = Pt[(size_t)p * (HW * 102) + a * 102 + 2 * DD + h * HD + n];
      else if (n == HD) v = 1.f;
    }
    vfragL1[((size_t)(h * 2 + p) * 32 + n) * 96 + a] = f2b(v);
  }
}

// ---- dispatch 4: fused layer-1 ----
__global__ __launch_bounds__(256) void fl1_kernel(
    const float* __restrict__ cell, const float* __restrict__ eAB,
    const unsigned short* __restrict__ vfragL1,
    const unsigned short* __restrict__ opwp, const float* __restrict__ opb,
    const float* __restrict__ g1v, const float* __restrict__ b1v,
    const unsigned short* __restrict__ w1p, const unsigned short* __restrict__ w2p,
    const float* __restrict__ fb1, const float* __restrict__ fb2,
    const float* __restrict__ g2v, const float* __restrict__ b2v,
    float* __restrict__ x) {
  __shared__ __align__(16) unsigned short sE[4][16 * 96];
  __shared__ __align__(16) unsigned short soA[16 * 72];
  __shared__ float sxF[16][35];
  __shared__ __align__(16) unsigned short sxA2[16 * 72];
  __shared__ float sxF2[16][35];
  __shared__ __align__(16) unsigned short hw_[4][16 * 40];
  __shared__ float yred[4][16][49];
  int t = threadIdx.x;
  int w = t >> 6, lane = t & 63, quad = lane >> 4, col = lane & 15;
  int r0 = blockIdx.x * 16;
  int nr = min(16, SS - r0);

  for (int i = t; i < 16 * 72; i += 256) { soA[i] = 0; sxA2[i] = 0; }
  for (int i = t; i < 16 * 35; i += 256) { ((float*)sxF)[i] = 0.f; ((float*)sxF2)[i] = 0.f; }
  for (int i = t; i < nr * DD; i += 256) {
    int r = i / DD, d = i - r * DD;
    int row = r0 + r;
    int ii = row / HW, jj = row - ii * HW;
    float v;
    if (d < CC) v = cell[ii * CC + d];
    else if (d < 2 * CC) v = cell[jj * CC + (d - CC)];
    else if (d == 32) v = (float)((ii / WW) - (jj / WW)) * 0.25f;
    else v = (float)((ii % WW) - (jj % WW)) * 0.25f;
    sxF[r][d] = v;
  }

  {
    int h = w >> 1, p = w & 1;
    const float* eA = eAB + ((size_t)((h * 2 + p) * 2 + 0) * 81) * 96;
    const float* eB = eAB + ((size_t)((h * 2 + p) * 2 + 1) * 81) * 96;
    int tl = lane >> 2, asub = lane & 3;
    int row = r0 + tl;
    int tc = row < SS ? row : SS - 1;
    int it = tc / HW, jt = tc - it * HW;
    const float* eAr = eA + it * 96 + asub * 24;
    const float* eBr = eB + jt * 96 + asub * 24;
    unsigned short etmp[24];
#pragma unroll
    for (int k = 0; k < 24; k++) etmp[k] = f2b(eAr[k] * eBr[k]);
    unsigned short* Eb = &sE[w][tl * 96 + asub * 24];
#pragma unroll
    for (int k = 0; k < 3; k++)
      *(bf16x8*)(Eb + k * 8) = *(bf16x8*)(etmp + k * 8);
    const unsigned short* vf = vfragL1 + (size_t)(h * 2 + p) * 32 * 96;
    f32x4 acc0 = {0.f, 0.f, 0.f, 0.f}, acc1 = {0.f, 0.f, 0.f, 0.f};
#pragma unroll
    for (int c = 0; c < 3; c++) {
      bf16x8 ea = *(const bf16x8*)&sE[w][col * 96 + c * 32 + quad * 8];
      bf16x8 vb0 = *(const bf16x8*)&vf[col * 96 + c * 32 + quad * 8];
      bf16x8 vb1 = *(const bf16x8*)&vf[(16 + col) * 96 + c * 32 + quad * 8];
      acc0 = __builtin_amdgcn_mfma_f32_16x16x32_bf16(ea, vb0, acc0, 0, 0, 0);
      acc1 = __builtin_amdgcn_mfma_f32_16x16x32_bf16(ea, vb1, acc1, 0, 0, 0);
    }
    float Sr[4];
#pragma unroll
    for (int r = 0; r < 4; r++) Sr[r] = __shfl(acc1[r], (lane & 48) + 1);
#pragma unroll
    for (int r = 0; r < 4; r++) {
      int rr = quad * 4 + r;
      float inv = 1.f / Sr[r];
      yred[w][rr][col] = acc0[r] * inv;
      if (col == 0) yred[w][rr][16] = acc1[r] * inv;
    }
  }
  __syncthreads();
  for (int i = t; i < 16 * DD; i += 256) {
    int r = i / DD, dd = i - r * DD;
    int h2 = dd / HD, d2 = dd - h2 * HD;
    soA[r * 72 + dd] = f2b(yred[2 * h2][r][d2] + yred[2 * h2 + 1][r][d2]);
  }
  __syncthreads();

  if (w == 0) {
    bf16x8 a0 = *(const bf16x8*)&soA[col * 72 + quad * 8];
    bf16x8 a1 = *(const bf16x8*)&soA[col * 72 + 32 + quad * 8];
    f32x4 y[3];
#pragma unroll
    for (int nt = 0; nt < 3; nt++) {
      int n = nt * 16 + col;
      bf16x8 b0 = *(const bf16x8*)&opwp[n * 64 + quad * 8];
      bf16x8 b1 = *(const bf16x8*)&opwp[n * 64 + 32 + quad * 8];
      f32x4 acc = {0.f, 0.f, 0.f, 0.f};
      acc = __builtin_amdgcn_mfma_f32_16x16x32_bf16(a0, b0, acc, 0, 0, 0);
      y[nt] = __builtin_amdgcn_mfma_f32_16x16x32_bf16(a1, b1, acc, 0, 0, 0);
    }
    float yv[3][4];
    float s1[4] = {0.f, 0.f, 0.f, 0.f}, s2[4] = {0.f, 0.f, 0.f, 0.f};
#pragma unroll
    for (int nt = 0; nt < 3; nt++) {
      int d = nt * 16 + col;
      bool vd = d < DD;
      float ob = vd ? opb[d] : 0.f;
#pragma unroll
      for (int r = 0; r < 4; r++) {
        int row = quad * 4 + r;
        float v = vd ? (y[nt][r] + ob + sxF[row][d]) : 0.f;
        yv[nt][r] = v;
        s1[r] += v;
        s2[r] += v * v;
      }
    }
#pragma unroll
    for (int msk = 1; msk <= 8; msk <<= 1)
#pragma unroll
      for (int r = 0; r < 4; r++) {
        s1[r] += __shfl_xor(s1[r], msk);
        s2[r] += __shfl_xor(s2[r], msk);
      }
#pragma unroll
    for (int r = 0; r < 4; r++) {
      int row = quad * 4 + r;
      float mean = s1[r] * (1.f / DD);
      float var = s2[r] * (1.f / DD) - mean * mean;
      float rs = rsqrtf(var + EPSF);
#pragma unroll
      for (int nt = 0; nt < 3; nt++) {
        int d = nt * 16 + col;
        if (d < DD) {
          float o = (yv[nt][r] - mean) * rs * g1v[d] + b1v[d];
          sxF2[row][d] = o;
          sxA2[row * 72 + d] = f2b(o);
        }
      }
    }
  }
  __syncthreads();

  bf16x8 a0 = *(const bf16x8*)&sxA2[col * 72 + quad * 8];
  bf16x8 a1 = *(const bf16x8*)&sxA2[col * 72 + 32 + quad * 8];
  unsigned short* myh = &hw_[w][0];
  f32x4 acc3[3];
#pragma unroll
  for (int nt = 0; nt < 3; nt++) acc3[nt] = (f32x4){0.f, 0.f, 0.f, 0.f};
  for (int kt = 0; kt < 16; kt++) {
    int fbase = kt * 128 + w * 32;
#pragma unroll
    for (int nt = 0; nt < 2; nt++) {
      int f = fbase + nt * 16 + col;
      bf16x8 b0f = *(const bf16x8*)&w1p[f * 64 + quad * 8];
      bf16x8 b1f = *(const bf16x8*)&w1p[f * 64 + 32 + quad * 8];
      f32x4 hacc = {0.f, 0.f, 0.f, 0.f};
      hacc = __builtin_amdgcn_mfma_f32_16x16x32_bf16(a0, b0f, hacc, 0, 0, 0);
      hacc = __builtin_amdgcn_mfma_f32_16x16x32_bf16(a1, b1f, hacc, 0, 0, 0);
      float bias = fb1[f];
#pragma unroll
      for (int r = 0; r < 4; r++) {
        float hv = fmaxf(hacc[r] + bias, 0.f);
        myh[(quad * 4 + r) * 40 + nt * 16 + col] = f2b(hv);
      }
    }
    bf16x8 pa = *(const bf16x8*)&myh[col * 40 + quad * 8];
#pragma unroll
    for (int nt = 0; nt < 3; nt++) {
      int n = nt * 16 + col;
      bf16x8 wb = *(const bf16x8*)&w2p[(size_t)n * FF + fbase + quad * 8];
      acc3[nt] = __builtin_amdgcn_mfma_f32_16x16x32_bf16(pa, wb, acc3[nt], 0, 0, 0);
    }
  }
#pragma unroll
  for (int nt = 0; nt < 3; nt++)
#pragma unroll
    for (int r = 0; r < 4; r++)
      yred[w][quad * 4 + r][nt * 16 + col] = acc3[nt][r];
  __syncthreads();
  if (w == 0) {
    float yv[3][4];
    float s1[4] = {0.f, 0.f, 0.f, 0.f}, s2[4] = {0.f, 0.f, 0.f, 0.f};
#pragma unroll
    for (int nt = 0; nt < 3; nt++) {
      int d = nt * 16 + col;
      bool valid = d < DD;
      float b2x = valid ? fb2[d] : 0.f;
#pragma unroll
      for (int r = 0; r < 4; r++) {
        int row = quad * 4 + r;
        float v = yred[0][row][nt * 16 + col] + yred[1][row][nt * 16 + col]
                + yred[2][row][nt * 16 + col] + yred[3][row][nt * 16 + col];
        v = valid ? (v + b2x + sxF2[row][d]) : 0.f;
        yv[nt][r] = v;
        s1[r] += v;
        s2[r] += v * v;
      }
    }
#pragma unroll
    for (int msk = 1; msk <= 8; msk <<= 1)
#pragma unroll
      for (int r = 0; r < 4; r++) {
        s1[r] += __shfl_xor(s1[r], msk);
        s2[r] += __shfl_xor(s2[r], msk);
      }
#pragma unroll
    for (int r = 0; r < 4; r++) {
      int row = quad * 4 + r;
      if (row >= nr) continue;
      float mean = s1[r] * (1.f / DD);
      float var = s2[r] * (1.f / DD) - mean * mean;
      float rs = rsqrtf(var + EPSF);
#pragma unroll
      for (int nt = 0; nt < 3; nt++) {
        int d = nt * 16 + col;
        if (d < DD)
          x[(size_t)(r0 + row) * DD + d] = (yv[nt][r] - mean) * rs * g2v[d] + b2v[d];
      }
    }
  }
}

// ---- dispatch 5: layer-2 qkv (K/V fragment scatter + Q rows) ----
__global__ __launch_bounds__(256) void qkv2_kernel(
    const float* __restrict__ x, const unsigned short* __restrict__ ipwp,
    const float* __restrict__ ipb, const int* __restrict__ abase,
    float* __restrict__ qkv, unsigned short* __restrict__ kfp,
    unsigned short* __restrict__ vfp, float* __restrict__ v16) {
  __shared__ __align__(16) unsigned short sxA[32 * 72];
  int t = threadIdx.x;
  int w = t >> 6, lane = t & 63, quad = lane >> 4, col = lane & 15;
  int m0 = (w & 1) * 16, half = w >> 1;
  bool qpart = blockIdx.x >= 206;
  int row0 = qpart ? (abase[0] * HW + (blockIdx.x - 206) * 32) : blockIdx.x * 32;
  int nr = min(32, SS - row0);
  for (int i = t; i < 32 * 72; i += 256) sxA[i] = 0;
  __syncthreads();
  for (int i = t; i < nr * DD; i += 256) {
    int r = i / DD, d = i - r * DD;
    sxA[r * 72 + d] = f2b(x[(size_t)(row0 + r) * DD + d]);
  }
  __syncthreads();
  bf16x8 a0 = *(const bf16x8*)&sxA[(m0 + col) * 72 + quad * 8];
  bf16x8 a1 = *(const bf16x8*)&sxA[(m0 + col) * 72 + 32 + quad * 8];
  if (!qpart) {
    int ntc = half ? 2 : 3;
    for (int nt2 = 0; nt2 < ntc; nt2++) {
      int nt = half * 3 + nt2;
      int n = DD + nt * 16 + col;
      int nc = n < 112 ? n : 111;
      bf16x8 b0 = *(const bf16x8*)&ipwp[nc * 64 + quad * 8];
      bf16x8 b1 = *(const bf16x8*)&ipwp[nc * 64 + 32 + quad * 8];
      f32x4 acc = {0.f, 0.f, 0.f, 0.f};
      acc = __builtin_amdgcn_mfma_f32_16x16x32_bf16(a0, b0, acc, 0, 0, 0);
      acc = __builtin_amdgcn_mfma_f32_16x16x32_bf16(a1, b1, acc, 0, 0, 0);
      if (n < 102) {
        float bias = ipb[n];
        int kd = n - DD;
#pragma unroll
        for (int r = 0; r < 4; r++) {
          int m = m0 + quad * 4 + r;
          if (m >= nr) continue;
          int tok = row0 + m;
          float val = acc[r] + bias;
          int T = tok >> 7, tl = tok & 127;
          if (kd < 2 * HD) {
            int h = kd >= HD;
            int d = kd - h * HD;
            int colf = tl >> 3, ntk = tl & 7;
            kfp[(((size_t)h * NTILES + T) * 8 + ntk) * 512 +
                ((d >> 3) * 16 + colf) * 8 + (d & 7)] = f2b(val);
          } else {
            int vd = kd - 2 * HD;
            int h = vd >= HD;
            int d = vd - h * HD;
            if (d < 16) {
              int c = tl >> 5, qf = (tl >> 3) & 3, j = tl & 7;
              vfp[(((size_t)h * NTILES + T) * 4 + c) * 512 +
                  (qf * 16 + d) * 8 + j] = f2b(val);
            } else {
              v16[(size_t)h * (NTILES * 128) + tok] = val;
            }
          }
        }
      }
    }
  } else {
    int ntc = half ? 1 : 2;
    for (int nt2 = 0; nt2 < ntc; nt2++) {
      int nt = half * 2 + nt2;
      int n = nt * 16 + col;
      bf16x8 b0 = *(const bf16x8*)&ipwp[n * 64 + quad * 8];
      bf16x8 b1 = *(const bf16x8*)&ipwp[n * 64 + 32 + quad * 8];
      f32x4 acc = {0.f, 0.f, 0.f, 0.f};
      acc = __builtin_amdgcn_mfma_f32_16x16x32_bf16(a0, b0, acc, 0, 0, 0);
      acc = __builtin_amdgcn_mfma_f32_16x16x32_bf16(a1, b1, acc, 0, 0, 0);
      if (n < DD) {
        float bias = ipb[n];
#pragma unroll
        for (int r = 0; r < 4; r++) {
          int m = row0 + m0 + quad * 4 + r;
          if (m < SS) qkv[(size_t)m * 102 + n] = acc[r] + bias;
        }
      }
    }
  }
}

// ---- dispatch 6: layer-2 attention ----
__global__ __launch_bounds__(256) void attn2_kernel(
    const float* __restrict__ qkv, const unsigned short* __restrict__ kfp,
    const unsigned short* __restrict__ vfp, const float* __restrict__ v16,
    const int* __restrict__ abase,
    float* __restrict__ opart, float* __restrict__ lpart) {
  __shared__ __align__(16) unsigned short scb[4][16 * 136];
  int t = threadIdx.x, w = t >> 6, lane = t & 63, quad = lane >> 4, col = lane & 15;
  int h = blockIdx.y, sp = blockIdx.z;
  int base = abase[0] * HW;
  int q0 = blockIdx.x * QB;
  const float scale = 0.24253562503633297f;
  const unsigned short* kf = kfp + (size_t)h * (NTILES * 8 * 512);
  const unsigned short* vf = vfp + (size_t)h * (NTILES * 4 * 512);
  const float* v16h = v16 + (size_t)h * (NTILES * 128);
  unsigned short* myscb = &scb[w][0];

  int mq = base + q0 + w * 16 + col;
  int qc = mq < SS ? mq : SS - 1;
  bf16x8 aq;
#pragma unroll
  for (int j = 0; j < 8; j++) {
    int d = quad * 8 + j;
    aq[j] = (short)((d < HD) ? f2b(qkv[(size_t)qc * 102 + h * HD + d] * scale) : 0);
  }

  f32x4 oacc = {0.f, 0.f, 0.f, 0.f};
  float o16a[4] = {0.f, 0.f, 0.f, 0.f};
  float lreg[4] = {0.f, 0.f, 0.f, 0.f};

  for (int tile = sp; tile < NTILES; tile += NSPLIT2) {
    int k0 = tile * 128;
    const unsigned short* kt = kf + (size_t)tile * (8 * 512);
    f32x4 s[8];
#pragma unroll
    for (int nt = 0; nt < 8; nt++) {
      bf16x8 kb = *(const bf16x8*)(kt + nt * 512 + lane * 8);
      f32x4 z = {0.f, 0.f, 0.f, 0.f};
      s[nt] = __builtin_amdgcn_mfma_f32_16x16x32_bf16(aq, kb, z, 0, 0, 0);
    }
    if (k0 + 128 > SS) {
#pragma unroll
      for (int nt = 0; nt < 8; nt++)
        if (k0 + col * 8 + nt >= SS) {
          s[nt][0] = -1e30f; s[nt][1] = -1e30f; s[nt][2] = -1e30f; s[nt][3] = -1e30f;
        }
    }
#pragma unroll
    for (int r = 0; r < 4; r++) {
      bf16x8 pv;
      float psl = 0.f;
#pragma unroll
      for (int nt = 0; nt < 8; nt++) {
        float p = __expf(fminf(s[nt][r], 70.f));
        s[nt][r] = p;
        psl += p;
        pv[nt] = (short)f2b(p);
      }
      lreg[r] += psl;
      *(bf16x8*)(myscb + (quad * 4 + r) * 136 + col * 8) = pv;
    }
    f32x4 va = *(const f32x4*)(v16h + k0 + col * 8);
    f32x4 vb4 = *(const f32x4*)(v16h + k0 + col * 8 + 4);
#pragma unroll
    for (int r = 0; r < 4; r++) {
      o16a[r] += s[0][r] * va[0] + s[1][r] * va[1] + s[2][r] * va[2] + s[3][r] * va[3]
               + s[4][r] * vb4[0] + s[5][r] * vb4[1] + s[6][r] * vb4[2] + s[7][r] * vb4[3];
    }
    const unsigned short* vt = vf + (size_t)tile * (4 * 512);
#pragma unroll
    for (int c = 0; c < 4; c++) {
      bf16x8 pa = *(const bf16x8*)(myscb + col * 136 + c * 32 + quad * 8);
      bf16x8 vbf = *(const bf16x8*)(vt + c * 512 + lane * 8);
      oacc = __builtin_amdgcn_mfma_f32_16x16x32_bf16(pa, vbf, oacc, 0, 0, 0);
    }
  }
#pragma unroll
  for (int msk = 1; msk <= 8; msk <<= 1)
#pragma unroll
    for (int r = 0; r < 4; r++) {
      o16a[r] += __shfl_xor(o16a[r], msk);
      lreg[r] += __shfl_xor(lreg[r], msk);
    }
  size_t obase = ((size_t)sp * NHEAD + h) * 128;
#pragma unroll
  for (int r = 0; r < 4; r++) {
    int ql = q0 + w * 16 + quad * 4 + r;
    if (ql < HW) {
      opart[(obase + ql) * HD + col] = oacc[r];
      if (col == 0) {
        opart[(obase + ql) * HD + 16] = o16a[r];
        lpart[obase + ql] = lreg[r];
      }
    }
  }
}

// ---- dispatch 7: fl2a: combine + proj + LN1 (redundant per ksplit) + partial FF ----
// grid (6 rowgroups, KSPLIT). Each block does 2 kt tiles; writes ypart[sp][row][34].
// sp==0 also writes the LN1'd rows to xln.
__global__ __launch_bounds__(256) void fl2a_kernel(
    const float* __restrict__ opart, const float* __restrict__ lpart,
    const unsigned short* __restrict__ opwp, const float* __restrict__ opb,
    const float* __restrict__ g1v, const float* __restrict__ b1v,
    const unsigned short* __restrict__ w1p, const unsigned short* __restrict__ w2p,
    const float* __restrict__ fb1, const int* __restrict__ abase,
    const float* __restrict__ x, float* __restrict__ xln, float* __restrict__ ypart) {
  __shared__ __align__(16) unsigned short soA[16 * 72];
  __shared__ float sxF[16][35];
  __shared__ __align__(16) unsigned short sxA2[16 * 72];
  __shared__ float sxF2[16][35];
  __shared__ __align__(16) unsigned short hw_[4][16 * 40];
  __shared__ float yred[4][16][49];
  int t = threadIdx.x;
  int w = t >> 6, lane = t & 63, quad = lane >> 4, col = lane & 15;
  int sp = blockIdx.y;
  int base = abase[0] * HW;
  int ql0 = blockIdx.x * 16;
  int nr = min(16, HW - ql0);
  int r0 = base + ql0;

  for (int i = t; i < 16 * 72; i += 256) { soA[i] = 0; sxA2[i] = 0; }
  for (int i = t; i < 16 * 35; i += 256) { ((float*)sxF)[i] = 0.f; ((float*)sxF2)[i] = 0.f; }
  __syncthreads();
  for (int i = t; i < nr * DD; i += 256) {
    int r = i / DD, rem = i - r * DD;
    sxF[r][rem] = x[(size_t)(r0 + r) * DD + rem];
    int ql = ql0 + r;
    int h = rem / HD, d = rem - h * HD;
    float L = 0.f, O = 0.f;
#pragma unroll
    for (int s = 0; s < NSPLIT2; s++) {
      L += lpart[((size_t)s * NHEAD + h) * 128 + ql];
      O += opart[(((size_t)s * NHEAD + h) * 128 + ql) * HD + d];
    }
    soA[r * 72 + rem] = f2b(O / L);
  }
  __syncthreads();
  if (w == 0) {
    bf16x8 a0 = *(const bf16x8*)&soA[col * 72 + quad * 8];
    bf16x8 a1 = *(const bf16x8*)&soA[col * 72 + 32 + quad * 8];
    f32x4 y[3];
#pragma unroll
    for (int nt = 0; nt < 3; nt++) {
      int n = nt * 16 + col;
      bf16x8 b0 = *(const bf16x8*)&opwp[n * 64 + quad * 8];
      bf16x8 b1 = *(const bf16x8*)&opwp[n * 64 + 32 + quad * 8];
      f32x4 acc = {0.f, 0.f, 0.f, 0.f};
      acc = __builtin_amdgcn_mfma_f32_16x16x32_bf16(a0, b0, acc, 0, 0, 0);
      y[nt] = __builtin_amdgcn_mfma_f32_16x16x32_bf16(a1, b1, acc, 0, 0, 0);
    }
    float yv[3][4];
    float s1[4] = {0.f, 0.f, 0.f, 0.f}, s2[4] = {0.f, 0.f, 0.f, 0.f};
#pragma unroll
    for (int nt = 0; nt < 3; nt++) {
      int d = nt * 16 + col;
      bool vd = d < DD;
      float ob = vd ? opb[d] : 0.f;
#pragma unroll
      for (int r = 0; r < 4; r++) {
        int row = quad * 4 + r;
        float v = vd ? (y[nt][r] + ob + sxF[row][d]) : 0.f;
        yv[nt][r] = v;
        s1[r] += v;
        s2[r] += v * v;
      }
    }
#pragma unroll
    for (int msk = 1; msk <= 8; msk <<= 1)
#pragma unroll
      for (int r = 0; r < 4; r++) {
        s1[r] += __shfl_xor(s1[r], msk);
        s2[r] += __shfl_xor(s2[r], msk);
      }
#pragma unroll
    for (int r = 0; r < 4; r++) {
      int row = quad * 4 + r;
      float mean = s1[r] * (1.f / DD);
      float var = s2[r] * (1.f / DD) - mean * mean;
      float rs = rsqrtf(var + EPSF);
#pragma unroll
      for (int nt = 0; nt < 3; nt++) {
        int d = nt * 16 + col;
        if (d < DD) {
          float o = (yv[nt][r] - mean) * rs * g1v[d] + b1v[d];
          sxF2[row][d] = o;
          sxA2[row * 72 + d] = f2b(o);
          if (sp == 0 && row < nr)
            xln[(size_t)(ql0 + row) * DD + d] = o;
        }
      }
    }
  }
  __syncthreads();
  // partial FF: this block's 2 kt tiles (kt = sp*2, sp*2+1)
  bf16x8 a0 = *(const bf16x8*)&sxA2[col * 72 + quad * 8];
  bf16x8 a1 = *(const bf16x8*)&sxA2[col * 72 + 32 + quad * 8];
  unsigned short* myh = &hw_[w][0];
  f32x4 acc3[3];
#pragma unroll
  for (int nt = 0; nt < 3; nt++) acc3[nt] = (f32x4){0.f, 0.f, 0.f, 0.f};
  for (int kt2 = 0; kt2 < 2; kt2++) {
    int kt = sp * 2 + kt2;
    int fbase = kt * 128 + w * 32;
#pragma unroll
    for (int nt = 0; nt < 2; nt++) {
      int f = fbase + nt * 16 + col;
      bf16x8 b0f = *(const bf16x8*)&w1p[f * 64 + quad * 8];
      bf16x8 b1f = *(const bf16x8*)&w1p[f * 64 + 32 + quad * 8];
      f32x4 hacc = {0.f, 0.f, 0.f, 0.f};
      hacc = __builtin_amdgcn_mfma_f32_16x16x32_bf16(a0, b0f, hacc, 0, 0, 0);
      hacc = __builtin_amdgcn_mfma_f32_16x16x32_bf16(a1, b1f, hacc, 0, 0, 0);
      float bias = fb1[f];
#pragma unroll
      for (int r = 0; r < 4; r++) {
        float hv = fmaxf(hacc[r] + bias, 0.f);
        myh[(quad * 4 + r) * 40 + nt * 16 + col] = f2b(hv);
      }
    }
    bf16x8 pa = *(const bf16x8*)&myh[col * 40 + quad * 8];
#pragma unroll
    for (int nt = 0; nt < 3; nt++) {
      int n = nt * 16 + col;
      bf16x8 wb = *(const bf16x8*)&w2p[(size_t)n * FF + fbase + quad * 8];
      acc3[nt] = __builtin_amdgcn_mfma_f32_16x16x32_bf16(pa, wb, acc3[nt], 0, 0, 0);
    }
  }
#pragma unroll
  for (int nt = 0; nt < 3; nt++)
#pragma unroll
    for (int r = 0; r < 4; r++)
      yred[w][quad * 4 + r][nt * 16 + col] = acc3[nt][r];
  __syncthreads();
  if (w == 0) {
    // reduce 4 waves, write partial y (d < 34 only)
    for (int i = lane; i < nr * DD; i += 64) {
      int r = i / DD, d = i - r * DD;
      float v = yred[0][r][d] + yred[1][r][d] + yred[2][r][d] + yred[3][r][d];
      ypart[((size_t)sp * HW + ql0 + r) * DD + d] = v;
    }
  }
}

// ---- dispatch 8: fl2b: reduce ksplits + bias + residual + LN2 -> x ----
__global__ __launch_bounds__(256) void fl2b_kernel(
    const float* __restrict__ ypart, const float* __restrict__ xln,
    const float* __restrict__ fb2, const float* __restrict__ g2v,
    const float* __restrict__ b2v, const int* __restrict__ abase,
    float* __restrict__ x) {
  int t = threadIdx.x;
  int row = blockIdx.x * 32 + (t >> 3);
  int s8 = t & 7;
  if (row >= HW) return;
  int base = abase[0] * HW;
  float yv[5];
  float s1 = 0.f, s2 = 0.f;
  int cnt = 0;
  for (int d = s8; d < DD; d += 8) {
    float v = fb2[d] + xln[(size_t)row * DD + d];
#pragma unroll
    for (int sp = 0; sp < KSPLIT; sp++)
      v += ypart[((size_t)sp * HW + row) * DD + d];
    yv[cnt++] = v;
    s1 += v;
    s2 += v * v;
  }
  s1 += __shfl_xor(s1, 1); s2 += __shfl_xor(s2, 1);
  s1 += __shfl_xor(s1, 2); s2 += __shfl_xor(s2, 2);
  s1 += __shfl_xor(s1, 4); s2 += __shfl_xor(s2, 4);
  float mean = s1 * (1.f / DD);
  float var = s2 * (1.f / DD) - mean * mean;
  float rs = rsqrtf(var + EPSF);
  cnt = 0;
  for (int d = s8; d < DD; d += 8)
    x[(size_t)(base + row) * DD + d] = (yv[cnt++] - mean) * rs * g2v[d] + b2v[d];
}

// ---- dispatch 9: final ----
__global__ __launch_bounds__(64) void final_kernel(
    const float* __restrict__ x, const int* __restrict__ aidx, float* __restrict__ out) {
  int d = threadIdx.x;
  if (d >= DD) return;
  int start = (*aidx) * HW;
  float acc = 0.f;
  for (int j = 0; j < HW; j++) acc += x[(size_t)(start + j) * DD + d];
  out[d] = acc * (1.f / HW);
}

extern "C" void kernel_launch(void* const* d_in, const int* in_sizes, int n_in,
                              void* d_out, int out_size, void* d_ws, size_t ws_size,
                              hipStream_t stream) {
  const float* obs = (const float*)d_in[0];
  const float* c1w = (const float*)d_in[1];
  const float* c1b = (const float*)d_in[2];
  const float* c2w = (const float*)d_in[3];
  const float* c2b = (const float*)d_in[4];
  const float* ipw = (const float*)d_in[5];
  const float* ipb = (const float*)d_in[6];
  const float* opw = (const float*)d_in[7];
  const float* opb = (const float*)d_in[8];
  const float* l1w = (const float*)d_in[9];
  const float* l1b = (const float*)d_in[10];
  const float* l2w = (const float*)d_in[11];
  const float* l2b = (const float*)d_in[12];
  const float* g1 = (const float*)d_in[13];
  const float* b1 = (const float*)d_in[14];
  const float* g2 = (const float*)d_in[15];
  const float* b2 = (const float*)d_in[16];
  float* out = (float*)d_out;

  float* ws = (float*)d_ws;
  size_t off = 0;
  float* x     = ws + off; off += SS * DD;
  float* qkv   = ws + off; off += SS * 102;
  float* cell  = ws + off; off += HW * CC;
  int*   aidx  = (int*)(ws + off); off += 1;
  off = (off + 3) & ~(size_t)3;
  float* Pt    = ws + off; off += 2 * HW * 102;
  float* opart = ws + off; off += (size_t)NSPLIT2 * NHEAD * 128 * HD;
  float* lpart = ws + off; off += (size_t)NSPLIT2 * NHEAD * 128;
  float* eAB   = ws + off; off += NEAB;
  float* xln   = ws + off; off += HW * DD;
  float* ypart = ws + off; off += (size_t)KSPLIT * HW * DD;
  off = (off + 3) & ~(size_t)3;
  unsigned short* vfragL1 = (unsigned short*)(ws + off); off += NVFL1 / 2;
  unsigned short* kfp  = (unsigned short*)(ws + off); off += NKF / 2;
  unsigned short* vfp  = (unsigned short*)(ws + off); off += NVF / 2;
  float* v16 = ws + off; off += NV16;
  unsigned short* ipwp = (unsigned short*)(ws + off); off += 2 * NIP / 2;
  unsigned short* opwp = (unsigned short*)(ws + off); off += 2 * NOP / 2;
  unsigned short* w1p  = (unsigned short*)(ws + off); off += 2 * NW1 / 2;
  unsigned short* w2p  = (unsigned short*)(ws + off); off += 2 * NW2 / 2;

  const int prep_grid = 1 + LPREP_BLOCKS + ZERO_BLOCKS;
  const int pt_blocks = (2 * HW * 102 + 255) / 256;
  const int exp_blocks = (NEAB + NVFL1 + 255) / 256;
  const int fl1_blocks = (SS + 15) / 16;

  prep_kernel<<<prep_grid, 256, 0, stream>>>(
      obs, c1w, c1b, c2w, c2b, cell, aidx,
      ipw, opw, l1w, l2w, ipwp, opwp, w1p, w2p, kfp, vfp, v16);
  ptprep_kernel<<<pt_blocks, 256, 0, stream>>>(cell, ipw, ipb, Pt);
  expprep_kernel<<<exp_blocks, 256, 0, stream>>>(Pt, eAB, vfragL1);
  fl1_kernel<<<fl1_blocks, 256, 0, stream>>>(
      cell, eAB, vfragL1, opwp, opb, g1, b1, w1p, w2p, l1b, l2b, g2, b2, x);
  qkv2_kernel<<<210, 256, 0, stream>>>(
      x, ipwp + NIP, ipb + 102, aidx, qkv, kfp, vfp, v16);
  dim3 a2g(2, NHEAD, NSPLIT2);
  attn2_kernel<<<a2g, 256, 0, stream>>>(qkv, kfp, vfp, v16, aidx, opart, lpart);
  dim3 f2g(6, KSPLIT);
  fl2a_kernel<<<f2g, 256, 0, stream>>>(
      opart, lpart, opwp + NOP, opb + DD, g1 + DD, b1 + DD,
      w1p + NW1, w2p + NW2, l1b + FF, aidx, x, xln, ypart);
  fl2b_kernel<<<3, 256, 0, stream>>>(
      ypart, xln, l2b + DD, g2 + DD, b2 + DD, aidx, x);
  final_kernel<<<1, 64, 0, stream>>>(x, aidx, out);
}